// Round 9
// baseline (2148.279 us; speedup 1.0000x reference)
//
#include <hip/hip_runtime.h>

// ---------------------------------------------------------------------------
// MoDeDiT block: LN1 -> QKV -> MHA -> proj(+res) -> LN2-stats -> router MLP
//                -> top2 -> MoE expert MLPs -> combine
//
// R13 == R12 resubmitted verbatim ("container failed twice" with no
// verification output; same signature as R6 which was an infra flake.
// attn_mfma re-audited: no divergent barriers, no OOB, 88KB LDS < 160KB
// gfx950 workgroup limit. If this fails identically again, the kernel is
// implicated and R14 reverts attention to the R11 VALU version.)
//
// R12: MFMA flash attention (fat path). R11 profile: attn_kernel 131us x2,
// MfmaUtil 0, VALUBusy 57% -- fp32 VALU attention with a 55us VALU floor.
// attn_mfma_kernel: split-bf16 (hi/lo) 3-pass MFMA for QK^T and PV, S/P in
// LDS as bf16 hi/lo [64][264], wave-parallel exact softmax, V staged
// transposed for the B-fragment, register-prefetched staging.
// ---------------------------------------------------------------------------

typedef unsigned short u16;
typedef unsigned int   u32;

typedef __bf16 bf16x8 __attribute__((ext_vector_type(8)));
typedef float  floatx4 __attribute__((ext_vector_type(4)));

__device__ __forceinline__ float b2f(u32 u) {
    union { float f; u32 i; } v; v.i = (u & 0xffffu) << 16; return v.f;
}
__device__ __forceinline__ u16 f2b(float f) {  // round-nearest-even
    union { float f; u32 i; } v; v.f = f;
    u32 x = v.i;
    u32 r = (x + 0x7fffu + ((x >> 16) & 1u)) >> 16;
    return (u16)r;
}
__device__ __forceinline__ float gelu_f(float x) {
    return 0.5f * x * (1.0f + erff(x * 0.70710678118654752440f));
}
__device__ __forceinline__ float lmix(const void* p, size_t i, int isf) {
    return isf ? ((const float*)p)[i] : b2f(((const u16*)p)[i]);
}
__device__ __forceinline__ void ld8(const void* p, size_t i, int isf, float w[8]) {
    if (isf) {
        const float* q = (const float*)p + i;
        float4 a = *(const float4*)q, b = *(const float4*)(q + 4);
        w[0] = a.x; w[1] = a.y; w[2] = a.z; w[3] = a.w;
        w[4] = b.x; w[5] = b.y; w[6] = b.z; w[7] = b.w;
    } else {
        const u16* q = (const u16*)p + i;
        uint4 r = *(const uint4*)q;
        w[0] = b2f(r.x); w[1] = b2f(r.x >> 16);
        w[2] = b2f(r.y); w[3] = b2f(r.y >> 16);
        w[4] = b2f(r.z); w[5] = b2f(r.z >> 16);
        w[6] = b2f(r.w); w[7] = b2f(r.w >> 16);
    }
}
__device__ __forceinline__ void ld4(const void* p, size_t i, int isf, float w[4]) {
    if (isf) {
        float4 a = *(const float4*)((const float*)p + i);
        w[0] = a.x; w[1] = a.y; w[2] = a.z; w[3] = a.w;
    } else {
        uint2 r = *(const uint2*)((const u16*)p + i);
        w[0] = b2f(r.x); w[1] = b2f(r.x >> 16);
        w[2] = b2f(r.y); w[3] = b2f(r.y >> 16);
    }
}

// ---------------------------------------------------------------------------
__global__ void init_kernel(const void* x0, int* cb) {
    __shared__ int sh[256];
    const int tid = threadIdx.x;
    if (tid < 12) cb[tid] = 0;
    int bad = 0;
    const u16* p = (const u16*)x0;
    for (int i = tid; i < 4096; i += 256) {
        float v = b2f(p[2 * i]);
        float a = fabsf(v);
        if (!(a <= 1e3f) || (v != 0.f && a < 1e-8f)) bad++;
    }
    sh[tid] = bad;
    __syncthreads();
    for (int s = 128; s > 0; s >>= 1) {
        if (tid < s) sh[tid] += sh[tid + s];
        __syncthreads();
    }
    if (tid == 0) cb[12] = (sh[0] > 512) ? 1 : 0;
}

// ---------------------------------------------------------------------------
// cond_kernel: ct[b][col] = sum_k cond[b][k] * W[1024+k][col], fp32.
// ---------------------------------------------------------------------------
__global__ __launch_bounds__(256) void cond_kernel(
    const void* __restrict__ cond, const void* __restrict__ w1,
    float* __restrict__ ct, const int* __restrict__ flg)
{
    const int isf = flg[12];
    const int b = blockIdx.y;
    const int col0 = blockIdx.x * 64;
    const int tid = threadIdx.x;
    const int wave = tid >> 6, lane = tid & 63;
    __shared__ float a[1024];
    __shared__ float part[4][64];
    {
        float v[4];
        ld4(cond, (size_t)b * 1024 + tid * 4, isf, v);
        a[tid * 4 + 0] = v[0]; a[tid * 4 + 1] = v[1];
        a[tid * 4 + 2] = v[2]; a[tid * 4 + 3] = v[3];
    }
    __syncthreads();
    const int col = col0 + lane;
    float s = 0.f;
    const int kbase = wave * 256;
    #pragma unroll 4
    for (int k = 0; k < 256; k++)
        s = fmaf(a[kbase + k], lmix(w1, (size_t)(1024 + kbase + k) * 2048 + col, isf), s);
    part[wave][lane] = s;
    __syncthreads();
    if (wave == 0) {
        float r = (part[0][lane] + part[1][lane]) + (part[2][lane] + part[3][lane]);
        ct[(size_t)b * 2048 + col] = r;
    }
}

// ---------------------------------------------------------------------------
// pack_ln: LN a row of 1024 -> split pack [row][hi|lo]; optionally also a
// plain bf16 copy into hb[global row] (fast-path h2b).
// ---------------------------------------------------------------------------
__global__ __launch_bounds__(256) void pack_ln_kernel(
    int mode, const void* __restrict__ xin, size_t rowbase,
    const void* __restrict__ g, const void* __restrict__ bta,
    const float* __restrict__ mu_g, const float* __restrict__ rs_g,
    u16* __restrict__ hpk, u16* __restrict__ hb, const int* __restrict__ flg)
{
    const int isf = flg[12];
    const int row = blockIdx.x, tid = threadIdx.x;
    float v[4];
    float mu, rsv;
    __shared__ float red[8];
    __shared__ float mu_rs[2];
    if (mode == 0) {
        ld4(xin, (rowbase + row) * 1024 + tid * 4, isf, v);
        float s = v[0] + v[1] + v[2] + v[3];
        float q = v[0] * v[0] + v[1] * v[1] + v[2] * v[2] + v[3] * v[3];
        #pragma unroll
        for (int off = 32; off > 0; off >>= 1) {
            s += __shfl_down(s, off, 64);
            q += __shfl_down(q, off, 64);
        }
        int wid = tid >> 6, lane = tid & 63;
        if (lane == 0) { red[wid] = s; red[4 + wid] = q; }
        __syncthreads();
        if (tid == 0) {
            float ts = red[0] + red[1] + red[2] + red[3];
            float tq = red[4] + red[5] + red[6] + red[7];
            float m = ts * (1.0f / 1024.0f);
            float var = tq * (1.0f / 1024.0f) - m * m;
            float xx = var + 1e-5f;
            float r = rsqrtf(xx);
            r = r * (1.5f - 0.5f * xx * r * r);
            mu_rs[0] = m; mu_rs[1] = r;
        }
        __syncthreads();
        mu = mu_rs[0]; rsv = mu_rs[1];
    } else {
        float4 t = *(const float4*)((const float*)xin + (rowbase + row) * 1024 + tid * 4);
        v[0] = t.x; v[1] = t.y; v[2] = t.z; v[3] = t.w;
        mu = mu_g[rowbase + row]; rsv = rs_g[rowbase + row];
    }
    float gg[4], bb[4];
    ld4(g, tid * 4, isf, gg);
    ld4(bta, tid * 4, isf, bb);
    u16 hi[4], lo[4];
    #pragma unroll
    for (int i = 0; i < 4; i++) {
        float h = (v[i] - mu) * rsv * gg[i] + bb[i];
        hi[i] = f2b(h);
        lo[i] = f2b(h - b2f(hi[i]));
    }
    uint2 ph, pl;
    ph.x = (u32)hi[0] | ((u32)hi[1] << 16);
    ph.y = (u32)hi[2] | ((u32)hi[3] << 16);
    pl.x = (u32)lo[0] | ((u32)lo[1] << 16);
    pl.y = (u32)lo[2] | ((u32)lo[3] << 16);
    *(uint2*)(hpk + (size_t)row * 2048 + tid * 4) = ph;
    *(uint2*)(hpk + (size_t)row * 2048 + 1024 + tid * 4) = pl;
    if (hb) *(uint2*)(hb + (rowbase + row) * 1024 + tid * 4) = ph;
}

// ---------------------------------------------------------------------------
// pack_wt: split W[K][N] (mixed) -> transposed split pack Bt[N][2K].
// ---------------------------------------------------------------------------
__global__ __launch_bounds__(256) void pack_wt_kernel(
    const void* __restrict__ W, int N, int K,
    u16* __restrict__ Bt, const int* __restrict__ flg)
{
    const int isf = flg[12];
    __shared__ float sh[64][65];
    const int k0 = blockIdx.x * 64, n0 = blockIdx.y * 64;
    const int tid = threadIdx.x;
    #pragma unroll
    for (int i = 0; i < 4; i++) {
        int r = (tid >> 4) + i * 16, c = (tid & 15) * 4;
        float w[4];
        ld4(W, (size_t)(k0 + r) * N + n0 + c, isf, w);
        sh[r][c] = w[0]; sh[r][c + 1] = w[1]; sh[r][c + 2] = w[2]; sh[r][c + 3] = w[3];
    }
    __syncthreads();
    const int n = tid >> 2, kc = (tid & 3) * 16;
    u16 hi[16], lo[16];
    #pragma unroll
    for (int j = 0; j < 16; j++) {
        float v = sh[kc + j][n];
        hi[j] = f2b(v);
        lo[j] = f2b(v - b2f(hi[j]));
    }
    u16* dst = Bt + (size_t)(n0 + n) * (2 * K) + k0 + kc;
    uint4 a, b;
    a.x = (u32)hi[0] | ((u32)hi[1] << 16);  a.y = (u32)hi[2] | ((u32)hi[3] << 16);
    a.z = (u32)hi[4] | ((u32)hi[5] << 16);  a.w = (u32)hi[6] | ((u32)hi[7] << 16);
    b.x = (u32)hi[8] | ((u32)hi[9] << 16);  b.y = (u32)hi[10] | ((u32)hi[11] << 16);
    b.z = (u32)hi[12] | ((u32)hi[13] << 16); b.w = (u32)hi[14] | ((u32)hi[15] << 16);
    *(uint4*)dst = a; *(uint4*)(dst + 8) = b;
    a.x = (u32)lo[0] | ((u32)lo[1] << 16);  a.y = (u32)lo[2] | ((u32)lo[3] << 16);
    a.z = (u32)lo[4] | ((u32)lo[5] << 16);  a.w = (u32)lo[6] | ((u32)lo[7] << 16);
    b.x = (u32)lo[8] | ((u32)lo[9] << 16);  b.y = (u32)lo[10] | ((u32)lo[11] << 16);
    b.z = (u32)lo[12] | ((u32)lo[13] << 16); b.w = (u32)lo[14] | ((u32)lo[15] << 16);
    *(uint4*)(dst + K) = a; *(uint4*)(dst + K + 8) = b;
}

// ---------------------------------------------------------------------------
// pack_wtb: plain bf16 transpose pack. W[K][N] (mixed, +wOff elems) -> Bt[N][K].
// ---------------------------------------------------------------------------
__global__ __launch_bounds__(256) void pack_wtb_kernel(
    const void* __restrict__ W, size_t wOff, int N, int K,
    u16* __restrict__ Bt, const int* __restrict__ flg)
{
    const int isf = flg[12];
    __shared__ float sh[64][65];
    const int k0 = blockIdx.x * 64, n0 = blockIdx.y * 64;
    const int tid = threadIdx.x;
    #pragma unroll
    for (int i = 0; i < 4; i++) {
        int r = (tid >> 4) + i * 16, c = (tid & 15) * 4;
        float w[4];
        ld4(W, wOff + (size_t)(k0 + r) * N + n0 + c, isf, w);
        sh[r][c] = w[0]; sh[r][c + 1] = w[1]; sh[r][c + 2] = w[2]; sh[r][c + 3] = w[3];
    }
    __syncthreads();
    const int n = tid >> 2, kc = (tid & 3) * 16;
    u16 hi[16];
    #pragma unroll
    for (int j = 0; j < 16; j++) hi[j] = f2b(sh[kc + j][n]);
    u16* dst = Bt + (size_t)(n0 + n) * K + k0 + kc;
    uint4 a, b;
    a.x = (u32)hi[0] | ((u32)hi[1] << 16);  a.y = (u32)hi[2] | ((u32)hi[3] << 16);
    a.z = (u32)hi[4] | ((u32)hi[5] << 16);  a.w = (u32)hi[6] | ((u32)hi[7] << 16);
    b.x = (u32)hi[8] | ((u32)hi[9] << 16);  b.y = (u32)hi[10] | ((u32)hi[11] << 16);
    b.z = (u32)hi[12] | ((u32)hi[13] << 16); b.w = (u32)hi[14] | ((u32)hi[15] << 16);
    *(uint4*)dst = a; *(uint4*)(dst + 8) = b;
}

// ---------------------------------------------------------------------------
// pack_sb_rows: fp32 [8192][1024] -> split pack [row][hi|lo] (for proj A).
// ---------------------------------------------------------------------------
__global__ __launch_bounds__(256) void pack_sb_rows_kernel(
    const float* __restrict__ src, u16* __restrict__ dst)
{
    const int row = blockIdx.x, tid = threadIdx.x;
    float4 t = *(const float4*)(src + (size_t)row * 1024 + tid * 4);
    float v[4] = {t.x, t.y, t.z, t.w};
    u16 hi[4], lo[4];
    #pragma unroll
    for (int i = 0; i < 4; i++) {
        hi[i] = f2b(v[i]);
        lo[i] = f2b(v[i] - b2f(hi[i]));
    }
    uint2 ph, pl;
    ph.x = (u32)hi[0] | ((u32)hi[1] << 16);
    ph.y = (u32)hi[2] | ((u32)hi[3] << 16);
    pl.x = (u32)lo[0] | ((u32)lo[1] << 16);
    pl.y = (u32)lo[2] | ((u32)lo[3] << 16);
    *(uint2*)(dst + (size_t)row * 2048 + tid * 4) = ph;
    *(uint2*)(dst + (size_t)row * 2048 + 1024 + tid * 4) = pl;
}

// ---------------------------------------------------------------------------
// gemm_sb: split-bf16 3-pass MFMA GEMM. A [M][2K], B [N][2K], C fp32.
// 128x128 tile, 4 waves (2x2) of 64x64, BK=32.
// ---------------------------------------------------------------------------
#define SB_PLAIN 0
#define SB_FC1   1
#define SB_PROJ  2

__global__ __launch_bounds__(256) void gemm_sb(
    int mode,
    const u16* __restrict__ Ap,
    const u16* __restrict__ Bt,
    int K,
    float* __restrict__ C, int ldc,
    const void* __restrict__ bias,
    const float* __restrict__ condt,
    const void* __restrict__ resid,
    int rowbase, const int* __restrict__ flg)
{
    const int isf = flg[12];
    __shared__ __align__(16) u16 Ah[128][40];
    __shared__ __align__(16) u16 Al[128][40];
    __shared__ __align__(16) u16 Bh[128][40];
    __shared__ __align__(16) u16 Bl[128][40];
    const int tid = threadIdx.x;
    const int row0 = blockIdx.y * 128, col0 = blockIdx.x * 128;
    const int wave = tid >> 6, lane = tid & 63;
    const int wm = (wave >> 1) * 64, wn = (wave & 1) * 64;
    const int ln = lane & 15, quad = lane >> 4;
    const size_t K2 = (size_t)2 * K;
    floatx4 acc[4][4];
    #pragma unroll
    for (int i = 0; i < 4; i++)
        #pragma unroll
        for (int j = 0; j < 4; j++) acc[i][j] = (floatx4){0.f, 0.f, 0.f, 0.f};

    const int ar = tid >> 1, ac = (tid & 1) * 16;
    uint4 pa0, pa1, pal0, pal1, pb0, pb1, pbl0, pbl1;

    {
        const u16* ap = Ap + (size_t)(row0 + ar) * K2 + ac;
        pa0 = *(const uint4*)ap;        pa1 = *(const uint4*)(ap + 8);
        pal0 = *(const uint4*)(ap + K); pal1 = *(const uint4*)(ap + K + 8);
        const u16* bp = Bt + (size_t)(col0 + ar) * K2 + ac;
        pb0 = *(const uint4*)bp;        pb1 = *(const uint4*)(bp + 8);
        pbl0 = *(const uint4*)(bp + K); pbl1 = *(const uint4*)(bp + K + 8);
    }

    for (int k0 = 0; k0 < K; k0 += 32) {
        __syncthreads();
        *(uint4*)&Ah[ar][ac] = pa0;  *(uint4*)&Ah[ar][ac + 8] = pa1;
        *(uint4*)&Al[ar][ac] = pal0; *(uint4*)&Al[ar][ac + 8] = pal1;
        *(uint4*)&Bh[ar][ac] = pb0;  *(uint4*)&Bh[ar][ac + 8] = pb1;
        *(uint4*)&Bl[ar][ac] = pbl0; *(uint4*)&Bl[ar][ac + 8] = pbl1;
        __syncthreads();
        if (k0 + 32 < K) {
            const u16* ap = Ap + (size_t)(row0 + ar) * K2 + k0 + 32 + ac;
            pa0 = *(const uint4*)ap;        pa1 = *(const uint4*)(ap + 8);
            pal0 = *(const uint4*)(ap + K); pal1 = *(const uint4*)(ap + K + 8);
            const u16* bp = Bt + (size_t)(col0 + ar) * K2 + k0 + 32 + ac;
            pb0 = *(const uint4*)bp;        pb1 = *(const uint4*)(bp + 8);
            pbl0 = *(const uint4*)(bp + K); pbl1 = *(const uint4*)(bp + K + 8);
        }
        bf16x8 ah[4], al[4];
        #pragma unroll
        for (int mt = 0; mt < 4; mt++) {
            ah[mt] = *(const bf16x8*)&Ah[wm + mt * 16 + ln][quad * 8];
            al[mt] = *(const bf16x8*)&Al[wm + mt * 16 + ln][quad * 8];
        }
        #pragma unroll
        for (int nt = 0; nt < 4; nt++) {
            bf16x8 bh = *(const bf16x8*)&Bh[wn + nt * 16 + ln][quad * 8];
            bf16x8 bl = *(const bf16x8*)&Bl[wn + nt * 16 + ln][quad * 8];
            #pragma unroll
            for (int mt = 0; mt < 4; mt++) {
                acc[mt][nt] = __builtin_amdgcn_mfma_f32_16x16x32_bf16(ah[mt], bh, acc[mt][nt], 0, 0, 0);
                acc[mt][nt] = __builtin_amdgcn_mfma_f32_16x16x32_bf16(ah[mt], bl, acc[mt][nt], 0, 0, 0);
                acc[mt][nt] = __builtin_amdgcn_mfma_f32_16x16x32_bf16(al[mt], bh, acc[mt][nt], 0, 0, 0);
            }
        }
    }
    #pragma unroll
    for (int mt = 0; mt < 4; mt++) {
        #pragma unroll
        for (int nt = 0; nt < 4; nt++) {
            #pragma unroll
            for (int r = 0; r < 4; r++) {
                int row = row0 + wm + mt * 16 + quad * 4 + r;
                int col = col0 + wn + nt * 16 + ln;
                float v = acc[mt][nt][r];
                if (mode == SB_FC1)
                    v = gelu_f(v + lmix(bias, col, isf) +
                               condt[(size_t)((rowbase + row) >> 8) * 2048 + col]);
                else if (mode == SB_PROJ)
                    v += lmix(bias, col, isf) + lmix(resid, (size_t)row * ldc + col, isf);
                C[(size_t)row * ldc + col] = v;
            }
        }
    }
}

// ---------------------------------------------------------------------------
// gemm_moe: plain bf16 MFMA GEMM, 128x128 tile (expert FC1).
// ---------------------------------------------------------------------------
#define MOE_FC1 0
#define MOE_FC2 1

__global__ __launch_bounds__(256) void gemm_moe(
    int mode,
    const u16* __restrict__ Ap,
    const u16* __restrict__ Bt,
    int K,
    u16* __restrict__ C, int ldc,
    const void* __restrict__ bias, size_t biasOff,
    const float* __restrict__ rowscale,
    const int* __restrict__ toklist,
    const int* __restrict__ cb, int e, int rowOff,
    const int* __restrict__ flg)
{
    const int isf = flg[12];
    const int Meff = cb[e];
    const int gbase = cb[4 + e];
    const int rg0 = rowOff + blockIdx.y * 128;
    if (rg0 >= Meff) return;
    const int col0 = blockIdx.x * 128;
    __shared__ __align__(16) u16 As[128][40];
    __shared__ __align__(16) u16 Bs[128][40];
    const int tid = threadIdx.x;
    const int wave = tid >> 6, lane = tid & 63;
    const int wm = (wave >> 1) * 64, wn = (wave & 1) * 64;
    const int ln = lane & 15, quad = lane >> 4;
    floatx4 acc[4][4];
    #pragma unroll
    for (int i = 0; i < 4; i++)
        #pragma unroll
        for (int j = 0; j < 4; j++) acc[i][j] = (floatx4){0.f, 0.f, 0.f, 0.f};

    const int ar = tid >> 1, ac = (tid & 1) * 16;
    const int rg = rg0 + ar;
    const bool valid = (rg < Meff);
    const u16* arow;
    if (mode == MOE_FC1) {
        int tokid = valid ? toklist[gbase + rg] : 0;
        arow = Ap + (size_t)tokid * K;
    } else {
        arow = Ap + (size_t)(rg - rowOff) * K;
    }
    const u16* brow = Bt + (size_t)(col0 + ar) * K;
    uint4 pa0 = {0u,0u,0u,0u}, pa1 = {0u,0u,0u,0u}, pb0, pb1;
    if (valid) { pa0 = *(const uint4*)(arow + ac); pa1 = *(const uint4*)(arow + ac + 8); }
    pb0 = *(const uint4*)(brow + ac); pb1 = *(const uint4*)(brow + ac + 8);

    for (int k0 = 0; k0 < K; k0 += 32) {
        __syncthreads();
        *(uint4*)&As[ar][ac] = pa0; *(uint4*)&As[ar][ac + 8] = pa1;
        *(uint4*)&Bs[ar][ac] = pb0; *(uint4*)&Bs[ar][ac + 8] = pb1;
        __syncthreads();
        if (k0 + 32 < K) {
            if (valid) {
                pa0 = *(const uint4*)(arow + k0 + 32 + ac);
                pa1 = *(const uint4*)(arow + k0 + 32 + ac + 8);
            }
            pb0 = *(const uint4*)(brow + k0 + 32 + ac);
            pb1 = *(const uint4*)(brow + k0 + 32 + ac + 8);
        }
        bf16x8 a[4];
        #pragma unroll
        for (int mt = 0; mt < 4; mt++)
            a[mt] = *(const bf16x8*)&As[wm + mt * 16 + ln][quad * 8];
        #pragma unroll
        for (int nt = 0; nt < 4; nt++) {
            bf16x8 b = *(const bf16x8*)&Bs[wn + nt * 16 + ln][quad * 8];
            #pragma unroll
            for (int mt = 0; mt < 4; mt++)
                acc[mt][nt] = __builtin_amdgcn_mfma_f32_16x16x32_bf16(a[mt], b, acc[mt][nt], 0, 0, 0);
        }
    }
    #pragma unroll
    for (int mt = 0; mt < 4; mt++) {
        #pragma unroll
        for (int nt = 0; nt < 4; nt++) {
            #pragma unroll
            for (int r = 0; r < 4; r++) {
                int gw = rg0 + wm + mt * 16 + quad * 4 + r;
                if (gw >= Meff) continue;
                int col = col0 + wn + nt * 16 + ln;
                float v = acc[mt][nt][r] + lmix(bias, biasOff + col, isf);
                if (mode == MOE_FC1) {
                    C[(size_t)(gw - rowOff) * ldc + col] = f2b(gelu_f(v));
                } else {
                    v *= rowscale[gbase + gw];
                    C[(size_t)(gbase + gw) * ldc + col] = f2b(v);
                }
            }
        }
    }
}

// ---------------------------------------------------------------------------
// gemm_moe2: expert FC2 bf16 MFMA GEMM. 128x64 tile, grid 16x16 = 256 blocks.
// ---------------------------------------------------------------------------
__global__ __launch_bounds__(256) void gemm_moe2(
    const u16* __restrict__ Ap,
    const u16* __restrict__ Bt,
    u16* __restrict__ C,
    const void* __restrict__ bias, size_t biasOff,
    const float* __restrict__ rowscale,
    const int* __restrict__ cb, int e, int rowOff,
    const int* __restrict__ flg)
{
    const int isf = flg[12];
    const int Meff = cb[e];
    const int gbase = cb[4 + e];
    const int rg0 = rowOff + blockIdx.y * 128;
    if (rg0 >= Meff) return;
    const int col0 = blockIdx.x * 64;
    const int K = 4096;
    __shared__ __align__(16) u16 As[128][40];
    __shared__ __align__(16) u16 Bs[64][40];
    const int tid = threadIdx.x;
    const int wave = tid >> 6, lane = tid & 63;
    const int ln = lane & 15, quad = lane >> 4;
    floatx4 acc[2][4];
    #pragma unroll
    for (int i = 0; i < 2; i++)
        #pragma unroll
        for (int j = 0; j < 4; j++) acc[i][j] = (floatx4){0.f, 0.f, 0.f, 0.f};

    const int ar = tid >> 1, ac = (tid & 1) * 16;   // A: 128 rows x 32 k
    const int br = tid >> 2, bc = (tid & 3) * 8;    // B: 64 rows x 32 k
    const int rg = rg0 + ar;
    const bool valid = (rg < Meff);
    const u16* arow = Ap + (size_t)(rg - rowOff) * K;
    const u16* brow = Bt + (size_t)(col0 + br) * K;
    uint4 pa0 = {0u,0u,0u,0u}, pa1 = {0u,0u,0u,0u}, pb;
    if (valid) { pa0 = *(const uint4*)(arow + ac); pa1 = *(const uint4*)(arow + ac + 8); }
    pb = *(const uint4*)(brow + bc);

    for (int k0 = 0; k0 < K; k0 += 32) {
        __syncthreads();
        *(uint4*)&As[ar][ac] = pa0; *(uint4*)&As[ar][ac + 8] = pa1;
        *(uint4*)&Bs[br][bc] = pb;
        __syncthreads();
        if (k0 + 32 < K) {
            if (valid) {
                pa0 = *(const uint4*)(arow + k0 + 32 + ac);
                pa1 = *(const uint4*)(arow + k0 + 32 + ac + 8);
            }
            pb = *(const uint4*)(brow + k0 + 32 + bc);
        }
        bf16x8 a0 = *(const bf16x8*)&As[wave * 32 + ln][quad * 8];
        bf16x8 a1 = *(const bf16x8*)&As[wave * 32 + 16 + ln][quad * 8];
        #pragma unroll
        for (int nt = 0; nt < 4; nt++) {
            bf16x8 b = *(const bf16x8*)&Bs[nt * 16 + ln][quad * 8];
            acc[0][nt] = __builtin_amdgcn_mfma_f32_16x16x32_bf16(a0, b, acc[0][nt], 0, 0, 0);
            acc[1][nt] = __builtin_amdgcn_mfma_f32_16x16x32_bf16(a1, b, acc[1][nt], 0, 0, 0);
        }
    }
    #pragma unroll
    for (int mt = 0; mt < 2; mt++) {
        #pragma unroll
        for (int nt = 0; nt < 4; nt++) {
            #pragma unroll
            for (int r = 0; r < 4; r++) {
                int gw = rg0 + wave * 32 + mt * 16 + quad * 4 + r;
                if (gw >= Meff) continue;
                int col = col0 + nt * 16 + ln;
                float v = acc[mt][nt][r] + lmix(bias, biasOff + col, isf);
                v *= rowscale[gbase + gw];
                C[(size_t)(gbase + gw) * 1024 + col] = f2b(v);
            }
        }
    }
}

// ---------------------------------------------------------------------------
__global__ __launch_bounds__(256) void ln_stats_kernel(
    const float* __restrict__ xin, float* __restrict__ mu, float* __restrict__ rs)
{
    const int row = blockIdx.x, tid = threadIdx.x;
    float4 t = *(const float4*)(xin + (size_t)row * 1024 + tid * 4);
    float s = t.x + t.y + t.z + t.w;
    float q = t.x * t.x + t.y * t.y + t.z * t.z + t.w * t.w;
    #pragma unroll
    for (int off = 32; off > 0; off >>= 1) {
        s += __shfl_down(s, off, 64);
        q += __shfl_down(q, off, 64);
    }
    __shared__ float red[8];
    int wid = tid >> 6, lane = tid & 63;
    if (lane == 0) { red[wid] = s; red[4 + wid] = q; }
    __syncthreads();
    if (tid == 0) {
        float ts = red[0] + red[1] + red[2] + red[3];
        float tq = red[4] + red[5] + red[6] + red[7];
        float m = ts * (1.0f / 1024.0f);
        float var = tq * (1.0f / 1024.0f) - m * m;
        float xx = var + 1e-5f;
        float r = rsqrtf(xx);
        r = r * (1.5f - 0.5f * xx * r * r);
        mu[row] = m; rs[row] = r;
    }
}

// ---------------------------------------------------------------------------
// fp32 VALU GEMM (fallback proj).
// ---------------------------------------------------------------------------
#define GM_PLAIN 0
#define GM_PROJ  1

__global__ __launch_bounds__(256) void gemm_f32(
    int mode, int aMode,
    const void* __restrict__ Av, int lda,
    const void* __restrict__ Bv, int ldb, int bRow0,
    int M, int N, int K,
    float* __restrict__ C, int ldc,
    const void* __restrict__ bias,
    const void* __restrict__ resid,
    const int* __restrict__ flg)
{
    const int isf = flg[12];
    __shared__ float As[16][132];
    __shared__ float Bs[16][132];
    const int tid = threadIdx.x;
    const int row0 = blockIdx.y * 128, col0 = blockIdx.x * 128;
    const int tx = tid & 15, ty = tid >> 4;
    float acc[8][8];
    #pragma unroll
    for (int i = 0; i < 8; i++)
        #pragma unroll
        for (int j = 0; j < 8; j++) acc[i][j] = 0.f;

    for (int k0 = 0; k0 < K; k0 += 16) {
        __syncthreads();
        #pragma unroll
        for (int i = 0; i < 2; i++) {
            int lin = tid + i * 256;
            int r = lin >> 2, kc = (lin & 3) * 4;
            float v[4] = {0.f, 0.f, 0.f, 0.f};
            if (row0 + r < M) {
                if (aMode == 1) {
                    ld4(Av, (size_t)(row0 + r) * lda + k0 + kc, isf, v);
                } else {
                    float4 t = *(const float4*)((const float*)Av + (size_t)(row0 + r) * lda + k0 + kc);
                    v[0] = t.x; v[1] = t.y; v[2] = t.z; v[3] = t.w;
                }
            }
            As[kc + 0][r] = v[0]; As[kc + 1][r] = v[1];
            As[kc + 2][r] = v[2]; As[kc + 3][r] = v[3];
        }
        {
            int kc = tid >> 4, c8 = (tid & 15) * 8;
            float w[8];
            ld8(Bv, (size_t)(bRow0 + k0 + kc) * ldb + col0 + c8, isf, w);
            #pragma unroll
            for (int j = 0; j < 8; j++) Bs[kc][c8 + j] = w[j];
        }
        __syncthreads();
        #pragma unroll
        for (int kk = 0; kk < 16; kk++) {
            float a[8], b[8];
            *(float4*)&a[0] = *(const float4*)&As[kk][ty * 8];
            *(float4*)&a[4] = *(const float4*)&As[kk][ty * 8 + 4];
            *(float4*)&b[0] = *(const float4*)&Bs[kk][tx * 8];
            *(float4*)&b[4] = *(const float4*)&Bs[kk][tx * 8 + 4];
            #pragma unroll
            for (int i = 0; i < 8; i++)
                #pragma unroll
                for (int j = 0; j < 8; j++) acc[i][j] = fmaf(a[i], b[j], acc[i][j]);
        }
    }
    #pragma unroll
    for (int i = 0; i < 8; i++) {
        int gr = row0 + ty * 8 + i;
        if (gr >= M) continue;
        #pragma unroll
        for (int j = 0; j < 8; j++) {
            int gc = col0 + tx * 8 + j;
            float v = acc[i][j];
            if (mode == GM_PROJ)
                v += lmix(bias, gc, isf) + lmix(resid, (size_t)gr * ldc + gc, isf);
            C[(size_t)gr * ldc + gc] = v;
        }
    }
}

// ---------------------------------------------------------------------------
// attn_mfma: split-bf16 MFMA flash attention (fat path).
// Block = (b_local, h, qtile of 64); 4 waves, wave owns 16 q rows.
// ---------------------------------------------------------------------------
__global__ __launch_bounds__(256) void attn_mfma_kernel(
    const float* __restrict__ qkv, float* __restrict__ o)
{
    const int bx = blockIdx.x;
    const int b  = bx >> 6;
    const int hh = (bx >> 2) & 15;
    const int qt = bx & 3;
    const int tid = threadIdx.x;
    const int wave = tid >> 6, lane = tid & 63;
    const int ln = lane & 15, quad = lane >> 4;

    __shared__ __align__(16) u16 Sh[64][264];
    __shared__ __align__(16) u16 Sl[64][264];
    __shared__ __align__(16) u16 KVh[64][72];
    __shared__ __align__(16) u16 KVl[64][72];
    __shared__ float mred[64][4];
    __shared__ float lred[64][4];
    __shared__ float lsh[64];

    const size_t tokbase = (size_t)b * 256;

    // ---- Q fragments in registers (hi/lo); q row = qt*64 + wave*16 + ln ----
    bf16x8 qh[2], ql[2];
    {
        const float* qp = qkv + (tokbase + qt * 64 + wave * 16 + ln) * 3072 + hh * 64;
        #pragma unroll
        for (int ks = 0; ks < 2; ks++) {
            float4 f0 = *(const float4*)(qp + ks * 32 + quad * 8);
            float4 f1 = *(const float4*)(qp + ks * 32 + quad * 8 + 4);
            float fv[8] = {f0.x, f0.y, f0.z, f0.w, f1.x, f1.y, f1.z, f1.w};
            union { uint4 u; bf16x8 v; } ch, cl;
            u32 hw[4], lw[4];
            #pragma unroll
            for (int j = 0; j < 4; j++) {
                u16 h0 = f2b(fv[2 * j]),      h1 = f2b(fv[2 * j + 1]);
                u16 l0 = f2b(fv[2 * j] - b2f(h0));
                u16 l1 = f2b(fv[2 * j + 1] - b2f(h1));
                hw[j] = (u32)h0 | ((u32)h1 << 16);
                lw[j] = (u32)l0 | ((u32)l1 << 16);
            }
            ch.u.x = hw[0]; ch.u.y = hw[1]; ch.u.z = hw[2]; ch.u.w = hw[3];
            cl.u.x = lw[0]; cl.u.y = lw[1]; cl.u.z = lw[2]; cl.u.w = lw[3];
            qh[ks] = ch.v; ql[ks] = cl.v;
        }
    }

    // ---- Phase 1: S = (Q K^T) * scale, written to LDS as hi/lo ----
    const int skey = tid >> 2, sds = (tid & 3) * 16;     // K staging coords
    float4 kpre[4];
    {
        const float* kp = qkv + (tokbase + skey) * 3072 + 1024 + hh * 64 + sds;
        #pragma unroll
        for (int i = 0; i < 4; i++) kpre[i] = *(const float4*)(kp + i * 4);
    }
    for (int kt = 0; kt < 4; kt++) {
        __syncthreads();
        #pragma unroll
        for (int i = 0; i < 4; i++) {
            float fv[4] = {kpre[i].x, kpre[i].y, kpre[i].z, kpre[i].w};
            u16 hv[4], lv[4];
            #pragma unroll
            for (int j = 0; j < 4; j++) {
                hv[j] = f2b(fv[j]);
                lv[j] = f2b(fv[j] - b2f(hv[j]));
            }
            uint2 uh, ul;
            uh.x = (u32)hv[0] | ((u32)hv[1] << 16);
            uh.y = (u32)hv[2] | ((u32)hv[3] << 16);
            ul.x = (u32)lv[0] | ((u32)lv[1] << 16);
            ul.y = (u32)lv[2] | ((u32)lv[3] << 16);
            *(uint2*)&KVh[skey][sds + i * 4] = uh;
            *(uint2*)&KVl[skey][sds + i * 4] = ul;
        }
        __syncthreads();
        if (kt < 3) {
            const float* kp = qkv + (tokbase + (kt + 1) * 64 + skey) * 3072 + 1024 + hh * 64 + sds;
            #pragma unroll
            for (int i = 0; i < 4; i++) kpre[i] = *(const float4*)(kp + i * 4);
        }
        floatx4 acc[4];
        #pragma unroll
        for (int nt = 0; nt < 4; nt++) acc[nt] = (floatx4){0.f, 0.f, 0.f, 0.f};
        #pragma unroll
        for (int ks = 0; ks < 2; ks++) {
            bf16x8 kh[4], kl[4];
            #pragma unroll
            for (int nt = 0; nt < 4; nt++) {
                kh[nt] = *(const bf16x8*)&KVh[nt * 16 + ln][ks * 32 + quad * 8];
                kl[nt] = *(const bf16x8*)&KVl[nt * 16 + ln][ks * 32 + quad * 8];
            }
            #pragma unroll
            for (int nt = 0; nt < 4; nt++)
                acc[nt] = __builtin_amdgcn_mfma_f32_16x16x32_bf16(qh[ks], kh[nt], acc[nt], 0, 0, 0);
            #pragma unroll
            for (int nt = 0; nt < 4; nt++)
                acc[nt] = __builtin_amdgcn_mfma_f32_16x16x32_bf16(qh[ks], kl[nt], acc[nt], 0, 0, 0);
            #pragma unroll
            for (int nt = 0; nt < 4; nt++)
                acc[nt] = __builtin_amdgcn_mfma_f32_16x16x32_bf16(ql[ks], kh[nt], acc[nt], 0, 0, 0);
        }
        #pragma unroll
        for (int nt = 0; nt < 4; nt++) {
            #pragma unroll
            for (int r = 0; r < 4; r++) {
                float s = acc[nt][r] * 0.125f;
                u16 hi = f2b(s);
                Sh[wave * 16 + quad * 4 + r][kt * 64 + nt * 16 + ln] = hi;
                Sl[wave * 16 + quad * 4 + r][kt * 64 + nt * 16 + ln] = f2b(s - b2f(hi));
            }
        }
    }

    // ---- Phase 2: softmax (exact row max; P written back hi/lo) ----
    __syncthreads();
    {
        const int q = tid >> 2, seg = tid & 3;
        float mx = -1e30f;
        #pragma unroll
        for (int i = 0; i < 8; i++) {
            uint4 h4 = *(const uint4*)&Sh[q][seg * 64 + i * 8];
            uint4 l4 = *(const uint4*)&Sl[q][seg * 64 + i * 8];
            mx = fmaxf(mx, fmaxf(b2f(h4.x) + b2f(l4.x), b2f(h4.x >> 16) + b2f(l4.x >> 16)));
            mx = fmaxf(mx, fmaxf(b2f(h4.y) + b2f(l4.y), b2f(h4.y >> 16) + b2f(l4.y >> 16)));
            mx = fmaxf(mx, fmaxf(b2f(h4.z) + b2f(l4.z), b2f(h4.z >> 16) + b2f(l4.z >> 16)));
            mx = fmaxf(mx, fmaxf(b2f(h4.w) + b2f(l4.w), b2f(h4.w >> 16) + b2f(l4.w >> 16)));
        }
        mred[q][seg] = mx;
        __syncthreads();
        float m = fmaxf(fmaxf(mred[q][0], mred[q][1]), fmaxf(mred[q][2], mred[q][3]));
        float sum = 0.f;
        #pragma unroll
        for (int i = 0; i < 8; i++) {
            uint4 h4 = *(const uint4*)&Sh[q][seg * 64 + i * 8];
            uint4 l4 = *(const uint4*)&Sl[q][seg * 64 + i * 8];
            u32 hw[4] = {h4.x, h4.y, h4.z, h4.w};
            u32 lw[4] = {l4.x, l4.y, l4.z, l4.w};
            uint4 oh, ol;
            u32* ohp = (u32*)&oh; u32* olp = (u32*)&ol;
            #pragma unroll
            for (int j = 0; j < 4; j++) {
                float p0 = __expf(b2f(hw[j]) + b2f(lw[j]) - m);
                float p1 = __expf(b2f(hw[j] >> 16) + b2f(lw[j] >> 16) - m);
                sum += p0 + p1;
                u16 ph0 = f2b(p0), ph1 = f2b(p1);
                u16 pl0 = f2b(p0 - b2f(ph0)), pl1 = f2b(p1 - b2f(ph1));
                ohp[j] = (u32)ph0 | ((u32)ph1 << 16);
                olp[j] = (u32)pl0 | ((u32)pl1 << 16);
            }
            *(uint4*)&Sh[q][seg * 64 + i * 8] = oh;
            *(uint4*)&Sl[q][seg * 64 + i * 8] = ol;
        }
        lred[q][seg] = sum;
        __syncthreads();
        if (seg == 0)
            lsh[q] = (lred[q][0] + lred[q][1]) + (lred[q][2] + lred[q][3]);
    }

    // ---- Phase 3: O = P V (V staged transposed [d][key], hi/lo) ----
    const int vd = tid & 63, vk0 = (tid >> 6) * 16;      // V staging coords
    float vpre[16];
    {
        const float* vp = qkv + (tokbase + vk0) * 3072 + 2048 + hh * 64 + vd;
        #pragma unroll
        for (int j = 0; j < 16; j++) vpre[j] = vp[(size_t)j * 3072];
    }
    floatx4 pacc[4];
    #pragma unroll
    for (int nt = 0; nt < 4; nt++) pacc[nt] = (floatx4){0.f, 0.f, 0.f, 0.f};
    for (int kt = 0; kt < 4; kt++) {
        __syncthreads();
        #pragma unroll
        for (int w = 0; w < 4; w++) {
            u16 hv[4], lv[4];
            #pragma unroll
            for (int j = 0; j < 4; j++) {
                float f = vpre[w * 4 + j];
                hv[j] = f2b(f);
                lv[j] = f2b(f - b2f(hv[j]));
            }
            uint2 uh, ul;
            uh.x = (u32)hv[0] | ((u32)hv[1] << 16);
            uh.y = (u32)hv[2] | ((u32)hv[3] << 16);
            ul.x = (u32)lv[0] | ((u32)lv[1] << 16);
            ul.y = (u32)lv[2] | ((u32)lv[3] << 16);
            *(uint2*)&KVh[vd][vk0 + w * 4] = uh;
            *(uint2*)&KVl[vd][vk0 + w * 4] = ul;
        }
        __syncthreads();
        if (kt < 3) {
            const float* vp = qkv + (tokbase + (kt + 1) * 64 + vk0) * 3072 + 2048 + hh * 64 + vd;
            #pragma unroll
            for (int j = 0; j < 16; j++) vpre[j] = vp[(size_t)j * 3072];
        }
        #pragma unroll
        for (int ks = 0; ks < 2; ks++) {
            const int kc = kt * 64 + ks * 32 + quad * 8;
            bf16x8 ph = *(const bf16x8*)&Sh[wave * 16 + ln][kc];
            bf16x8 pl = *(const bf16x8*)&Sl[wave * 16 + ln][kc];
            bf16x8 vh[4], vl[4];
            #pragma unroll
            for (int nt = 0; nt < 4; nt++) {
                vh[nt] = *(const bf16x8*)&KVh[nt * 16 + ln][ks * 32 + quad * 8];
                vl[nt] = *(const bf16x8*)&KVl[nt * 16 + ln][ks * 32 + quad * 8];
            }
            #pragma unroll
            for (int nt = 0; nt < 4; nt++)
                pacc[nt] = __builtin_amdgcn_mfma_f32_16x16x32_bf16(ph, vh[nt], pacc[nt], 0, 0, 0);
            #pragma unroll
            for (int nt = 0; nt < 4; nt++)
                pacc[nt] = __builtin_amdgcn_mfma_f32_16x16x32_bf16(ph, vl[nt], pacc[nt], 0, 0, 0);
            #pragma unroll
            for (int nt = 0; nt < 4; nt++)
                pacc[nt] = __builtin_amdgcn_mfma_f32_16x16x32_bf16(pl, vh[nt], pacc[nt], 0, 0, 0);
        }
    }
    // ---- Epilogue ----
    {
        float linv[4];
        #pragma unroll
        for (int r = 0; r < 4; r++)
            linv[r] = 1.0f / lsh[wave * 16 + quad * 4 + r];
        #pragma unroll
        for (int nt = 0; nt < 4; nt++) {
            #pragma unroll
            for (int r = 0; r < 4; r++) {
                int row = wave * 16 + quad * 4 + r;
                o[(tokbase + qt * 64 + row) * 1024 + hh * 64 + nt * 16 + ln] =
                    pacc[nt][r] * linv[r];
            }
        }
    }
}

// ---------------------------------------------------------------------------
// Fallback attention (fp32 VALU). Block = (b, h, qtile of 64).
// ---------------------------------------------------------------------------
__global__ __launch_bounds__(256) void attn_kernel(
    const float* __restrict__ qkv, float* __restrict__ o)
{
    const int bx = blockIdx.x;
    const int b  = bx >> 6;
    const int hh = (bx >> 2) & 15;
    const int qt = bx & 3;
    const int tid = threadIdx.x;
    const int wave = tid >> 6, lane = tid & 63;

    __shared__ float sh[2 * 64 * 68];
    float* Ks = sh;
    float* Vs = sh + 64 * 68;

    const int q = qt * 64 + lane;
    float qreg[64];
    const float* qp = qkv + (size_t)(b * 256 + q) * 3072 + hh * 64;
    #pragma unroll
    for (int i = 0; i < 16; i++) *(float4*)&qreg[i * 4] = *(const float4*)(qp + i * 4);

    float oa[64];
    #pragma unroll
    for (int d = 0; d < 64; d++) oa[d] = 0.f;
    float m = -1e30f, l = 0.f;

    for (int s = 0; s < 4; s++) {
        __syncthreads();
        {
            int r = tid >> 2;
            int c = (tid & 3) * 16;
            int key = (r >> 4) * 64 + s * 16 + (r & 15);
            const float* kp = qkv + (size_t)(b * 256 + key) * 3072 + 1024 + hh * 64 + c;
            #pragma unroll
            for (int i = 0; i < 4; i++) {
                *(float4*)&Ks[r * 68 + c + i * 4] = *(const float4*)(kp + i * 4);
                *(float4*)&Vs[r * 68 + c + i * 4] = *(const float4*)(kp + 1024 + i * 4);
            }
        }
        __syncthreads();
        const float* Kw = Ks + wave * 16 * 68;
        const float* Vw = Vs + wave * 16 * 68;
        for (int jj = 0; jj < 16; jj++) {
            float s0 = 0.f, s1 = 0.f, s2 = 0.f, s3 = 0.f;
            #pragma unroll
            for (int d = 0; d < 64; d += 4) {
                s0 = fmaf(qreg[d + 0], Kw[jj * 68 + d + 0], s0);
                s1 = fmaf(qreg[d + 1], Kw[jj * 68 + d + 1], s1);
                s2 = fmaf(qreg[d + 2], Kw[jj * 68 + d + 2], s2);
                s3 = fmaf(qreg[d + 3], Kw[jj * 68 + d + 3], s3);
            }
            float sc = ((s0 + s1) + (s2 + s3)) * 0.125f;
            float mn = fmaxf(m, sc);
            float c = __expf(m - mn);
            float p = __expf(sc - mn);
            l = l * c + p;
            #pragma unroll
            for (int d = 0; d < 64; d++)
                oa[d] = fmaf(oa[d], c, p * Vw[jj * 68 + d]);
            m = mn;
        }
    }

    __syncthreads();
    if (wave == 1 || wave == 3) {
        float* dst = sh + (wave >> 1) * (64 * 66) + lane * 66;
        #pragma unroll
        for (int d = 0; d < 64; d++) dst[d] = oa[d];
        dst[64] = m; dst[65] = l;
    }
    __syncthreads();
    if (wave == 0 || wave == 2) {
        const float* src = sh + (wave >> 1) * (64 * 66) + lane * 66;
        float m2 = src[64], l2 = src[65];
        float M = fmaxf(m, m2);
        float c1 = __expf(m - M), c2 = __expf(m2 - M);
        l = l * c1 + l2 * c2;
        #pragma unroll
        for (int d = 0; d < 64; d++) oa[d] = oa[d] * c1 + src[d] * c2;
        m = M;
    }
    __syncthreads();
    if (wave == 2) {
        float* dst = sh + lane * 66;
        #pragma unroll
        for (int d = 0; d < 64; d++) dst[d] = oa[d];
        dst[64] = m; dst[65] = l;
    }
    __syncthreads();
    if (wave == 0) {
        const float* src = sh + lane * 66;
        float m2 = src[64], l2 = src[65];
        float M = fmaxf(m, m2);
        float c1 = __expf(m - M), c2 = __expf(m2 - M);
        l = l * c1 + l2 * c2;
        #pragma unroll
        for (int d = 0; d < 64; d++) oa[d] = oa[d] * c1 + src[d] * c2;
        float inv = 1.0f / l;
        float* op = o + (size_t)(b * 256 + q) * 1024 + hh * 64;
        #pragma unroll
        for (int i = 0; i < 16; i++) {
            float4 v = { oa[i * 4] * inv, oa[i * 4 + 1] * inv,
                         oa[i * 4 + 2] * inv, oa[i * 4 + 3] * inv };
            *(float4*)(op + i * 4) = v;
        }
    }
}

// ---------------------------------------------------------------------------
__global__ __launch_bounds__(256) void router_kernel(
    const float* __restrict__ hr, const void* __restrict__ w2,
    const void* __restrict__ b2, int* __restrict__ t2i,
    float* __restrict__ t2w, int* __restrict__ cb, int rowbase,
    const int* __restrict__ flg)
{
    const int isf = flg[12];
    const int lt = blockIdx.x * 4 + (threadIdx.x >> 6);
    const int t = rowbase + lt;
    const int lane = threadIdx.x & 63;
    float a0 = 0.f, a1 = 0.f, a2 = 0.f, a3 = 0.f;
    const float* hp = hr + (size_t)lt * 2048;
    for (int j = lane; j < 2048; j += 64) {
        float hv = hp[j];
        float w[4];
        ld4(w2, (size_t)j * 4, isf, w);
        a0 = fmaf(hv, w[0], a0);
        a1 = fmaf(hv, w[1], a1);
        a2 = fmaf(hv, w[2], a2);
        a3 = fmaf(hv, w[3], a3);
    }
    #pragma unroll
    for (int off = 32; off > 0; off >>= 1) {
        a0 += __shfl_down(a0, off, 64);
        a1 += __shfl_down(a1, off, 64);
        a2 += __shfl_down(a2, off, 64);
        a3 += __shfl_down(a3, off, 64);
    }
    if (lane == 0) {
        float l[4];
        l[0] = a0 + lmix(b2, 0, isf); l[1] = a1 + lmix(b2, 1, isf);
        l[2] = a2 + lmix(b2, 2, isf); l[3] = a3 + lmix(b2, 3, isf);
        int i0 = 0;
        #pragma unroll
        for (int i = 1; i < 4; i++) if (l[i] > l[i0]) i0 = i;
        int i1 = (i0 == 0) ? 1 : 0;
        #pragma unroll
        for (int i = 0; i < 4; i++) if (i != i0 && l[i] > l[i1]) i1 = i;
        float mx = fmaxf(fmaxf(l[0], l[1]), fmaxf(l[2], l[3]));
        float e0 = __expf(l[0] - mx), e1 = __expf(l[1] - mx);
        float e2 = __expf(l[2] - mx), e3 = __expf(l[3] - mx);
        float inv = 1.0f / (e0 + e1 + e2 + e3);
        float p[4] = { e0 * inv, e1 * inv, e2 * inv, e3 * inv };
        float b0 = fminf(fmaxf(p[i0], 1e-9f), 1.0f - 1e-9f);
        float b1 = fminf(fmaxf(p[i1], 1e-9f), 1.0f - 1e-9f);
        float winv = 1.0f / (b0 + b1);
        t2i[2 * t] = i0; t2i[2 * t + 1] = i1;
        t2w[2 * t] = b0 * winv; t2w[2 * t + 1] = b1 * winv;
        atomicAdd(&cb[i0], 1);
        atomicAdd(&cb[i1], 1);
    }
}

// ---------------------------------------------------------------------------
// fill2: deterministic token->slot assignment via LDS scan; no contended
// atomics; writes cb[4+e].
// ---------------------------------------------------------------------------
__global__ __launch_bounds__(256) void fill2_kernel(
    const int* __restrict__ t2i, const float* __restrict__ t2w,
    int* __restrict__ cb, int* __restrict__ tok,
    float* __restrict__ aw, int* __restrict__ apos)
{
    const int e = blockIdx.x;
    const int tid = threadIdx.x;
    __shared__ int scan[256];
    int base = 0;
    #pragma unroll
    for (int i = 0; i < 4; i++) if (i < e) base += cb[i];
    const int t0 = tid * 32;
    int cnt = 0;
    for (int t = t0; t < t0 + 32; t++)
        cnt += (t2i[2 * t] == e) + (t2i[2 * t + 1] == e);
    scan[tid] = cnt;
    __syncthreads();
    for (int off = 1; off < 256; off <<= 1) {
        int add = (tid >= off) ? scan[tid - off] : 0;
        __syncthreads();
        scan[tid] += add;
        __syncthreads();
    }
    int pos = base + scan[tid] - cnt;   // exclusive prefix within expert
    for (int t = t0; t < t0 + 32; t++) {
        #pragma unroll
        for (int j = 0; j < 2; j++) {
            if (t2i[2 * t + j] == e) {
                tok[pos] = t;
                aw[pos] = t2w[2 * t + j];
                apos[2 * t + j] = pos;
                pos++;
            }
        }
    }
    if (tid == 0) cb[4 + e] = base;
}

// ---------------------------------------------------------------------------
// Fallback MoE GEMM (R7): 64x64 tile, in-loop LN + f2b.
// ---------------------------------------------------------------------------
#define EM_FC1 0
#define EM_FC2 1

__global__ __launch_bounds__(256) void gemm_mfma(
    int mode,
    const float* __restrict__ x1,
    const float* __restrict__ mu, const float* __restrict__ rs,
    const void* __restrict__ lng, const void* __restrict__ lnb,
    const u16* __restrict__ Ab,
    const void* __restrict__ B, size_t bOff, int ldb, int K,
    u16* __restrict__ C, int ldc,
    const void* __restrict__ bias, size_t biasOff,
    const float* __restrict__ rowscale,
    const int* __restrict__ toklist,
    const int* __restrict__ cb, int e, int rowOff,
    const int* __restrict__ flg)
{
    const int isf = flg[12];
    const int Meff = cb[e];
    const int gbase = cb[4 + e];
    const int rg0 = rowOff + blockIdx.y * 64;
    if (rg0 >= Meff) return;
    const int col0 = blockIdx.x * 64;
    __shared__ __align__(16) u16 As[64][72];
    __shared__ __align__(16) u16 Bs[64][72];
    const int tid = threadIdx.x;
    const int wave = tid >> 6, lane = tid & 63;
    const int ln = lane & 15, quad = lane >> 4;
    floatx4 acc[4];
    #pragma unroll
    for (int nt = 0; nt < 4; nt++) acc[nt] = (floatx4){0.f, 0.f, 0.f, 0.f};

    const int ar = tid >> 2, ac = (tid & 3) * 8;
    const int bk = tid >> 3, bn = (tid & 7) * 8;
    const int rg = rg0 + ar;
    const bool valid = (rg < Meff);
    int tokid = 0; float lm = 0.f, lr = 0.f;
    if (mode == EM_FC1 && valid) {
        tokid = toklist[gbase + rg];
        lm = mu[tokid]; lr = rs[tokid];
    }

    for (int k0 = 0; k0 < K; k0 += 32) {
        __syncthreads();
        if (mode == EM_FC1) {
            uint4 packed = {0u, 0u, 0u, 0u};
            if (valid) {
                float4 p0 = *(const float4*)(x1 + (size_t)tokid * 1024 + k0 + ac);
                float4 p1 = *(const float4*)(x1 + (size_t)tokid * 1024 + k0 + ac + 4);
                float pv[8] = {p0.x, p0.y, p0.z, p0.w, p1.x, p1.y, p1.z, p1.w};
                float gg[8], bb[8];
                ld8(lng, k0 + ac, isf, gg);
                ld8(lnb, k0 + ac, isf, bb);
                u16 wb[8];
                #pragma unroll
                for (int z = 0; z < 8; z++)
                    wb[z] = f2b((pv[z] - lm) * lr * gg[z] + bb[z]);
                packed.x = (u32)wb[0] | ((u32)wb[1] << 16);
                packed.y = (u32)wb[2] | ((u32)wb[3] << 16);
                packed.z = (u32)wb[4] | ((u32)wb[5] << 16);
                packed.w = (u32)wb[6] | ((u32)wb[7] << 16);
            }
            *(uint4*)&As[ar][ac] = packed;
        } else {
            uint4 av = {0u, 0u, 0u, 0u};
            if (valid) av = *(const uint4*)(Ab + (size_t)(rg - rowOff) * K + k0 + ac);
            *(uint4*)&As[ar][ac] = av;
        }
        u16 u[8];
        {
            float w[8];
            ld8(B, bOff + (size_t)(k0 + bk) * ldb + col0 + bn, isf, w);
            #pragma unroll
            for (int z = 0; z < 8; z++) u[z] = f2b(w[z]);
        }
        #pragma unroll
        for (int jj = 0; jj < 8; jj++) {
            int j = (jj + (tid & 7)) & 7;
            Bs[bn + j][bk] = u[j];
        }
        __syncthreads();
        bf16x8 af = *(const bf16x8*)&As[wave * 16 + ln][quad * 8];
        #pragma unroll
        for (int nt = 0; nt < 4; nt++) {
            bf16x8 bf = *(const bf16x8*)&Bs[nt * 16 + ln][quad * 8];
            acc[nt] = __builtin_amdgcn_mfma_f32_16x16x32_bf16(af, bf, acc[nt], 0, 0, 0);
        }
    }
    #pragma unroll
    for (int nt = 0; nt < 4; nt++) {
        #pragma unroll
        for (int r = 0; r < 4; r++) {
            int gw = rg0 + wave * 16 + quad * 4 + r;
            if (gw >= Meff) continue;
            int gcol = col0 + nt * 16 + ln;
            float v = acc[nt][r] + lmix(bias, biasOff + gcol, isf);
            if (mode == EM_FC1) {
                C[(size_t)(gw - rowOff) * ldc + gcol] = f2b(gelu_f(v));
            } else {
                v *= rowscale[gbase + gw];
                C[(size_t)(gbase + gw) * ldc + gcol] = f2b(v);
            }
        }
    }
}

// ---------------------------------------------------------------------------
__global__ __launch_bounds__(256) void combine_kernel(
    const float* __restrict__ x1, const u16* __restrict__ eo,
    const int* __restrict__ apos, void* __restrict__ outv,
    const int* __restrict__ flg)
{
    const int isf = flg[12];
    int t = blockIdx.x;
    int c = threadIdx.x * 4;
    int p0 = apos[2 * t], p1 = apos[2 * t + 1];
    float4 xv = *(const float4*)(x1 + (size_t)t * 1024 + c);
    uint2 ea = *(const uint2*)(eo + (size_t)p0 * 1024 + c);
    uint2 eb = *(const uint2*)(eo + (size_t)p1 * 1024 + c);
    float r0 = xv.x + b2f(ea.x) + b2f(eb.x);
    float r1 = xv.y + b2f(ea.x >> 16) + b2f(eb.x >> 16);
    float r2 = xv.z + b2f(ea.y) + b2f(eb.y);
    float r3 = xv.w + b2f(ea.y >> 16) + b2f(eb.y >> 16);
    if (isf) {
        float4 res = {r0, r1, r2, r3};
        *(float4*)((float*)outv + (size_t)t * 1024 + c) = res;
    } else {
        uint2 res;
        res.x = (u32)f2b(r0) | ((u32)f2b(r1) << 16);
        res.y = (u32)f2b(r2) | ((u32)f2b(r3) << 16);
        *(uint2*)((u16*)outv + (size_t)t * 1024 + c) = res;
    }
}

// ---------------------------------------------------------------------------
extern "C" void kernel_launch(void* const* d_in, const int* in_sizes, int n_in,
                              void* d_out, int out_size, void* d_ws, size_t ws_size,
                              hipStream_t stream)
{
    const void* x      = d_in[0];
    const void* cond   = d_in[1];
    const void* ln1_g  = d_in[2];
    const void* ln1_b  = d_in[3];
    const void* qkv_w  = d_in[4];
    const void* proj_w = d_in[5];
    const void* proj_b = d_in[6];
    const void* ln2_g  = d_in[7];
    const void* ln2_b  = d_in[8];
    const void* rf1w   = d_in[9];
    const void* rf1b   = d_in[10];
    const void* rf2w   = d_in[11];
    const void* rf2b   = d_in[12];
    const void* ew1    = d_in[13];
    const void* eb1    = d_in[14];
    const void* ew2    = d_in[15];
    const void* eb2    = d_in[16];
    (void)in_sizes; (void)n_in; (void)out_size;

    char* ws = (char*)d_ws;
    const size_t MB = 1024 * 1024;
    const bool fat = ws_size >= (size_t)116 * MB;

    // [0,32M): x1 after proj. Attn phase (fat): qkvt [0,12), hpk [12,28).
    float* x1   = (float*)(ws);
    u16*   qkvt = (u16*)(ws);
    u16*   hpk  = (u16*)(ws + 12 * MB);
    float* qkvcFb = (float*)(ws + 16 * MB);   // fallback: 1024 rows
    // [32,64M): ob (attn out) -> rf1t [32,40) + h2t [40,56) (router) -> eo (MoE).
    char*  B1   = ws + 32 * MB;
    float* ob   = (float*)B1;
    u16*   rf1tF= (u16*)B1;                   // fat router: [32,40)
    u16*   h2tF = (u16*)(ws + 40 * MB);       // fat router: [40,56), 4096 rows
    u16*   eo   = (u16*)B1;
    u16*   rf1tB= (u16*)B1;
    // [64,...): fat attn: qkvc 48M at [64,112). fat proj: obp [64,96).
    // fat router: hrc 32M at [64,96). fat MoE: hid [64,80)+ew1t[80,88)+ew2t[88,96).
    char*  R    = ws + 64 * MB;
    float* qkvcF= (float*)R;                  // fat: 4096 rows x 3072 fp32 = 48M
    u16*   h2tB = (u16*)R;
    float* hrcB = (float*)(R + 8 * MB);
    float* hrcF = (float*)R;                  // fat: 4096 x 2048 fp32 = 32M
    u16*   hid  = (u16*)R;
    u16*   obp  = (u16*)R;
    u16*   ew1t = (u16*)(R + 16 * MB);
    u16*   ew2t = (u16*)(R + 24 * MB);
    u16*   pwt  = (u16*)(ws + 96 * MB);
    u16*   h2b  = (u16*)(ws + 96 * MB);
    char*  ST   = ws + (fat ? 112 : 96) * MB;

    size_t so = 0;
    auto salloc = [&](size_t bytes) { size_t o = so; so += (bytes + 255) & ~(size_t)255; return o; };
    float* mu   = (float*)(ST + salloc(8192 * 4));
    float* rs   = (float*)(ST + salloc(8192 * 4));
    float* ct   = (float*)(ST + salloc((size_t)32 * 2048 * 4));
    int*   t2i  = (int*)  (ST + salloc(16384 * 4));
    float* t2w  = (float*)(ST + salloc(16384 * 4));
    int*   cb   = (int*)  (ST + salloc(16 * 4));
    int*   tok  = (int*)  (ST + salloc(16384 * 4));
    float* aw   = (float*)(ST + salloc(16384 * 4));
    int*   apos = (int*)  (ST + salloc(16384 * 4));

    init_kernel<<<1, 256, 0, stream>>>(x, cb);

    // ---- Attention pipeline ----
    pack_wt_kernel<<<dim3(16, 48), 256, 0, stream>>>(qkv_w, 3072, 1024, qkvt, cb);
    if (fat) {
        for (int c = 0; c < 2; c++) {
            const size_t r0 = (size_t)c * 4096;
            pack_ln_kernel<<<4096, 256, 0, stream>>>(
                0, x, r0, ln1_g, ln1_b, nullptr, nullptr, hpk, nullptr, cb);
            gemm_sb<<<dim3(24, 32), 256, 0, stream>>>(
                SB_PLAIN, hpk, qkvt, 1024, qkvcF, 3072, nullptr, nullptr, nullptr, 0, cb);
            attn_mfma_kernel<<<1024, 256, 0, stream>>>(qkvcF, ob + r0 * 1024);
        }
    } else {
        for (int c = 0; c < 8; c++) {
            const size_t r0 = (size_t)c * 1024;
            pack_ln_kernel<<<1024, 256, 0, stream>>>(
                0, x, r0, ln1_g, ln1_b, nullptr, nullptr, hpk, nullptr, cb);
            gemm_sb<<<dim3(24, 8), 256, 0, stream>>>(
                SB_PLAIN, hpk, qkvt, 1024, qkvcFb, 3072, nullptr, nullptr, nullptr, 0, cb);
            attn_kernel<<<256, 256, 0, stream>>>(qkvcFb, ob + r0 * 1024);
        }
    }

    // ---- proj + bias + residual(x) -> x1 ----
    if (fat) {
        pack_sb_rows_kernel<<<8192, 256, 0, stream>>>(ob, obp);
        pack_wt_kernel<<<dim3(16, 16), 256, 0, stream>>>(proj_w, 1024, 1024, pwt, cb);
        gemm_sb<<<dim3(8, 64), 256, 0, stream>>>(
            SB_PROJ, obp, pwt, 1024, x1, 1024, proj_b, nullptr, x, 0, cb);
    } else {
        gemm_f32<<<dim3(8, 64), 256, 0, stream>>>(
            GM_PROJ, 0, (const void*)ob, 1024, proj_w, 1024, 0, 8192, 1024, 1024,
            x1, 1024, proj_b, x, cb);
    }

    // LN2 stats
    ln_stats_kernel<<<8192, 256, 0, stream>>>(x1, mu, rs);

    // cond @ r_fc1_w[1024:2048,:] -> ct [32,2048]
    cond_kernel<<<dim3(32, 32), 256, 0, stream>>>(cond, rf1w, ct, cb);

    // ---- Router fc1 (split-bf16 MFMA) + fc2/top2 ----
    if (fat) {
        pack_wt_kernel<<<dim3(16, 32), 256, 0, stream>>>(rf1w, 2048, 1024, rf1tF, cb);
        for (int rc = 0; rc < 2; rc++) {
            const int rb = rc * 4096;
            pack_ln_kernel<<<4096, 256, 0, stream>>>(
                1, x1, rb, ln2_g, ln2_b, mu, rs, h2tF, h2b, cb);
            gemm_sb<<<dim3(16, 32), 256, 0, stream>>>(
                SB_FC1, h2tF, rf1tF, 1024, hrcF, 2048, rf1b, ct, nullptr, rb, cb);
            router_kernel<<<1024, 256, 0, stream>>>(hrcF, rf2w, rf2b, t2i, t2w, cb, rb, cb);
        }
    } else {
        pack_wt_kernel<<<dim3(16, 32), 256, 0, stream>>>(rf1w, 2048, 1024, rf1tB, cb);
        for (int rc = 0; rc < 4; rc++) {
            const int rb = rc * 2048;
            pack_ln_kernel<<<2048, 256, 0, stream>>>(
                1, x1, rb, ln2_g, ln2_b, mu, rs, h2tB, nullptr, cb);
            gemm_sb<<<dim3(16, 16), 256, 0, stream>>>(
                SB_FC1, h2tB, rf1tB, 1024, hrcB, 2048, rf1b, ct, nullptr, rb, cb);
            router_kernel<<<512, 256, 0, stream>>>(hrcB, rf2w, rf2b, t2i, t2w, cb, rb, cb);
        }
    }
    fill2_kernel<<<4, 256, 0, stream>>>(t2i, t2w, cb, tok, aw, apos);

    // ---- Expert MLPs ----
    if (fat) {
        for (int e = 0; e < 4; e++) {
            pack_wtb_kernel<<<dim3(16, 64), 256, 0, stream>>>(
                ew1, (size_t)e * 1024 * 4096, 4096, 1024, ew1t, cb);
            pack_wtb_kernel<<<dim3(64, 16), 256, 0, stream>>>(
                ew2, (size_t)e * 4096 * 1024, 1024, 4096, ew2t, cb);
            for (int c = 0; c < 4; c++) {
                const int ro = c * 2048;
                gemm_moe<<<dim3(32, 16), 256, 0, stream>>>(
                    MOE_FC1, h2b, ew1t, 1024, hid, 4096,
                    eb1, (size_t)e * 4096, nullptr, tok, cb, e, ro, cb);
                gemm_moe2<<<dim3(16, 16), 256, 0, stream>>>(
                    hid, ew2t, eo, eb2, (size_t)e * 1024, aw, cb, e, ro, cb);
            }
        }
    } else {
        for (int e = 0; e < 4; e++) {
            for (int c = 0; c < 2; c++) {
                const int ro = c * 4096;
                gemm_mfma<<<dim3(64, 64), 256, 0, stream>>>(
                    EM_FC1, x1, mu, rs, ln2_g, ln2_b, nullptr,
                    ew1, (size_t)e * 1024 * 4096, 4096, 1024,
                    hid, 4096, eb1, (size_t)e * 4096, nullptr, tok, cb, e, ro, cb);
                gemm_mfma<<<dim3(16, 64), 256, 0, stream>>>(
                    EM_FC2, nullptr, nullptr, nullptr, nullptr, nullptr, hid,
                    ew2, (size_t)e * 4096 * 1024, 1024, 4096,
                    eo, 1024, eb2, (size_t)e * 1024, aw, tok, cb, e, ro, cb);
            }
        }
    }

    combine_kernel<<<8192, 256, 0, stream>>>(x1, eo, apos, d_out, cb);
}

// Round 10
// 2021.362 us; speedup vs baseline: 1.0628x; 1.0628x over previous
//
#include <hip/hip_runtime.h>

// ---------------------------------------------------------------------------
// MoDeDiT block: LN1 -> QKV -> MHA -> proj(+res) -> LN2-stats -> router MLP
//                -> top2 -> MoE expert MLPs -> combine
//
// R14: router_kernel vectorization. R13 profile: router_kernel 113us x2,
// VALUBusy 2.2%, HBM 1.9% -- latency-bound (scalar 4B loads, 32 serial-ish
// iterations, waves parked in vmcnt stalls). New loop: float4 h loads
// (1KB/wave/iter, 8 unrolled iterations), w2 via cached 16B loads.
// fp32 reassociation only (same class as accepted cond/fc1 changes).
// Everything else identical to R13 (passed, absmax 0.03125).
// ---------------------------------------------------------------------------

typedef unsigned short u16;
typedef unsigned int   u32;

typedef __bf16 bf16x8 __attribute__((ext_vector_type(8)));
typedef float  floatx4 __attribute__((ext_vector_type(4)));

__device__ __forceinline__ float b2f(u32 u) {
    union { float f; u32 i; } v; v.i = (u & 0xffffu) << 16; return v.f;
}
__device__ __forceinline__ u16 f2b(float f) {  // round-nearest-even
    union { float f; u32 i; } v; v.f = f;
    u32 x = v.i;
    u32 r = (x + 0x7fffu + ((x >> 16) & 1u)) >> 16;
    return (u16)r;
}
__device__ __forceinline__ float gelu_f(float x) {
    return 0.5f * x * (1.0f + erff(x * 0.70710678118654752440f));
}
__device__ __forceinline__ float lmix(const void* p, size_t i, int isf) {
    return isf ? ((const float*)p)[i] : b2f(((const u16*)p)[i]);
}
__device__ __forceinline__ void ld8(const void* p, size_t i, int isf, float w[8]) {
    if (isf) {
        const float* q = (const float*)p + i;
        float4 a = *(const float4*)q, b = *(const float4*)(q + 4);
        w[0] = a.x; w[1] = a.y; w[2] = a.z; w[3] = a.w;
        w[4] = b.x; w[5] = b.y; w[6] = b.z; w[7] = b.w;
    } else {
        const u16* q = (const u16*)p + i;
        uint4 r = *(const uint4*)q;
        w[0] = b2f(r.x); w[1] = b2f(r.x >> 16);
        w[2] = b2f(r.y); w[3] = b2f(r.y >> 16);
        w[4] = b2f(r.z); w[5] = b2f(r.z >> 16);
        w[6] = b2f(r.w); w[7] = b2f(r.w >> 16);
    }
}
__device__ __forceinline__ void ld4(const void* p, size_t i, int isf, float w[4]) {
    if (isf) {
        float4 a = *(const float4*)((const float*)p + i);
        w[0] = a.x; w[1] = a.y; w[2] = a.z; w[3] = a.w;
    } else {
        uint2 r = *(const uint2*)((const u16*)p + i);
        w[0] = b2f(r.x); w[1] = b2f(r.x >> 16);
        w[2] = b2f(r.y); w[3] = b2f(r.y >> 16);
    }
}

// ---------------------------------------------------------------------------
__global__ void init_kernel(const void* x0, int* cb) {
    __shared__ int sh[256];
    const int tid = threadIdx.x;
    if (tid < 12) cb[tid] = 0;
    int bad = 0;
    const u16* p = (const u16*)x0;
    for (int i = tid; i < 4096; i += 256) {
        float v = b2f(p[2 * i]);
        float a = fabsf(v);
        if (!(a <= 1e3f) || (v != 0.f && a < 1e-8f)) bad++;
    }
    sh[tid] = bad;
    __syncthreads();
    for (int s = 128; s > 0; s >>= 1) {
        if (tid < s) sh[tid] += sh[tid + s];
        __syncthreads();
    }
    if (tid == 0) cb[12] = (sh[0] > 512) ? 1 : 0;
}

// ---------------------------------------------------------------------------
// cond_kernel: ct[b][col] = sum_k cond[b][k] * W[1024+k][col], fp32.
// ---------------------------------------------------------------------------
__global__ __launch_bounds__(256) void cond_kernel(
    const void* __restrict__ cond, const void* __restrict__ w1,
    float* __restrict__ ct, const int* __restrict__ flg)
{
    const int isf = flg[12];
    const int b = blockIdx.y;
    const int col0 = blockIdx.x * 64;
    const int tid = threadIdx.x;
    const int wave = tid >> 6, lane = tid & 63;
    __shared__ float a[1024];
    __shared__ float part[4][64];
    {
        float v[4];
        ld4(cond, (size_t)b * 1024 + tid * 4, isf, v);
        a[tid * 4 + 0] = v[0]; a[tid * 4 + 1] = v[1];
        a[tid * 4 + 2] = v[2]; a[tid * 4 + 3] = v[3];
    }
    __syncthreads();
    const int col = col0 + lane;
    float s = 0.f;
    const int kbase = wave * 256;
    #pragma unroll 4
    for (int k = 0; k < 256; k++)
        s = fmaf(a[kbase + k], lmix(w1, (size_t)(1024 + kbase + k) * 2048 + col, isf), s);
    part[wave][lane] = s;
    __syncthreads();
    if (wave == 0) {
        float r = (part[0][lane] + part[1][lane]) + (part[2][lane] + part[3][lane]);
        ct[(size_t)b * 2048 + col] = r;
    }
}

// ---------------------------------------------------------------------------
// pack_ln: LN a row of 1024 -> split pack [row][hi|lo]; optionally also a
// plain bf16 copy into hb[global row] (fast-path h2b).
// ---------------------------------------------------------------------------
__global__ __launch_bounds__(256) void pack_ln_kernel(
    int mode, const void* __restrict__ xin, size_t rowbase,
    const void* __restrict__ g, const void* __restrict__ bta,
    const float* __restrict__ mu_g, const float* __restrict__ rs_g,
    u16* __restrict__ hpk, u16* __restrict__ hb, const int* __restrict__ flg)
{
    const int isf = flg[12];
    const int row = blockIdx.x, tid = threadIdx.x;
    float v[4];
    float mu, rsv;
    __shared__ float red[8];
    __shared__ float mu_rs[2];
    if (mode == 0) {
        ld4(xin, (rowbase + row) * 1024 + tid * 4, isf, v);
        float s = v[0] + v[1] + v[2] + v[3];
        float q = v[0] * v[0] + v[1] * v[1] + v[2] * v[2] + v[3] * v[3];
        #pragma unroll
        for (int off = 32; off > 0; off >>= 1) {
            s += __shfl_down(s, off, 64);
            q += __shfl_down(q, off, 64);
        }
        int wid = tid >> 6, lane = tid & 63;
        if (lane == 0) { red[wid] = s; red[4 + wid] = q; }
        __syncthreads();
        if (tid == 0) {
            float ts = red[0] + red[1] + red[2] + red[3];
            float tq = red[4] + red[5] + red[6] + red[7];
            float m = ts * (1.0f / 1024.0f);
            float var = tq * (1.0f / 1024.0f) - m * m;
            float xx = var + 1e-5f;
            float r = rsqrtf(xx);
            r = r * (1.5f - 0.5f * xx * r * r);
            mu_rs[0] = m; mu_rs[1] = r;
        }
        __syncthreads();
        mu = mu_rs[0]; rsv = mu_rs[1];
    } else {
        float4 t = *(const float4*)((const float*)xin + (rowbase + row) * 1024 + tid * 4);
        v[0] = t.x; v[1] = t.y; v[2] = t.z; v[3] = t.w;
        mu = mu_g[rowbase + row]; rsv = rs_g[rowbase + row];
    }
    float gg[4], bb[4];
    ld4(g, tid * 4, isf, gg);
    ld4(bta, tid * 4, isf, bb);
    u16 hi[4], lo[4];
    #pragma unroll
    for (int i = 0; i < 4; i++) {
        float h = (v[i] - mu) * rsv * gg[i] + bb[i];
        hi[i] = f2b(h);
        lo[i] = f2b(h - b2f(hi[i]));
    }
    uint2 ph, pl;
    ph.x = (u32)hi[0] | ((u32)hi[1] << 16);
    ph.y = (u32)hi[2] | ((u32)hi[3] << 16);
    pl.x = (u32)lo[0] | ((u32)lo[1] << 16);
    pl.y = (u32)lo[2] | ((u32)lo[3] << 16);
    *(uint2*)(hpk + (size_t)row * 2048 + tid * 4) = ph;
    *(uint2*)(hpk + (size_t)row * 2048 + 1024 + tid * 4) = pl;
    if (hb) *(uint2*)(hb + (rowbase + row) * 1024 + tid * 4) = ph;
}

// ---------------------------------------------------------------------------
// pack_wt: split W[K][N] (mixed) -> transposed split pack Bt[N][2K].
// ---------------------------------------------------------------------------
__global__ __launch_bounds__(256) void pack_wt_kernel(
    const void* __restrict__ W, int N, int K,
    u16* __restrict__ Bt, const int* __restrict__ flg)
{
    const int isf = flg[12];
    __shared__ float sh[64][65];
    const int k0 = blockIdx.x * 64, n0 = blockIdx.y * 64;
    const int tid = threadIdx.x;
    #pragma unroll
    for (int i = 0; i < 4; i++) {
        int r = (tid >> 4) + i * 16, c = (tid & 15) * 4;
        float w[4];
        ld4(W, (size_t)(k0 + r) * N + n0 + c, isf, w);
        sh[r][c] = w[0]; sh[r][c + 1] = w[1]; sh[r][c + 2] = w[2]; sh[r][c + 3] = w[3];
    }
    __syncthreads();
    const int n = tid >> 2, kc = (tid & 3) * 16;
    u16 hi[16], lo[16];
    #pragma unroll
    for (int j = 0; j < 16; j++) {
        float v = sh[kc + j][n];
        hi[j] = f2b(v);
        lo[j] = f2b(v - b2f(hi[j]));
    }
    u16* dst = Bt + (size_t)(n0 + n) * (2 * K) + k0 + kc;
    uint4 a, b;
    a.x = (u32)hi[0] | ((u32)hi[1] << 16);  a.y = (u32)hi[2] | ((u32)hi[3] << 16);
    a.z = (u32)hi[4] | ((u32)hi[5] << 16);  a.w = (u32)hi[6] | ((u32)hi[7] << 16);
    b.x = (u32)hi[8] | ((u32)hi[9] << 16);  b.y = (u32)hi[10] | ((u32)hi[11] << 16);
    b.z = (u32)hi[12] | ((u32)hi[13] << 16); b.w = (u32)hi[14] | ((u32)hi[15] << 16);
    *(uint4*)dst = a; *(uint4*)(dst + 8) = b;
    a.x = (u32)lo[0] | ((u32)lo[1] << 16);  a.y = (u32)lo[2] | ((u32)lo[3] << 16);
    a.z = (u32)lo[4] | ((u32)lo[5] << 16);  a.w = (u32)lo[6] | ((u32)lo[7] << 16);
    b.x = (u32)lo[8] | ((u32)lo[9] << 16);  b.y = (u32)lo[10] | ((u32)lo[11] << 16);
    b.z = (u32)lo[12] | ((u32)lo[13] << 16); b.w = (u32)lo[14] | ((u32)lo[15] << 16);
    *(uint4*)(dst + K) = a; *(uint4*)(dst + K + 8) = b;
}

// ---------------------------------------------------------------------------
// pack_wtb: plain bf16 transpose pack. W[K][N] (mixed, +wOff elems) -> Bt[N][K].
// ---------------------------------------------------------------------------
__global__ __launch_bounds__(256) void pack_wtb_kernel(
    const void* __restrict__ W, size_t wOff, int N, int K,
    u16* __restrict__ Bt, const int* __restrict__ flg)
{
    const int isf = flg[12];
    __shared__ float sh[64][65];
    const int k0 = blockIdx.x * 64, n0 = blockIdx.y * 64;
    const int tid = threadIdx.x;
    #pragma unroll
    for (int i = 0; i < 4; i++) {
        int r = (tid >> 4) + i * 16, c = (tid & 15) * 4;
        float w[4];
        ld4(W, wOff + (size_t)(k0 + r) * N + n0 + c, isf, w);
        sh[r][c] = w[0]; sh[r][c + 1] = w[1]; sh[r][c + 2] = w[2]; sh[r][c + 3] = w[3];
    }
    __syncthreads();
    const int n = tid >> 2, kc = (tid & 3) * 16;
    u16 hi[16];
    #pragma unroll
    for (int j = 0; j < 16; j++) hi[j] = f2b(sh[kc + j][n]);
    u16* dst = Bt + (size_t)(n0 + n) * K + k0 + kc;
    uint4 a, b;
    a.x = (u32)hi[0] | ((u32)hi[1] << 16);  a.y = (u32)hi[2] | ((u32)hi[3] << 16);
    a.z = (u32)hi[4] | ((u32)hi[5] << 16);  a.w = (u32)hi[6] | ((u32)hi[7] << 16);
    b.x = (u32)hi[8] | ((u32)hi[9] << 16);  b.y = (u32)hi[10] | ((u32)hi[11] << 16);
    b.z = (u32)hi[12] | ((u32)hi[13] << 16); b.w = (u32)hi[14] | ((u32)hi[15] << 16);
    *(uint4*)dst = a; *(uint4*)(dst + 8) = b;
}

// ---------------------------------------------------------------------------
// pack_sb_rows: fp32 [8192][1024] -> split pack [row][hi|lo] (for proj A).
// ---------------------------------------------------------------------------
__global__ __launch_bounds__(256) void pack_sb_rows_kernel(
    const float* __restrict__ src, u16* __restrict__ dst)
{
    const int row = blockIdx.x, tid = threadIdx.x;
    float4 t = *(const float4*)(src + (size_t)row * 1024 + tid * 4);
    float v[4] = {t.x, t.y, t.z, t.w};
    u16 hi[4], lo[4];
    #pragma unroll
    for (int i = 0; i < 4; i++) {
        hi[i] = f2b(v[i]);
        lo[i] = f2b(v[i] - b2f(hi[i]));
    }
    uint2 ph, pl;
    ph.x = (u32)hi[0] | ((u32)hi[1] << 16);
    ph.y = (u32)hi[2] | ((u32)hi[3] << 16);
    pl.x = (u32)lo[0] | ((u32)lo[1] << 16);
    pl.y = (u32)lo[2] | ((u32)lo[3] << 16);
    *(uint2*)(dst + (size_t)row * 2048 + tid * 4) = ph;
    *(uint2*)(dst + (size_t)row * 2048 + 1024 + tid * 4) = pl;
}

// ---------------------------------------------------------------------------
// gemm_sb: split-bf16 3-pass MFMA GEMM. A [M][2K], B [N][2K], C fp32.
// 128x128 tile, 4 waves (2x2) of 64x64, BK=32.
// ---------------------------------------------------------------------------
#define SB_PLAIN 0
#define SB_FC1   1
#define SB_PROJ  2

__global__ __launch_bounds__(256) void gemm_sb(
    int mode,
    const u16* __restrict__ Ap,
    const u16* __restrict__ Bt,
    int K,
    float* __restrict__ C, int ldc,
    const void* __restrict__ bias,
    const float* __restrict__ condt,
    const void* __restrict__ resid,
    int rowbase, const int* __restrict__ flg)
{
    const int isf = flg[12];
    __shared__ __align__(16) u16 Ah[128][40];
    __shared__ __align__(16) u16 Al[128][40];
    __shared__ __align__(16) u16 Bh[128][40];
    __shared__ __align__(16) u16 Bl[128][40];
    const int tid = threadIdx.x;
    const int row0 = blockIdx.y * 128, col0 = blockIdx.x * 128;
    const int wave = tid >> 6, lane = tid & 63;
    const int wm = (wave >> 1) * 64, wn = (wave & 1) * 64;
    const int ln = lane & 15, quad = lane >> 4;
    const size_t K2 = (size_t)2 * K;
    floatx4 acc[4][4];
    #pragma unroll
    for (int i = 0; i < 4; i++)
        #pragma unroll
        for (int j = 0; j < 4; j++) acc[i][j] = (floatx4){0.f, 0.f, 0.f, 0.f};

    const int ar = tid >> 1, ac = (tid & 1) * 16;
    uint4 pa0, pa1, pal0, pal1, pb0, pb1, pbl0, pbl1;

    {
        const u16* ap = Ap + (size_t)(row0 + ar) * K2 + ac;
        pa0 = *(const uint4*)ap;        pa1 = *(const uint4*)(ap + 8);
        pal0 = *(const uint4*)(ap + K); pal1 = *(const uint4*)(ap + K + 8);
        const u16* bp = Bt + (size_t)(col0 + ar) * K2 + ac;
        pb0 = *(const uint4*)bp;        pb1 = *(const uint4*)(bp + 8);
        pbl0 = *(const uint4*)(bp + K); pbl1 = *(const uint4*)(bp + K + 8);
    }

    for (int k0 = 0; k0 < K; k0 += 32) {
        __syncthreads();
        *(uint4*)&Ah[ar][ac] = pa0;  *(uint4*)&Ah[ar][ac + 8] = pa1;
        *(uint4*)&Al[ar][ac] = pal0; *(uint4*)&Al[ar][ac + 8] = pal1;
        *(uint4*)&Bh[ar][ac] = pb0;  *(uint4*)&Bh[ar][ac + 8] = pb1;
        *(uint4*)&Bl[ar][ac] = pbl0; *(uint4*)&Bl[ar][ac + 8] = pbl1;
        __syncthreads();
        if (k0 + 32 < K) {
            const u16* ap = Ap + (size_t)(row0 + ar) * K2 + k0 + 32 + ac;
            pa0 = *(const uint4*)ap;        pa1 = *(const uint4*)(ap + 8);
            pal0 = *(const uint4*)(ap + K); pal1 = *(const uint4*)(ap + K + 8);
            const u16* bp = Bt + (size_t)(col0 + ar) * K2 + k0 + 32 + ac;
            pb0 = *(const uint4*)bp;        pb1 = *(const uint4*)(bp + 8);
            pbl0 = *(const uint4*)(bp + K); pbl1 = *(const uint4*)(bp + K + 8);
        }
        bf16x8 ah[4], al[4];
        #pragma unroll
        for (int mt = 0; mt < 4; mt++) {
            ah[mt] = *(const bf16x8*)&Ah[wm + mt * 16 + ln][quad * 8];
            al[mt] = *(const bf16x8*)&Al[wm + mt * 16 + ln][quad * 8];
        }
        #pragma unroll
        for (int nt = 0; nt < 4; nt++) {
            bf16x8 bh = *(const bf16x8*)&Bh[wn + nt * 16 + ln][quad * 8];
            bf16x8 bl = *(const bf16x8*)&Bl[wn + nt * 16 + ln][quad * 8];
            #pragma unroll
            for (int mt = 0; mt < 4; mt++) {
                acc[mt][nt] = __builtin_amdgcn_mfma_f32_16x16x32_bf16(ah[mt], bh, acc[mt][nt], 0, 0, 0);
                acc[mt][nt] = __builtin_amdgcn_mfma_f32_16x16x32_bf16(ah[mt], bl, acc[mt][nt], 0, 0, 0);
                acc[mt][nt] = __builtin_amdgcn_mfma_f32_16x16x32_bf16(al[mt], bh, acc[mt][nt], 0, 0, 0);
            }
        }
    }
    #pragma unroll
    for (int mt = 0; mt < 4; mt++) {
        #pragma unroll
        for (int nt = 0; nt < 4; nt++) {
            #pragma unroll
            for (int r = 0; r < 4; r++) {
                int row = row0 + wm + mt * 16 + quad * 4 + r;
                int col = col0 + wn + nt * 16 + ln;
                float v = acc[mt][nt][r];
                if (mode == SB_FC1)
                    v = gelu_f(v + lmix(bias, col, isf) +
                               condt[(size_t)((rowbase + row) >> 8) * 2048 + col]);
                else if (mode == SB_PROJ)
                    v += lmix(bias, col, isf) + lmix(resid, (size_t)row * ldc + col, isf);
                C[(size_t)row * ldc + col] = v;
            }
        }
    }
}

// ---------------------------------------------------------------------------
// gemm_moe: plain bf16 MFMA GEMM, 128x128 tile (expert FC1).
// ---------------------------------------------------------------------------
#define MOE_FC1 0
#define MOE_FC2 1

__global__ __launch_bounds__(256) void gemm_moe(
    int mode,
    const u16* __restrict__ Ap,
    const u16* __restrict__ Bt,
    int K,
    u16* __restrict__ C, int ldc,
    const void* __restrict__ bias, size_t biasOff,
    const float* __restrict__ rowscale,
    const int* __restrict__ toklist,
    const int* __restrict__ cb, int e, int rowOff,
    const int* __restrict__ flg)
{
    const int isf = flg[12];
    const int Meff = cb[e];
    const int gbase = cb[4 + e];
    const int rg0 = rowOff + blockIdx.y * 128;
    if (rg0 >= Meff) return;
    const int col0 = blockIdx.x * 128;
    __shared__ __align__(16) u16 As[128][40];
    __shared__ __align__(16) u16 Bs[128][40];
    const int tid = threadIdx.x;
    const int wave = tid >> 6, lane = tid & 63;
    const int wm = (wave >> 1) * 64, wn = (wave & 1) * 64;
    const int ln = lane & 15, quad = lane >> 4;
    floatx4 acc[4][4];
    #pragma unroll
    for (int i = 0; i < 4; i++)
        #pragma unroll
        for (int j = 0; j < 4; j++) acc[i][j] = (floatx4){0.f, 0.f, 0.f, 0.f};

    const int ar = tid >> 1, ac = (tid & 1) * 16;
    const int rg = rg0 + ar;
    const bool valid = (rg < Meff);
    const u16* arow;
    if (mode == MOE_FC1) {
        int tokid = valid ? toklist[gbase + rg] : 0;
        arow = Ap + (size_t)tokid * K;
    } else {
        arow = Ap + (size_t)(rg - rowOff) * K;
    }
    const u16* brow = Bt + (size_t)(col0 + ar) * K;
    uint4 pa0 = {0u,0u,0u,0u}, pa1 = {0u,0u,0u,0u}, pb0, pb1;
    if (valid) { pa0 = *(const uint4*)(arow + ac); pa1 = *(const uint4*)(arow + ac + 8); }
    pb0 = *(const uint4*)(brow + ac); pb1 = *(const uint4*)(brow + ac + 8);

    for (int k0 = 0; k0 < K; k0 += 32) {
        __syncthreads();
        *(uint4*)&As[ar][ac] = pa0; *(uint4*)&As[ar][ac + 8] = pa1;
        *(uint4*)&Bs[ar][ac] = pb0; *(uint4*)&Bs[ar][ac + 8] = pb1;
        __syncthreads();
        if (k0 + 32 < K) {
            if (valid) {
                pa0 = *(const uint4*)(arow + k0 + 32 + ac);
                pa1 = *(const uint4*)(arow + k0 + 32 + ac + 8);
            }
            pb0 = *(const uint4*)(brow + k0 + 32 + ac);
            pb1 = *(const uint4*)(brow + k0 + 32 + ac + 8);
        }
        bf16x8 a[4];
        #pragma unroll
        for (int mt = 0; mt < 4; mt++)
            a[mt] = *(const bf16x8*)&As[wm + mt * 16 + ln][quad * 8];
        #pragma unroll
        for (int nt = 0; nt < 4; nt++) {
            bf16x8 b = *(const bf16x8*)&Bs[wn + nt * 16 + ln][quad * 8];
            #pragma unroll
            for (int mt = 0; mt < 4; mt++)
                acc[mt][nt] = __builtin_amdgcn_mfma_f32_16x16x32_bf16(a[mt], b, acc[mt][nt], 0, 0, 0);
        }
    }
    #pragma unroll
    for (int mt = 0; mt < 4; mt++) {
        #pragma unroll
        for (int nt = 0; nt < 4; nt++) {
            #pragma unroll
            for (int r = 0; r < 4; r++) {
                int gw = rg0 + wm + mt * 16 + quad * 4 + r;
                if (gw >= Meff) continue;
                int col = col0 + wn + nt * 16 + ln;
                float v = acc[mt][nt][r] + lmix(bias, biasOff + col, isf);
                if (mode == MOE_FC1) {
                    C[(size_t)(gw - rowOff) * ldc + col] = f2b(gelu_f(v));
                } else {
                    v *= rowscale[gbase + gw];
                    C[(size_t)(gbase + gw) * ldc + col] = f2b(v);
                }
            }
        }
    }
}

// ---------------------------------------------------------------------------
// gemm_moe2: expert FC2 bf16 MFMA GEMM. 128x64 tile, grid 16x16 = 256 blocks.
// ---------------------------------------------------------------------------
__global__ __launch_bounds__(256) void gemm_moe2(
    const u16* __restrict__ Ap,
    const u16* __restrict__ Bt,
    u16* __restrict__ C,
    const void* __restrict__ bias, size_t biasOff,
    const float* __restrict__ rowscale,
    const int* __restrict__ cb, int e, int rowOff,
    const int* __restrict__ flg)
{
    const int isf = flg[12];
    const int Meff = cb[e];
    const int gbase = cb[4 + e];
    const int rg0 = rowOff + blockIdx.y * 128;
    if (rg0 >= Meff) return;
    const int col0 = blockIdx.x * 64;
    const int K = 4096;
    __shared__ __align__(16) u16 As[128][40];
    __shared__ __align__(16) u16 Bs[64][40];
    const int tid = threadIdx.x;
    const int wave = tid >> 6, lane = tid & 63;
    const int ln = lane & 15, quad = lane >> 4;
    floatx4 acc[2][4];
    #pragma unroll
    for (int i = 0; i < 2; i++)
        #pragma unroll
        for (int j = 0; j < 4; j++) acc[i][j] = (floatx4){0.f, 0.f, 0.f, 0.f};

    const int ar = tid >> 1, ac = (tid & 1) * 16;   // A: 128 rows x 32 k
    const int br = tid >> 2, bc = (tid & 3) * 8;    // B: 64 rows x 32 k
    const int rg = rg0 + ar;
    const bool valid = (rg < Meff);
    const u16* arow = Ap + (size_t)(rg - rowOff) * K;
    const u16* brow = Bt + (size_t)(col0 + br) * K;
    uint4 pa0 = {0u,0u,0u,0u}, pa1 = {0u,0u,0u,0u}, pb;
    if (valid) { pa0 = *(const uint4*)(arow + ac); pa1 = *(const uint4*)(arow + ac + 8); }
    pb = *(const uint4*)(brow + bc);

    for (int k0 = 0; k0 < K; k0 += 32) {
        __syncthreads();
        *(uint4*)&As[ar][ac] = pa0; *(uint4*)&As[ar][ac + 8] = pa1;
        *(uint4*)&Bs[br][bc] = pb;
        __syncthreads();
        if (k0 + 32 < K) {
            if (valid) {
                pa0 = *(const uint4*)(arow + k0 + 32 + ac);
                pa1 = *(const uint4*)(arow + k0 + 32 + ac + 8);
            }
            pb = *(const uint4*)(brow + k0 + 32 + bc);
        }
        bf16x8 a0 = *(const bf16x8*)&As[wave * 32 + ln][quad * 8];
        bf16x8 a1 = *(const bf16x8*)&As[wave * 32 + 16 + ln][quad * 8];
        #pragma unroll
        for (int nt = 0; nt < 4; nt++) {
            bf16x8 b = *(const bf16x8*)&Bs[nt * 16 + ln][quad * 8];
            acc[0][nt] = __builtin_amdgcn_mfma_f32_16x16x32_bf16(a0, b, acc[0][nt], 0, 0, 0);
            acc[1][nt] = __builtin_amdgcn_mfma_f32_16x16x32_bf16(a1, b, acc[1][nt], 0, 0, 0);
        }
    }
    #pragma unroll
    for (int mt = 0; mt < 2; mt++) {
        #pragma unroll
        for (int nt = 0; nt < 4; nt++) {
            #pragma unroll
            for (int r = 0; r < 4; r++) {
                int gw = rg0 + wave * 32 + mt * 16 + quad * 4 + r;
                if (gw >= Meff) continue;
                int col = col0 + nt * 16 + ln;
                float v = acc[mt][nt][r] + lmix(bias, biasOff + col, isf);
                v *= rowscale[gbase + gw];
                C[(size_t)(gbase + gw) * 1024 + col] = f2b(v);
            }
        }
    }
}

// ---------------------------------------------------------------------------
__global__ __launch_bounds__(256) void ln_stats_kernel(
    const float* __restrict__ xin, float* __restrict__ mu, float* __restrict__ rs)
{
    const int row = blockIdx.x, tid = threadIdx.x;
    float4 t = *(const float4*)(xin + (size_t)row * 1024 + tid * 4);
    float s = t.x + t.y + t.z + t.w;
    float q = t.x * t.x + t.y * t.y + t.z * t.z + t.w * t.w;
    #pragma unroll
    for (int off = 32; off > 0; off >>= 1) {
        s += __shfl_down(s, off, 64);
        q += __shfl_down(q, off, 64);
    }
    __shared__ float red[8];
    int wid = tid >> 6, lane = tid & 63;
    if (lane == 0) { red[wid] = s; red[4 + wid] = q; }
    __syncthreads();
    if (tid == 0) {
        float ts = red[0] + red[1] + red[2] + red[3];
        float tq = red[4] + red[5] + red[6] + red[7];
        float m = ts * (1.0f / 1024.0f);
        float var = tq * (1.0f / 1024.0f) - m * m;
        float xx = var + 1e-5f;
        float r = rsqrtf(xx);
        r = r * (1.5f - 0.5f * xx * r * r);
        mu[row] = m; rs[row] = r;
    }
}

// ---------------------------------------------------------------------------
// fp32 VALU GEMM (fallback proj).
// ---------------------------------------------------------------------------
#define GM_PLAIN 0
#define GM_PROJ  1

__global__ __launch_bounds__(256) void gemm_f32(
    int mode, int aMode,
    const void* __restrict__ Av, int lda,
    const void* __restrict__ Bv, int ldb, int bRow0,
    int M, int N, int K,
    float* __restrict__ C, int ldc,
    const void* __restrict__ bias,
    const void* __restrict__ resid,
    const int* __restrict__ flg)
{
    const int isf = flg[12];
    __shared__ float As[16][132];
    __shared__ float Bs[16][132];
    const int tid = threadIdx.x;
    const int row0 = blockIdx.y * 128, col0 = blockIdx.x * 128;
    const int tx = tid & 15, ty = tid >> 4;
    float acc[8][8];
    #pragma unroll
    for (int i = 0; i < 8; i++)
        #pragma unroll
        for (int j = 0; j < 8; j++) acc[i][j] = 0.f;

    for (int k0 = 0; k0 < K; k0 += 16) {
        __syncthreads();
        #pragma unroll
        for (int i = 0; i < 2; i++) {
            int lin = tid + i * 256;
            int r = lin >> 2, kc = (lin & 3) * 4;
            float v[4] = {0.f, 0.f, 0.f, 0.f};
            if (row0 + r < M) {
                if (aMode == 1) {
                    ld4(Av, (size_t)(row0 + r) * lda + k0 + kc, isf, v);
                } else {
                    float4 t = *(const float4*)((const float*)Av + (size_t)(row0 + r) * lda + k0 + kc);
                    v[0] = t.x; v[1] = t.y; v[2] = t.z; v[3] = t.w;
                }
            }
            As[kc + 0][r] = v[0]; As[kc + 1][r] = v[1];
            As[kc + 2][r] = v[2]; As[kc + 3][r] = v[3];
        }
        {
            int kc = tid >> 4, c8 = (tid & 15) * 8;
            float w[8];
            ld8(Bv, (size_t)(bRow0 + k0 + kc) * ldb + col0 + c8, isf, w);
            #pragma unroll
            for (int j = 0; j < 8; j++) Bs[kc][c8 + j] = w[j];
        }
        __syncthreads();
        #pragma unroll
        for (int kk = 0; kk < 16; kk++) {
            float a[8], b[8];
            *(float4*)&a[0] = *(const float4*)&As[kk][ty * 8];
            *(float4*)&a[4] = *(const float4*)&As[kk][ty * 8 + 4];
            *(float4*)&b[0] = *(const float4*)&Bs[kk][tx * 8];
            *(float4*)&b[4] = *(const float4*)&Bs[kk][tx * 8 + 4];
            #pragma unroll
            for (int i = 0; i < 8; i++)
                #pragma unroll
                for (int j = 0; j < 8; j++) acc[i][j] = fmaf(a[i], b[j], acc[i][j]);
        }
    }
    #pragma unroll
    for (int i = 0; i < 8; i++) {
        int gr = row0 + ty * 8 + i;
        if (gr >= M) continue;
        #pragma unroll
        for (int j = 0; j < 8; j++) {
            int gc = col0 + tx * 8 + j;
            float v = acc[i][j];
            if (mode == GM_PROJ)
                v += lmix(bias, gc, isf) + lmix(resid, (size_t)gr * ldc + gc, isf);
            C[(size_t)gr * ldc + gc] = v;
        }
    }
}

// ---------------------------------------------------------------------------
// attn_mfma: split-bf16 MFMA flash attention (fat path).
// Block = (b_local, h, qtile of 64); 4 waves, wave owns 16 q rows.
// ---------------------------------------------------------------------------
__global__ __launch_bounds__(256) void attn_mfma_kernel(
    const float* __restrict__ qkv, float* __restrict__ o)
{
    const int bx = blockIdx.x;
    const int b  = bx >> 6;
    const int hh = (bx >> 2) & 15;
    const int qt = bx & 3;
    const int tid = threadIdx.x;
    const int wave = tid >> 6, lane = tid & 63;
    const int ln = lane & 15, quad = lane >> 4;

    __shared__ __align__(16) u16 Sh[64][264];
    __shared__ __align__(16) u16 Sl[64][264];
    __shared__ __align__(16) u16 KVh[64][72];
    __shared__ __align__(16) u16 KVl[64][72];
    __shared__ float mred[64][4];
    __shared__ float lred[64][4];
    __shared__ float lsh[64];

    const size_t tokbase = (size_t)b * 256;

    // ---- Q fragments in registers (hi/lo); q row = qt*64 + wave*16 + ln ----
    bf16x8 qh[2], ql[2];
    {
        const float* qp = qkv + (tokbase + qt * 64 + wave * 16 + ln) * 3072 + hh * 64;
        #pragma unroll
        for (int ks = 0; ks < 2; ks++) {
            float4 f0 = *(const float4*)(qp + ks * 32 + quad * 8);
            float4 f1 = *(const float4*)(qp + ks * 32 + quad * 8 + 4);
            float fv[8] = {f0.x, f0.y, f0.z, f0.w, f1.x, f1.y, f1.z, f1.w};
            union { uint4 u; bf16x8 v; } ch, cl;
            u32 hw[4], lw[4];
            #pragma unroll
            for (int j = 0; j < 4; j++) {
                u16 h0 = f2b(fv[2 * j]),      h1 = f2b(fv[2 * j + 1]);
                u16 l0 = f2b(fv[2 * j] - b2f(h0));
                u16 l1 = f2b(fv[2 * j + 1] - b2f(h1));
                hw[j] = (u32)h0 | ((u32)h1 << 16);
                lw[j] = (u32)l0 | ((u32)l1 << 16);
            }
            ch.u.x = hw[0]; ch.u.y = hw[1]; ch.u.z = hw[2]; ch.u.w = hw[3];
            cl.u.x = lw[0]; cl.u.y = lw[1]; cl.u.z = lw[2]; cl.u.w = lw[3];
            qh[ks] = ch.v; ql[ks] = cl.v;
        }
    }

    // ---- Phase 1: S = (Q K^T) * scale, written to LDS as hi/lo ----
    const int skey = tid >> 2, sds = (tid & 3) * 16;     // K staging coords
    float4 kpre[4];
    {
        const float* kp = qkv + (tokbase + skey) * 3072 + 1024 + hh * 64 + sds;
        #pragma unroll
        for (int i = 0; i < 4; i++) kpre[i] = *(const float4*)(kp + i * 4);
    }
    for (int kt = 0; kt < 4; kt++) {
        __syncthreads();
        #pragma unroll
        for (int i = 0; i < 4; i++) {
            float fv[4] = {kpre[i].x, kpre[i].y, kpre[i].z, kpre[i].w};
            u16 hv[4], lv[4];
            #pragma unroll
            for (int j = 0; j < 4; j++) {
                hv[j] = f2b(fv[j]);
                lv[j] = f2b(fv[j] - b2f(hv[j]));
            }
            uint2 uh, ul;
            uh.x = (u32)hv[0] | ((u32)hv[1] << 16);
            uh.y = (u32)hv[2] | ((u32)hv[3] << 16);
            ul.x = (u32)lv[0] | ((u32)lv[1] << 16);
            ul.y = (u32)lv[2] | ((u32)lv[3] << 16);
            *(uint2*)&KVh[skey][sds + i * 4] = uh;
            *(uint2*)&KVl[skey][sds + i * 4] = ul;
        }
        __syncthreads();
        if (kt < 3) {
            const float* kp = qkv + (tokbase + (kt + 1) * 64 + skey) * 3072 + 1024 + hh * 64 + sds;
            #pragma unroll
            for (int i = 0; i < 4; i++) kpre[i] = *(const float4*)(kp + i * 4);
        }
        floatx4 acc[4];
        #pragma unroll
        for (int nt = 0; nt < 4; nt++) acc[nt] = (floatx4){0.f, 0.f, 0.f, 0.f};
        #pragma unroll
        for (int ks = 0; ks < 2; ks++) {
            bf16x8 kh[4], kl[4];
            #pragma unroll
            for (int nt = 0; nt < 4; nt++) {
                kh[nt] = *(const bf16x8*)&KVh[nt * 16 + ln][ks * 32 + quad * 8];
                kl[nt] = *(const bf16x8*)&KVl[nt * 16 + ln][ks * 32 + quad * 8];
            }
            #pragma unroll
            for (int nt = 0; nt < 4; nt++)
                acc[nt] = __builtin_amdgcn_mfma_f32_16x16x32_bf16(qh[ks], kh[nt], acc[nt], 0, 0, 0);
            #pragma unroll
            for (int nt = 0; nt < 4; nt++)
                acc[nt] = __builtin_amdgcn_mfma_f32_16x16x32_bf16(qh[ks], kl[nt], acc[nt], 0, 0, 0);
            #pragma unroll
            for (int nt = 0; nt < 4; nt++)
                acc[nt] = __builtin_amdgcn_mfma_f32_16x16x32_bf16(ql[ks], kh[nt], acc[nt], 0, 0, 0);
        }
        #pragma unroll
        for (int nt = 0; nt < 4; nt++) {
            #pragma unroll
            for (int r = 0; r < 4; r++) {
                float s = acc[nt][r] * 0.125f;
                u16 hi = f2b(s);
                Sh[wave * 16 + quad * 4 + r][kt * 64 + nt * 16 + ln] = hi;
                Sl[wave * 16 + quad * 4 + r][kt * 64 + nt * 16 + ln] = f2b(s - b2f(hi));
            }
        }
    }

    // ---- Phase 2: softmax (exact row max; P written back hi/lo) ----
    __syncthreads();
    {
        const int q = tid >> 2, seg = tid & 3;
        float mx = -1e30f;
        #pragma unroll
        for (int i = 0; i < 8; i++) {
            uint4 h4 = *(const uint4*)&Sh[q][seg * 64 + i * 8];
            uint4 l4 = *(const uint4*)&Sl[q][seg * 64 + i * 8];
            mx = fmaxf(mx, fmaxf(b2f(h4.x) + b2f(l4.x), b2f(h4.x >> 16) + b2f(l4.x >> 16)));
            mx = fmaxf(mx, fmaxf(b2f(h4.y) + b2f(l4.y), b2f(h4.y >> 16) + b2f(l4.y >> 16)));
            mx = fmaxf(mx, fmaxf(b2f(h4.z) + b2f(l4.z), b2f(h4.z >> 16) + b2f(l4.z >> 16)));
            mx = fmaxf(mx, fmaxf(b2f(h4.w) + b2f(l4.w), b2f(h4.w >> 16) + b2f(l4.w >> 16)));
        }
        mred[q][seg] = mx;
        __syncthreads();
        float m = fmaxf(fmaxf(mred[q][0], mred[q][1]), fmaxf(mred[q][2], mred[q][3]));
        float sum = 0.f;
        #pragma unroll
        for (int i = 0; i < 8; i++) {
            uint4 h4 = *(const uint4*)&Sh[q][seg * 64 + i * 8];
            uint4 l4 = *(const uint4*)&Sl[q][seg * 64 + i * 8];
            u32 hw[4] = {h4.x, h4.y, h4.z, h4.w};
            u32 lw[4] = {l4.x, l4.y, l4.z, l4.w};
            uint4 oh, ol;
            u32* ohp = (u32*)&oh; u32* olp = (u32*)&ol;
            #pragma unroll
            for (int j = 0; j < 4; j++) {
                float p0 = __expf(b2f(hw[j]) + b2f(lw[j]) - m);
                float p1 = __expf(b2f(hw[j] >> 16) + b2f(lw[j] >> 16) - m);
                sum += p0 + p1;
                u16 ph0 = f2b(p0), ph1 = f2b(p1);
                u16 pl0 = f2b(p0 - b2f(ph0)), pl1 = f2b(p1 - b2f(ph1));
                ohp[j] = (u32)ph0 | ((u32)ph1 << 16);
                olp[j] = (u32)pl0 | ((u32)pl1 << 16);
            }
            *(uint4*)&Sh[q][seg * 64 + i * 8] = oh;
            *(uint4*)&Sl[q][seg * 64 + i * 8] = ol;
        }
        lred[q][seg] = sum;
        __syncthreads();
        if (seg == 0)
            lsh[q] = (lred[q][0] + lred[q][1]) + (lred[q][2] + lred[q][3]);
    }

    // ---- Phase 3: O = P V (V staged transposed [d][key], hi/lo) ----
    const int vd = tid & 63, vk0 = (tid >> 6) * 16;      // V staging coords
    float vpre[16];
    {
        const float* vp = qkv + (tokbase + vk0) * 3072 + 2048 + hh * 64 + vd;
        #pragma unroll
        for (int j = 0; j < 16; j++) vpre[j] = vp[(size_t)j * 3072];
    }
    floatx4 pacc[4];
    #pragma unroll
    for (int nt = 0; nt < 4; nt++) pacc[nt] = (floatx4){0.f, 0.f, 0.f, 0.f};
    for (int kt = 0; kt < 4; kt++) {
        __syncthreads();
        #pragma unroll
        for (int w = 0; w < 4; w++) {
            u16 hv[4], lv[4];
            #pragma unroll
            for (int j = 0; j < 4; j++) {
                float f = vpre[w * 4 + j];
                hv[j] = f2b(f);
                lv[j] = f2b(f - b2f(hv[j]));
            }
            uint2 uh, ul;
            uh.x = (u32)hv[0] | ((u32)hv[1] << 16);
            uh.y = (u32)hv[2] | ((u32)hv[3] << 16);
            ul.x = (u32)lv[0] | ((u32)lv[1] << 16);
            ul.y = (u32)lv[2] | ((u32)lv[3] << 16);
            *(uint2*)&KVh[vd][vk0 + w * 4] = uh;
            *(uint2*)&KVl[vd][vk0 + w * 4] = ul;
        }
        __syncthreads();
        if (kt < 3) {
            const float* vp = qkv + (tokbase + (kt + 1) * 64 + vk0) * 3072 + 2048 + hh * 64 + vd;
            #pragma unroll
            for (int j = 0; j < 16; j++) vpre[j] = vp[(size_t)j * 3072];
        }
        #pragma unroll
        for (int ks = 0; ks < 2; ks++) {
            const int kc = kt * 64 + ks * 32 + quad * 8;
            bf16x8 ph = *(const bf16x8*)&Sh[wave * 16 + ln][kc];
            bf16x8 pl = *(const bf16x8*)&Sl[wave * 16 + ln][kc];
            bf16x8 vh[4], vl[4];
            #pragma unroll
            for (int nt = 0; nt < 4; nt++) {
                vh[nt] = *(const bf16x8*)&KVh[nt * 16 + ln][ks * 32 + quad * 8];
                vl[nt] = *(const bf16x8*)&KVl[nt * 16 + ln][ks * 32 + quad * 8];
            }
            #pragma unroll
            for (int nt = 0; nt < 4; nt++)
                pacc[nt] = __builtin_amdgcn_mfma_f32_16x16x32_bf16(ph, vh[nt], pacc[nt], 0, 0, 0);
            #pragma unroll
            for (int nt = 0; nt < 4; nt++)
                pacc[nt] = __builtin_amdgcn_mfma_f32_16x16x32_bf16(ph, vl[nt], pacc[nt], 0, 0, 0);
            #pragma unroll
            for (int nt = 0; nt < 4; nt++)
                pacc[nt] = __builtin_amdgcn_mfma_f32_16x16x32_bf16(pl, vh[nt], pacc[nt], 0, 0, 0);
        }
    }
    // ---- Epilogue ----
    {
        float linv[4];
        #pragma unroll
        for (int r = 0; r < 4; r++)
            linv[r] = 1.0f / lsh[wave * 16 + quad * 4 + r];
        #pragma unroll
        for (int nt = 0; nt < 4; nt++) {
            #pragma unroll
            for (int r = 0; r < 4; r++) {
                int row = wave * 16 + quad * 4 + r;
                o[(tokbase + qt * 64 + row) * 1024 + hh * 64 + nt * 16 + ln] =
                    pacc[nt][r] * linv[r];
            }
        }
    }
}

// ---------------------------------------------------------------------------
// Fallback attention (fp32 VALU). Block = (b, h, qtile of 64).
// ---------------------------------------------------------------------------
__global__ __launch_bounds__(256) void attn_kernel(
    const float* __restrict__ qkv, float* __restrict__ o)
{
    const int bx = blockIdx.x;
    const int b  = bx >> 6;
    const int hh = (bx >> 2) & 15;
    const int qt = bx & 3;
    const int tid = threadIdx.x;
    const int wave = tid >> 6, lane = tid & 63;

    __shared__ float sh[2 * 64 * 68];
    float* Ks = sh;
    float* Vs = sh + 64 * 68;

    const int q = qt * 64 + lane;
    float qreg[64];
    const float* qp = qkv + (size_t)(b * 256 + q) * 3072 + hh * 64;
    #pragma unroll
    for (int i = 0; i < 16; i++) *(float4*)&qreg[i * 4] = *(const float4*)(qp + i * 4);

    float oa[64];
    #pragma unroll
    for (int d = 0; d < 64; d++) oa[d] = 0.f;
    float m = -1e30f, l = 0.f;

    for (int s = 0; s < 4; s++) {
        __syncthreads();
        {
            int r = tid >> 2;
            int c = (tid & 3) * 16;
            int key = (r >> 4) * 64 + s * 16 + (r & 15);
            const float* kp = qkv + (size_t)(b * 256 + key) * 3072 + 1024 + hh * 64 + c;
            #pragma unroll
            for (int i = 0; i < 4; i++) {
                *(float4*)&Ks[r * 68 + c + i * 4] = *(const float4*)(kp + i * 4);
                *(float4*)&Vs[r * 68 + c + i * 4] = *(const float4*)(kp + 1024 + i * 4);
            }
        }
        __syncthreads();
        const float* Kw = Ks + wave * 16 * 68;
        const float* Vw = Vs + wave * 16 * 68;
        for (int jj = 0; jj < 16; jj++) {
            float s0 = 0.f, s1 = 0.f, s2 = 0.f, s3 = 0.f;
            #pragma unroll
            for (int d = 0; d < 64; d += 4) {
                s0 = fmaf(qreg[d + 0], Kw[jj * 68 + d + 0], s0);
                s1 = fmaf(qreg[d + 1], Kw[jj * 68 + d + 1], s1);
                s2 = fmaf(qreg[d + 2], Kw[jj * 68 + d + 2], s2);
                s3 = fmaf(qreg[d + 3], Kw[jj * 68 + d + 3], s3);
            }
            float sc = ((s0 + s1) + (s2 + s3)) * 0.125f;
            float mn = fmaxf(m, sc);
            float c = __expf(m - mn);
            float p = __expf(sc - mn);
            l = l * c + p;
            #pragma unroll
            for (int d = 0; d < 64; d++)
                oa[d] = fmaf(oa[d], c, p * Vw[jj * 68 + d]);
            m = mn;
        }
    }

    __syncthreads();
    if (wave == 1 || wave == 3) {
        float* dst = sh + (wave >> 1) * (64 * 66) + lane * 66;
        #pragma unroll
        for (int d = 0; d < 64; d++) dst[d] = oa[d];
        dst[64] = m; dst[65] = l;
    }
    __syncthreads();
    if (wave == 0 || wave == 2) {
        const float* src = sh + (wave >> 1) * (64 * 66) + lane * 66;
        float m2 = src[64], l2 = src[65];
        float M = fmaxf(m, m2);
        float c1 = __expf(m - M), c2 = __expf(m2 - M);
        l = l * c1 + l2 * c2;
        #pragma unroll
        for (int d = 0; d < 64; d++) oa[d] = oa[d] * c1 + src[d] * c2;
        m = M;
    }
    __syncthreads();
    if (wave == 2) {
        float* dst = sh + lane * 66;
        #pragma unroll
        for (int d = 0; d < 64; d++) dst[d] = oa[d];
        dst[64] = m; dst[65] = l;
    }
    __syncthreads();
    if (wave == 0) {
        const float* src = sh + lane * 66;
        float m2 = src[64], l2 = src[65];
        float M = fmaxf(m, m2);
        float c1 = __expf(m - M), c2 = __expf(m2 - M);
        l = l * c1 + l2 * c2;
        #pragma unroll
        for (int d = 0; d < 64; d++) oa[d] = oa[d] * c1 + src[d] * c2;
        float inv = 1.0f / l;
        float* op = o + (size_t)(b * 256 + q) * 1024 + hh * 64;
        #pragma unroll
        for (int i = 0; i < 16; i++) {
            float4 v = { oa[i * 4] * inv, oa[i * 4 + 1] * inv,
                         oa[i * 4 + 2] * inv, oa[i * 4 + 3] * inv };
            *(float4*)(op + i * 4) = v;
        }
    }
}

// ---------------------------------------------------------------------------
// Router fc2 + top2. One wave per token; float4-vectorized h reads (R14).
// ---------------------------------------------------------------------------
__global__ __launch_bounds__(256) void router_kernel(
    const float* __restrict__ hr, const void* __restrict__ w2,
    const void* __restrict__ b2, int* __restrict__ t2i,
    float* __restrict__ t2w, int* __restrict__ cb, int rowbase,
    const int* __restrict__ flg)
{
    const int isf = flg[12];
    const int lt = blockIdx.x * 4 + (threadIdx.x >> 6);
    const int t = rowbase + lt;
    const int lane = threadIdx.x & 63;
    float a0 = 0.f, a1 = 0.f, a2 = 0.f, a3 = 0.f;
    const float* hp = hr + (size_t)lt * 2048;
    #pragma unroll
    for (int it = 0; it < 8; it++) {
        const int j = it * 256 + lane * 4;
        float4 hv = *(const float4*)(hp + j);
        float w[4];
        ld4(w2, (size_t)(j + 0) * 4, isf, w);
        a0 = fmaf(hv.x, w[0], a0); a1 = fmaf(hv.x, w[1], a1);
        a2 = fmaf(hv.x, w[2], a2); a3 = fmaf(hv.x, w[3], a3);
        ld4(w2, (size_t)(j + 1) * 4, isf, w);
        a0 = fmaf(hv.y, w[0], a0); a1 = fmaf(hv.y, w[1], a1);
        a2 = fmaf(hv.y, w[2], a2); a3 = fmaf(hv.y, w[3], a3);
        ld4(w2, (size_t)(j + 2) * 4, isf, w);
        a0 = fmaf(hv.z, w[0], a0); a1 = fmaf(hv.z, w[1], a1);
        a2 = fmaf(hv.z, w[2], a2); a3 = fmaf(hv.z, w[3], a3);
        ld4(w2, (size_t)(j + 3) * 4, isf, w);
        a0 = fmaf(hv.w, w[0], a0); a1 = fmaf(hv.w, w[1], a1);
        a2 = fmaf(hv.w, w[2], a2); a3 = fmaf(hv.w, w[3], a3);
    }
    #pragma unroll
    for (int off = 32; off > 0; off >>= 1) {
        a0 += __shfl_down(a0, off, 64);
        a1 += __shfl_down(a1, off, 64);
        a2 += __shfl_down(a2, off, 64);
        a3 += __shfl_down(a3, off, 64);
    }
    if (lane == 0) {
        float l[4];
        l[0] = a0 + lmix(b2, 0, isf); l[1] = a1 + lmix(b2, 1, isf);
        l[2] = a2 + lmix(b2, 2, isf); l[3] = a3 + lmix(b2, 3, isf);
        int i0 = 0;
        #pragma unroll
        for (int i = 1; i < 4; i++) if (l[i] > l[i0]) i0 = i;
        int i1 = (i0 == 0) ? 1 : 0;
        #pragma unroll
        for (int i = 0; i < 4; i++) if (i != i0 && l[i] > l[i1]) i1 = i;
        float mx = fmaxf(fmaxf(l[0], l[1]), fmaxf(l[2], l[3]));
        float e0 = __expf(l[0] - mx), e1 = __expf(l[1] - mx);
        float e2 = __expf(l[2] - mx), e3 = __expf(l[3] - mx);
        float inv = 1.0f / (e0 + e1 + e2 + e3);
        float p[4] = { e0 * inv, e1 * inv, e2 * inv, e3 * inv };
        float b0 = fminf(fmaxf(p[i0], 1e-9f), 1.0f - 1e-9f);
        float b1 = fminf(fmaxf(p[i1], 1e-9f), 1.0f - 1e-9f);
        float winv = 1.0f / (b0 + b1);
        t2i[2 * t] = i0; t2i[2 * t + 1] = i1;
        t2w[2 * t] = b0 * winv; t2w[2 * t + 1] = b1 * winv;
        atomicAdd(&cb[i0], 1);
        atomicAdd(&cb[i1], 1);
    }
}

// ---------------------------------------------------------------------------
// fill2: deterministic token->slot assignment via LDS scan; no contended
// atomics; writes cb[4+e].
// ---------------------------------------------------------------------------
__global__ __launch_bounds__(256) void fill2_kernel(
    const int* __restrict__ t2i, const float* __restrict__ t2w,
    int* __restrict__ cb, int* __restrict__ tok,
    float* __restrict__ aw, int* __restrict__ apos)
{
    const int e = blockIdx.x;
    const int tid = threadIdx.x;
    __shared__ int scan[256];
    int base = 0;
    #pragma unroll
    for (int i = 0; i < 4; i++) if (i < e) base += cb[i];
    const int t0 = tid * 32;
    int cnt = 0;
    for (int t = t0; t < t0 + 32; t++)
        cnt += (t2i[2 * t] == e) + (t2i[2 * t + 1] == e);
    scan[tid] = cnt;
    __syncthreads();
    for (int off = 1; off < 256; off <<= 1) {
        int add = (tid >= off) ? scan[tid - off] : 0;
        __syncthreads();
        scan[tid] += add;
        __syncthreads();
    }
    int pos = base + scan[tid] - cnt;   // exclusive prefix within expert
    for (int t = t0; t < t0 + 32; t++) {
        #pragma unroll
        for (int j = 0; j < 2; j++) {
            if (t2i[2 * t + j] == e) {
                tok[pos] = t;
                aw[pos] = t2w[2 * t + j];
                apos[2 * t + j] = pos;
                pos++;
            }
        }
    }
    if (tid == 0) cb[4 + e] = base;
}

// ---------------------------------------------------------------------------
// Fallback MoE GEMM (R7): 64x64 tile, in-loop LN + f2b.
// ---------------------------------------------------------------------------
#define EM_FC1 0
#define EM_FC2 1

__global__ __launch_bounds__(256) void gemm_mfma(
    int mode,
    const float* __restrict__ x1,
    const float* __restrict__ mu, const float* __restrict__ rs,
    const void* __restrict__ lng, const void* __restrict__ lnb,
    const u16* __restrict__ Ab,
    const void* __restrict__ B, size_t bOff, int ldb, int K,
    u16* __restrict__ C, int ldc,
    const void* __restrict__ bias, size_t biasOff,
    const float* __restrict__ rowscale,
    const int* __restrict__ toklist,
    const int* __restrict__ cb, int e, int rowOff,
    const int* __restrict__ flg)
{
    const int isf = flg[12];
    const int Meff = cb[e];
    const int gbase = cb[4 + e];
    const int rg0 = rowOff + blockIdx.y * 64;
    if (rg0 >= Meff) return;
    const int col0 = blockIdx.x * 64;
    __shared__ __align__(16) u16 As[64][72];
    __shared__ __align__(16) u16 Bs[64][72];
    const int tid = threadIdx.x;
    const int wave = tid >> 6, lane = tid & 63;
    const int ln = lane & 15, quad = lane >> 4;
    floatx4 acc[4];
    #pragma unroll
    for (int nt = 0; nt < 4; nt++) acc[nt] = (floatx4){0.f, 0.f, 0.f, 0.f};

    const int ar = tid >> 2, ac = (tid & 3) * 8;
    const int bk = tid >> 3, bn = (tid & 7) * 8;
    const int rg = rg0 + ar;
    const bool valid = (rg < Meff);
    int tokid = 0; float lm = 0.f, lr = 0.f;
    if (mode == EM_FC1 && valid) {
        tokid = toklist[gbase + rg];
        lm = mu[tokid]; lr = rs[tokid];
    }

    for (int k0 = 0; k0 < K; k0 += 32) {
        __syncthreads();
        if (mode == EM_FC1) {
            uint4 packed = {0u, 0u, 0u, 0u};
            if (valid) {
                float4 p0 = *(const float4*)(x1 + (size_t)tokid * 1024 + k0 + ac);
                float4 p1 = *(const float4*)(x1 + (size_t)tokid * 1024 + k0 + ac + 4);
                float pv[8] = {p0.x, p0.y, p0.z, p0.w, p1.x, p1.y, p1.z, p1.w};
                float gg[8], bb[8];
                ld8(lng, k0 + ac, isf, gg);
                ld8(lnb, k0 + ac, isf, bb);
                u16 wb[8];
                #pragma unroll
                for (int z = 0; z < 8; z++)
                    wb[z] = f2b((pv[z] - lm) * lr * gg[z] + bb[z]);
                packed.x = (u32)wb[0] | ((u32)wb[1] << 16);
                packed.y = (u32)wb[2] | ((u32)wb[3] << 16);
                packed.z = (u32)wb[4] | ((u32)wb[5] << 16);
                packed.w = (u32)wb[6] | ((u32)wb[7] << 16);
            }
            *(uint4*)&As[ar][ac] = packed;
        } else {
            uint4 av = {0u, 0u, 0u, 0u};
            if (valid) av = *(const uint4*)(Ab + (size_t)(rg - rowOff) * K + k0 + ac);
            *(uint4*)&As[ar][ac] = av;
        }
        u16 u[8];
        {
            float w[8];
            ld8(B, bOff + (size_t)(k0 + bk) * ldb + col0 + bn, isf, w);
            #pragma unroll
            for (int z = 0; z < 8; z++) u[z] = f2b(w[z]);
        }
        #pragma unroll
        for (int jj = 0; jj < 8; jj++) {
            int j = (jj + (tid & 7)) & 7;
            Bs[bn + j][bk] = u[j];
        }
        __syncthreads();
        bf16x8 af = *(const bf16x8*)&As[wave * 16 + ln][quad * 8];
        #pragma unroll
        for (int nt = 0; nt < 4; nt++) {
            bf16x8 bf = *(const bf16x8*)&Bs[nt * 16 + ln][quad * 8];
            acc[nt] = __builtin_amdgcn_mfma_f32_16x16x32_bf16(af, bf, acc[nt], 0, 0, 0);
        }
    }
    #pragma unroll
    for (int nt = 0; nt < 4; nt++) {
        #pragma unroll
        for (int r = 0; r < 4; r++) {
            int gw = rg0 + wave * 16 + quad * 4 + r;
            if (gw >= Meff) continue;
            int gcol = col0 + nt * 16 + ln;
            float v = acc[nt][r] + lmix(bias, biasOff + gcol, isf);
            if (mode == EM_FC1) {
                C[(size_t)(gw - rowOff) * ldc + gcol] = f2b(gelu_f(v));
            } else {
                v *= rowscale[gbase + gw];
                C[(size_t)(gbase + gw) * ldc + gcol] = f2b(v);
            }
        }
    }
}

// ---------------------------------------------------------------------------
__global__ __launch_bounds__(256) void combine_kernel(
    const float* __restrict__ x1, const u16* __restrict__ eo,
    const int* __restrict__ apos, void* __restrict__ outv,
    const int* __restrict__ flg)
{
    const int isf = flg[12];
    int t = blockIdx.x;
    int c = threadIdx.x * 4;
    int p0 = apos[2 * t], p1 = apos[2 * t + 1];
    float4 xv = *(const float4*)(x1 + (size_t)t * 1024 + c);
    uint2 ea = *(const uint2*)(eo + (size_t)p0 * 1024 + c);
    uint2 eb = *(const uint2*)(eo + (size_t)p1 * 1024 + c);
    float r0 = xv.x + b2f(ea.x) + b2f(eb.x);
    float r1 = xv.y + b2f(ea.x >> 16) + b2f(eb.x >> 16);
    float r2 = xv.z + b2f(ea.y) + b2f(eb.y);
    float r3 = xv.w + b2f(ea.y >> 16) + b2f(eb.y >> 16);
    if (isf) {
        float4 res = {r0, r1, r2, r3};
        *(float4*)((float*)outv + (size_t)t * 1024 + c) = res;
    } else {
        uint2 res;
        res.x = (u32)f2b(r0) | ((u32)f2b(r1) << 16);
        res.y = (u32)f2b(r2) | ((u32)f2b(r3) << 16);
        *(uint2*)((u16*)outv + (size_t)t * 1024 + c) = res;
    }
}

// ---------------------------------------------------------------------------
extern "C" void kernel_launch(void* const* d_in, const int* in_sizes, int n_in,
                              void* d_out, int out_size, void* d_ws, size_t ws_size,
                              hipStream_t stream)
{
    const void* x      = d_in[0];
    const void* cond   = d_in[1];
    const void* ln1_g  = d_in[2];
    const void* ln1_b  = d_in[3];
    const void* qkv_w  = d_in[4];
    const void* proj_w = d_in[5];
    const void* proj_b = d_in[6];
    const void* ln2_g  = d_in[7];
    const void* ln2_b  = d_in[8];
    const void* rf1w   = d_in[9];
    const void* rf1b   = d_in[10];
    const void* rf2w   = d_in[11];
    const void* rf2b   = d_in[12];
    const void* ew1    = d_in[13];
    const void* eb1    = d_in[14];
    const void* ew2    = d_in[15];
    const void* eb2    = d_in[16];
    (void)in_sizes; (void)n_in; (void)out_size;

    char* ws = (char*)d_ws;
    const size_t MB = 1024 * 1024;
    const bool fat = ws_size >= (size_t)116 * MB;

    // [0,32M): x1 after proj. Attn phase (fat): qkvt [0,12), hpk [12,28).
    float* x1   = (float*)(ws);
    u16*   qkvt = (u16*)(ws);
    u16*   hpk  = (u16*)(ws + 12 * MB);
    float* qkvcFb = (float*)(ws + 16 * MB);   // fallback: 1024 rows
    // [32,64M): ob (attn out) -> rf1t [32,40) + h2t [40,56) (router) -> eo (MoE).
    char*  B1   = ws + 32 * MB;
    float* ob   = (float*)B1;
    u16*   rf1tF= (u16*)B1;                   // fat router: [32,40)
    u16*   h2tF = (u16*)(ws + 40 * MB);       // fat router: [40,56), 4096 rows
    u16*   eo   = (u16*)B1;
    u16*   rf1tB= (u16*)B1;
    // [64,...): fat attn: qkvc 48M at [64,112). fat proj: obp [64,96).
    // fat router: hrc 32M at [64,96). fat MoE: hid [64,80)+ew1t[80,88)+ew2t[88,96).
    char*  R    = ws + 64 * MB;
    float* qkvcF= (float*)R;                  // fat: 4096 rows x 3072 fp32 = 48M
    u16*   h2tB = (u16*)R;
    float* hrcB = (float*)(R + 8 * MB);
    float* hrcF = (float*)R;                  // fat: 4096 x 2048 fp32 = 32M
    u16*   hid  = (u16*)R;
    u16*   obp  = (u16*)R;
    u16*   ew1t = (u16*)(R + 16 * MB);
    u16*   ew2t = (u16*)(R + 24 * MB);
    u16*   pwt  = (u16*)(ws + 96 * MB);
    u16*   h2b  = (u16*)(ws + 96 * MB);
    char*  ST   = ws + (fat ? 112 : 96) * MB;

    size_t so = 0;
    auto salloc = [&](size_t bytes) { size_t o = so; so += (bytes + 255) & ~(size_t)255; return o; };
    float* mu   = (float*)(ST + salloc(8192 * 4));
    float* rs   = (float*)(ST + salloc(8192 * 4));
    float* ct   = (float*)(ST + salloc((size_t)32 * 2048 * 4));
    int*   t2i  = (int*)  (ST + salloc(16384 * 4));
    float* t2w  = (float*)(ST + salloc(16384 * 4));
    int*   cb   = (int*)  (ST + salloc(16 * 4));
    int*   tok  = (int*)  (ST + salloc(16384 * 4));
    float* aw   = (float*)(ST + salloc(16384 * 4));
    int*   apos = (int*)  (ST + salloc(16384 * 4));

    init_kernel<<<1, 256, 0, stream>>>(x, cb);

    // ---- Attention pipeline ----
    pack_wt_kernel<<<dim3(16, 48), 256, 0, stream>>>(qkv_w, 3072, 1024, qkvt, cb);
    if (fat) {
        for (int c = 0; c < 2; c++) {
            const size_t r0 = (size_t)c * 4096;
            pack_ln_kernel<<<4096, 256, 0, stream>>>(
                0, x, r0, ln1_g, ln1_b, nullptr, nullptr, hpk, nullptr, cb);
            gemm_sb<<<dim3(24, 32), 256, 0, stream>>>(
                SB_PLAIN, hpk, qkvt, 1024, qkvcF, 3072, nullptr, nullptr, nullptr, 0, cb);
            attn_mfma_kernel<<<1024, 256, 0, stream>>>(qkvcF, ob + r0 * 1024);
        }
    } else {
        for (int c = 0; c < 8; c++) {
            const size_t r0 = (size_t)c * 1024;
            pack_ln_kernel<<<1024, 256, 0, stream>>>(
                0, x, r0, ln1_g, ln1_b, nullptr, nullptr, hpk, nullptr, cb);
            gemm_sb<<<dim3(24, 8), 256, 0, stream>>>(
                SB_PLAIN, hpk, qkvt, 1024, qkvcFb, 3072, nullptr, nullptr, nullptr, 0, cb);
            attn_kernel<<<256, 256, 0, stream>>>(qkvcFb, ob + r0 * 1024);
        }
    }

    // ---- proj + bias + residual(x) -> x1 ----
    if (fat) {
        pack_sb_rows_kernel<<<8192, 256, 0, stream>>>(ob, obp);
        pack_wt_kernel<<<dim3(16, 16), 256, 0, stream>>>(proj_w, 1024, 1024, pwt, cb);
        gemm_sb<<<dim3(8, 64), 256, 0, stream>>>(
            SB_PROJ, obp, pwt, 1024, x1, 1024, proj_b, nullptr, x, 0, cb);
    } else {
        gemm_f32<<<dim3(8, 64), 256, 0, stream>>>(
            GM_PROJ, 0, (const void*)ob, 1024, proj_w, 1024, 0, 8192, 1024, 1024,
            x1, 1024, proj_b, x, cb);
    }

    // LN2 stats
    ln_stats_kernel<<<8192, 256, 0, stream>>>(x1, mu, rs);

    // cond @ r_fc1_w[1024:2048,:] -> ct [32,2048]
    cond_kernel<<<dim3(32, 32), 256, 0, stream>>>(cond, rf1w, ct, cb);

    // ---- Router fc1 (split-bf16 MFMA) + fc2/top2 ----
    if (fat) {
        pack_wt_kernel<<<dim3(16, 32), 256, 0, stream>>>(rf1w, 2048, 1024, rf1tF, cb);
        for (int rc = 0; rc < 2; rc++) {
            const int rb = rc * 4096;
            pack_ln_kernel<<<4096, 256, 0, stream>>>(
                1, x1, rb, ln2_g, ln2_b, mu, rs, h2tF, h2b, cb);
            gemm_sb<<<dim3(16, 32), 256, 0, stream>>>(
                SB_FC1, h2tF, rf1tF, 1024, hrcF, 2048, rf1b, ct, nullptr, rb, cb);
            router_kernel<<<1024, 256, 0, stream>>>(hrcF, rf2w, rf2b, t2i, t2w, cb, rb, cb);
        }
    } else {
        pack_wt_kernel<<<dim3(16, 32), 256, 0, stream>>>(rf1w, 2048, 1024, rf1tB, cb);
        for (int rc = 0; rc < 4; rc++) {
            const int rb = rc * 2048;
            pack_ln_kernel<<<2048, 256, 0, stream>>>(
                1, x1, rb, ln2_g, ln2_b, mu, rs, h2tB, nullptr, cb);
            gemm_sb<<<dim3(16, 16), 256, 0, stream>>>(
                SB_FC1, h2tB, rf1tB, 1024, hrcB, 2048, rf1b, ct, nullptr, rb, cb);
            router_kernel<<<512, 256, 0, stream>>>(hrcB, rf2w, rf2b, t2i, t2w, cb, rb, cb);
        }
    }
    fill2_kernel<<<4, 256, 0, stream>>>(t2i, t2w, cb, tok, aw, apos);

    // ---- Expert MLPs ----
    if (fat) {
        for (int e = 0; e < 4; e++) {
            pack_wtb_kernel<<<dim3(16, 64), 256, 0, stream>>>(
                ew1, (size_t)e * 1024 * 4096, 4096, 1024, ew1t, cb);
            pack_wtb_kernel<<<dim3(64, 16), 256, 0, stream>>>(
                ew2, (size_t)e * 4096 * 1024, 1024, 4096, ew2t, cb);
            for (int c = 0; c < 4; c++) {
                const int ro = c * 2048;
                gemm_moe<<<dim3(32, 16), 256, 0, stream>>>(
                    MOE_FC1, h2b, ew1t, 1024, hid, 4096,
                    eb1, (size_t)e * 4096, nullptr, tok, cb, e, ro, cb);
                gemm_moe2<<<dim3(16, 16), 256, 0, stream>>>(
                    hid, ew2t, eo, eb2, (size_t)e * 1024, aw, cb, e, ro, cb);
            }
        }
    } else {
        for (int e = 0; e < 4; e++) {
            for (int c = 0; c < 2; c++) {
                const int ro = c * 4096;
                gemm_mfma<<<dim3(64, 64), 256, 0, stream>>>(
                    EM_FC1, x1, mu, rs, ln2_g, ln2_b, nullptr,
                    ew1, (size_t)e * 1024 * 4096, 4096, 1024,
                    hid, 4096, eb1, (size_t)e * 4096, nullptr, tok, cb, e, ro, cb);
                gemm_mfma<<<dim3(16, 64), 256, 0, stream>>>(
                    EM_FC2, nullptr, nullptr, nullptr, nullptr, nullptr, hid,
                    ew2, (size_t)e * 4096 * 1024, 1024, 4096,
                    eo, 1024, eb2, (size_t)e * 1024, aw, tok, cb, e, ro, cb);
            }
        }
    }

    combine_kernel<<<8192, 256, 0, stream>>>(x1, eo, apos, d_out, cb);
}

// Round 11
// 1908.200 us; speedup vs baseline: 1.1258x; 1.0593x over previous
//
#include <hip/hip_runtime.h>

// ---------------------------------------------------------------------------
// MoDeDiT block: LN1 -> QKV -> MHA -> proj(+res) -> LN2-stats -> router MLP
//                -> top2 -> MoE expert MLPs -> combine
//
// R15: fuse router fc2 into the fc1 GEMM epilogue. R14 post-mortem: router
// fc2 kernel stayed latency-bound (~1 outstanding load/wave, VALUBusy 2%)
// at 100us x2 despite vectorization -- structural, not fixable by patching.
// Fix: h-row values are already in registers in gemm_sb SB_FC1's epilogue;
// accumulate v*w2[col][e] there (16-lane shfl_xor reduce per row, one
// fp32 atomicAdd per (row,expert) per col-block into lg[8192][4]; ~32
// atomics/address). hrc is never written nor read (-128MB traffic); router
// kernel replaced by trivial top2_kernel (no atomics) + zero_lg. fill2 now
// self-counts all experts (no atomic counts needed). Fallback unchanged.
// ---------------------------------------------------------------------------

typedef unsigned short u16;
typedef unsigned int   u32;

typedef __bf16 bf16x8 __attribute__((ext_vector_type(8)));
typedef float  floatx4 __attribute__((ext_vector_type(4)));

__device__ __forceinline__ float b2f(u32 u) {
    union { float f; u32 i; } v; v.i = (u & 0xffffu) << 16; return v.f;
}
__device__ __forceinline__ u16 f2b(float f) {  // round-nearest-even
    union { float f; u32 i; } v; v.f = f;
    u32 x = v.i;
    u32 r = (x + 0x7fffu + ((x >> 16) & 1u)) >> 16;
    return (u16)r;
}
__device__ __forceinline__ float gelu_f(float x) {
    return 0.5f * x * (1.0f + erff(x * 0.70710678118654752440f));
}
__device__ __forceinline__ float lmix(const void* p, size_t i, int isf) {
    return isf ? ((const float*)p)[i] : b2f(((const u16*)p)[i]);
}
__device__ __forceinline__ void ld8(const void* p, size_t i, int isf, float w[8]) {
    if (isf) {
        const float* q = (const float*)p + i;
        float4 a = *(const float4*)q, b = *(const float4*)(q + 4);
        w[0] = a.x; w[1] = a.y; w[2] = a.z; w[3] = a.w;
        w[4] = b.x; w[5] = b.y; w[6] = b.z; w[7] = b.w;
    } else {
        const u16* q = (const u16*)p + i;
        uint4 r = *(const uint4*)q;
        w[0] = b2f(r.x); w[1] = b2f(r.x >> 16);
        w[2] = b2f(r.y); w[3] = b2f(r.y >> 16);
        w[4] = b2f(r.z); w[5] = b2f(r.z >> 16);
        w[6] = b2f(r.w); w[7] = b2f(r.w >> 16);
    }
}
__device__ __forceinline__ void ld4(const void* p, size_t i, int isf, float w[4]) {
    if (isf) {
        float4 a = *(const float4*)((const float*)p + i);
        w[0] = a.x; w[1] = a.y; w[2] = a.z; w[3] = a.w;
    } else {
        uint2 r = *(const uint2*)((const u16*)p + i);
        w[0] = b2f(r.x); w[1] = b2f(r.x >> 16);
        w[2] = b2f(r.y); w[3] = b2f(r.y >> 16);
    }
}

// ---------------------------------------------------------------------------
__global__ void init_kernel(const void* x0, int* cb) {
    __shared__ int sh[256];
    const int tid = threadIdx.x;
    if (tid < 12) cb[tid] = 0;
    int bad = 0;
    const u16* p = (const u16*)x0;
    for (int i = tid; i < 4096; i += 256) {
        float v = b2f(p[2 * i]);
        float a = fabsf(v);
        if (!(a <= 1e3f) || (v != 0.f && a < 1e-8f)) bad++;
    }
    sh[tid] = bad;
    __syncthreads();
    for (int s = 128; s > 0; s >>= 1) {
        if (tid < s) sh[tid] += sh[tid + s];
        __syncthreads();
    }
    if (tid == 0) cb[12] = (sh[0] > 512) ? 1 : 0;
}

// ---------------------------------------------------------------------------
__global__ __launch_bounds__(256) void zero_lg_kernel(float* __restrict__ lg) {
    lg[blockIdx.x * 256 + threadIdx.x] = 0.f;   // 32768 floats, 128 blocks
}

// ---------------------------------------------------------------------------
// cond_kernel: ct[b][col] = sum_k cond[b][k] * W[1024+k][col], fp32.
// ---------------------------------------------------------------------------
__global__ __launch_bounds__(256) void cond_kernel(
    const void* __restrict__ cond, const void* __restrict__ w1,
    float* __restrict__ ct, const int* __restrict__ flg)
{
    const int isf = flg[12];
    const int b = blockIdx.y;
    const int col0 = blockIdx.x * 64;
    const int tid = threadIdx.x;
    const int wave = tid >> 6, lane = tid & 63;
    __shared__ float a[1024];
    __shared__ float part[4][64];
    {
        float v[4];
        ld4(cond, (size_t)b * 1024 + tid * 4, isf, v);
        a[tid * 4 + 0] = v[0]; a[tid * 4 + 1] = v[1];
        a[tid * 4 + 2] = v[2]; a[tid * 4 + 3] = v[3];
    }
    __syncthreads();
    const int col = col0 + lane;
    float s = 0.f;
    const int kbase = wave * 256;
    #pragma unroll 4
    for (int k = 0; k < 256; k++)
        s = fmaf(a[kbase + k], lmix(w1, (size_t)(1024 + kbase + k) * 2048 + col, isf), s);
    part[wave][lane] = s;
    __syncthreads();
    if (wave == 0) {
        float r = (part[0][lane] + part[1][lane]) + (part[2][lane] + part[3][lane]);
        ct[(size_t)b * 2048 + col] = r;
    }
}

// ---------------------------------------------------------------------------
// pack_ln: LN a row of 1024 -> split pack [row][hi|lo]; optionally also a
// plain bf16 copy into hb[global row] (fast-path h2b).
// ---------------------------------------------------------------------------
__global__ __launch_bounds__(256) void pack_ln_kernel(
    int mode, const void* __restrict__ xin, size_t rowbase,
    const void* __restrict__ g, const void* __restrict__ bta,
    const float* __restrict__ mu_g, const float* __restrict__ rs_g,
    u16* __restrict__ hpk, u16* __restrict__ hb, const int* __restrict__ flg)
{
    const int isf = flg[12];
    const int row = blockIdx.x, tid = threadIdx.x;
    float v[4];
    float mu, rsv;
    __shared__ float red[8];
    __shared__ float mu_rs[2];
    if (mode == 0) {
        ld4(xin, (rowbase + row) * 1024 + tid * 4, isf, v);
        float s = v[0] + v[1] + v[2] + v[3];
        float q = v[0] * v[0] + v[1] * v[1] + v[2] * v[2] + v[3] * v[3];
        #pragma unroll
        for (int off = 32; off > 0; off >>= 1) {
            s += __shfl_down(s, off, 64);
            q += __shfl_down(q, off, 64);
        }
        int wid = tid >> 6, lane = tid & 63;
        if (lane == 0) { red[wid] = s; red[4 + wid] = q; }
        __syncthreads();
        if (tid == 0) {
            float ts = red[0] + red[1] + red[2] + red[3];
            float tq = red[4] + red[5] + red[6] + red[7];
            float m = ts * (1.0f / 1024.0f);
            float var = tq * (1.0f / 1024.0f) - m * m;
            float xx = var + 1e-5f;
            float r = rsqrtf(xx);
            r = r * (1.5f - 0.5f * xx * r * r);
            mu_rs[0] = m; mu_rs[1] = r;
        }
        __syncthreads();
        mu = mu_rs[0]; rsv = mu_rs[1];
    } else {
        float4 t = *(const float4*)((const float*)xin + (rowbase + row) * 1024 + tid * 4);
        v[0] = t.x; v[1] = t.y; v[2] = t.z; v[3] = t.w;
        mu = mu_g[rowbase + row]; rsv = rs_g[rowbase + row];
    }
    float gg[4], bb[4];
    ld4(g, tid * 4, isf, gg);
    ld4(bta, tid * 4, isf, bb);
    u16 hi[4], lo[4];
    #pragma unroll
    for (int i = 0; i < 4; i++) {
        float h = (v[i] - mu) * rsv * gg[i] + bb[i];
        hi[i] = f2b(h);
        lo[i] = f2b(h - b2f(hi[i]));
    }
    uint2 ph, pl;
    ph.x = (u32)hi[0] | ((u32)hi[1] << 16);
    ph.y = (u32)hi[2] | ((u32)hi[3] << 16);
    pl.x = (u32)lo[0] | ((u32)lo[1] << 16);
    pl.y = (u32)lo[2] | ((u32)lo[3] << 16);
    *(uint2*)(hpk + (size_t)row * 2048 + tid * 4) = ph;
    *(uint2*)(hpk + (size_t)row * 2048 + 1024 + tid * 4) = pl;
    if (hb) *(uint2*)(hb + (rowbase + row) * 1024 + tid * 4) = ph;
}

// ---------------------------------------------------------------------------
// pack_wt: split W[K][N] (mixed) -> transposed split pack Bt[N][2K].
// ---------------------------------------------------------------------------
__global__ __launch_bounds__(256) void pack_wt_kernel(
    const void* __restrict__ W, int N, int K,
    u16* __restrict__ Bt, const int* __restrict__ flg)
{
    const int isf = flg[12];
    __shared__ float sh[64][65];
    const int k0 = blockIdx.x * 64, n0 = blockIdx.y * 64;
    const int tid = threadIdx.x;
    #pragma unroll
    for (int i = 0; i < 4; i++) {
        int r = (tid >> 4) + i * 16, c = (tid & 15) * 4;
        float w[4];
        ld4(W, (size_t)(k0 + r) * N + n0 + c, isf, w);
        sh[r][c] = w[0]; sh[r][c + 1] = w[1]; sh[r][c + 2] = w[2]; sh[r][c + 3] = w[3];
    }
    __syncthreads();
    const int n = tid >> 2, kc = (tid & 3) * 16;
    u16 hi[16], lo[16];
    #pragma unroll
    for (int j = 0; j < 16; j++) {
        float v = sh[kc + j][n];
        hi[j] = f2b(v);
        lo[j] = f2b(v - b2f(hi[j]));
    }
    u16* dst = Bt + (size_t)(n0 + n) * (2 * K) + k0 + kc;
    uint4 a, b;
    a.x = (u32)hi[0] | ((u32)hi[1] << 16);  a.y = (u32)hi[2] | ((u32)hi[3] << 16);
    a.z = (u32)hi[4] | ((u32)hi[5] << 16);  a.w = (u32)hi[6] | ((u32)hi[7] << 16);
    b.x = (u32)hi[8] | ((u32)hi[9] << 16);  b.y = (u32)hi[10] | ((u32)hi[11] << 16);
    b.z = (u32)hi[12] | ((u32)hi[13] << 16); b.w = (u32)hi[14] | ((u32)hi[15] << 16);
    *(uint4*)dst = a; *(uint4*)(dst + 8) = b;
    a.x = (u32)lo[0] | ((u32)lo[1] << 16);  a.y = (u32)lo[2] | ((u32)lo[3] << 16);
    a.z = (u32)lo[4] | ((u32)lo[5] << 16);  a.w = (u32)lo[6] | ((u32)lo[7] << 16);
    b.x = (u32)lo[8] | ((u32)lo[9] << 16);  b.y = (u32)lo[10] | ((u32)lo[11] << 16);
    b.z = (u32)lo[12] | ((u32)lo[13] << 16); b.w = (u32)lo[14] | ((u32)lo[15] << 16);
    *(uint4*)(dst + K) = a; *(uint4*)(dst + K + 8) = b;
}

// ---------------------------------------------------------------------------
// pack_wtb: plain bf16 transpose pack. W[K][N] (mixed, +wOff elems) -> Bt[N][K].
// ---------------------------------------------------------------------------
__global__ __launch_bounds__(256) void pack_wtb_kernel(
    const void* __restrict__ W, size_t wOff, int N, int K,
    u16* __restrict__ Bt, const int* __restrict__ flg)
{
    const int isf = flg[12];
    __shared__ float sh[64][65];
    const int k0 = blockIdx.x * 64, n0 = blockIdx.y * 64;
    const int tid = threadIdx.x;
    #pragma unroll
    for (int i = 0; i < 4; i++) {
        int r = (tid >> 4) + i * 16, c = (tid & 15) * 4;
        float w[4];
        ld4(W, wOff + (size_t)(k0 + r) * N + n0 + c, isf, w);
        sh[r][c] = w[0]; sh[r][c + 1] = w[1]; sh[r][c + 2] = w[2]; sh[r][c + 3] = w[3];
    }
    __syncthreads();
    const int n = tid >> 2, kc = (tid & 3) * 16;
    u16 hi[16];
    #pragma unroll
    for (int j = 0; j < 16; j++) hi[j] = f2b(sh[kc + j][n]);
    u16* dst = Bt + (size_t)(n0 + n) * K + k0 + kc;
    uint4 a, b;
    a.x = (u32)hi[0] | ((u32)hi[1] << 16);  a.y = (u32)hi[2] | ((u32)hi[3] << 16);
    a.z = (u32)hi[4] | ((u32)hi[5] << 16);  a.w = (u32)hi[6] | ((u32)hi[7] << 16);
    b.x = (u32)hi[8] | ((u32)hi[9] << 16);  b.y = (u32)hi[10] | ((u32)hi[11] << 16);
    b.z = (u32)hi[12] | ((u32)hi[13] << 16); b.w = (u32)hi[14] | ((u32)hi[15] << 16);
    *(uint4*)dst = a; *(uint4*)(dst + 8) = b;
}

// ---------------------------------------------------------------------------
// pack_sb_rows: fp32 [8192][1024] -> split pack [row][hi|lo] (for proj A).
// ---------------------------------------------------------------------------
__global__ __launch_bounds__(256) void pack_sb_rows_kernel(
    const float* __restrict__ src, u16* __restrict__ dst)
{
    const int row = blockIdx.x, tid = threadIdx.x;
    float4 t = *(const float4*)(src + (size_t)row * 1024 + tid * 4);
    float v[4] = {t.x, t.y, t.z, t.w};
    u16 hi[4], lo[4];
    #pragma unroll
    for (int i = 0; i < 4; i++) {
        hi[i] = f2b(v[i]);
        lo[i] = f2b(v[i] - b2f(hi[i]));
    }
    uint2 ph, pl;
    ph.x = (u32)hi[0] | ((u32)hi[1] << 16);
    ph.y = (u32)hi[2] | ((u32)hi[3] << 16);
    pl.x = (u32)lo[0] | ((u32)lo[1] << 16);
    pl.y = (u32)lo[2] | ((u32)lo[3] << 16);
    *(uint2*)(dst + (size_t)row * 2048 + tid * 4) = ph;
    *(uint2*)(dst + (size_t)row * 2048 + 1024 + tid * 4) = pl;
}

// ---------------------------------------------------------------------------
// gemm_sb: split-bf16 3-pass MFMA GEMM. A [M][2K], B [N][2K], C fp32.
// 128x128 tile, 4 waves (2x2) of 64x64, BK=32.
// SB_FC1: fused router fc2 -- no C store; per-row partial logits
// (v * w2[col][e]) reduced over the 16-lane col groups and atomicAdd'ed
// into lg[token][4]. (R15)
// ---------------------------------------------------------------------------
#define SB_PLAIN 0
#define SB_FC1   1
#define SB_PROJ  2

__global__ __launch_bounds__(256) void gemm_sb(
    int mode,
    const u16* __restrict__ Ap,
    const u16* __restrict__ Bt,
    int K,
    float* __restrict__ C, int ldc,
    const void* __restrict__ bias,
    const float* __restrict__ condt,
    const void* __restrict__ resid,
    const void* __restrict__ w2,
    float* __restrict__ lg,
    int rowbase, const int* __restrict__ flg)
{
    const int isf = flg[12];
    __shared__ __align__(16) u16 Ah[128][40];
    __shared__ __align__(16) u16 Al[128][40];
    __shared__ __align__(16) u16 Bh[128][40];
    __shared__ __align__(16) u16 Bl[128][40];
    const int tid = threadIdx.x;
    const int row0 = blockIdx.y * 128, col0 = blockIdx.x * 128;
    const int wave = tid >> 6, lane = tid & 63;
    const int wm = (wave >> 1) * 64, wn = (wave & 1) * 64;
    const int ln = lane & 15, quad = lane >> 4;
    const size_t K2 = (size_t)2 * K;
    floatx4 acc[4][4];
    #pragma unroll
    for (int i = 0; i < 4; i++)
        #pragma unroll
        for (int j = 0; j < 4; j++) acc[i][j] = (floatx4){0.f, 0.f, 0.f, 0.f};

    const int ar = tid >> 1, ac = (tid & 1) * 16;
    uint4 pa0, pa1, pal0, pal1, pb0, pb1, pbl0, pbl1;

    {
        const u16* ap = Ap + (size_t)(row0 + ar) * K2 + ac;
        pa0 = *(const uint4*)ap;        pa1 = *(const uint4*)(ap + 8);
        pal0 = *(const uint4*)(ap + K); pal1 = *(const uint4*)(ap + K + 8);
        const u16* bp = Bt + (size_t)(col0 + ar) * K2 + ac;
        pb0 = *(const uint4*)bp;        pb1 = *(const uint4*)(bp + 8);
        pbl0 = *(const uint4*)(bp + K); pbl1 = *(const uint4*)(bp + K + 8);
    }

    for (int k0 = 0; k0 < K; k0 += 32) {
        __syncthreads();
        *(uint4*)&Ah[ar][ac] = pa0;  *(uint4*)&Ah[ar][ac + 8] = pa1;
        *(uint4*)&Al[ar][ac] = pal0; *(uint4*)&Al[ar][ac + 8] = pal1;
        *(uint4*)&Bh[ar][ac] = pb0;  *(uint4*)&Bh[ar][ac + 8] = pb1;
        *(uint4*)&Bl[ar][ac] = pbl0; *(uint4*)&Bl[ar][ac + 8] = pbl1;
        __syncthreads();
        if (k0 + 32 < K) {
            const u16* ap = Ap + (size_t)(row0 + ar) * K2 + k0 + 32 + ac;
            pa0 = *(const uint4*)ap;        pa1 = *(const uint4*)(ap + 8);
            pal0 = *(const uint4*)(ap + K); pal1 = *(const uint4*)(ap + K + 8);
            const u16* bp = Bt + (size_t)(col0 + ar) * K2 + k0 + 32 + ac;
            pb0 = *(const uint4*)bp;        pb1 = *(const uint4*)(bp + 8);
            pbl0 = *(const uint4*)(bp + K); pbl1 = *(const uint4*)(bp + K + 8);
        }
        bf16x8 ah[4], al[4];
        #pragma unroll
        for (int mt = 0; mt < 4; mt++) {
            ah[mt] = *(const bf16x8*)&Ah[wm + mt * 16 + ln][quad * 8];
            al[mt] = *(const bf16x8*)&Al[wm + mt * 16 + ln][quad * 8];
        }
        #pragma unroll
        for (int nt = 0; nt < 4; nt++) {
            bf16x8 bh = *(const bf16x8*)&Bh[wn + nt * 16 + ln][quad * 8];
            bf16x8 bl = *(const bf16x8*)&Bl[wn + nt * 16 + ln][quad * 8];
            #pragma unroll
            for (int mt = 0; mt < 4; mt++) {
                acc[mt][nt] = __builtin_amdgcn_mfma_f32_16x16x32_bf16(ah[mt], bh, acc[mt][nt], 0, 0, 0);
                acc[mt][nt] = __builtin_amdgcn_mfma_f32_16x16x32_bf16(ah[mt], bl, acc[mt][nt], 0, 0, 0);
                acc[mt][nt] = __builtin_amdgcn_mfma_f32_16x16x32_bf16(al[mt], bh, acc[mt][nt], 0, 0, 0);
            }
        }
    }
    if (mode == SB_FC1) {
        // fused fc2: load w2 rows for this thread's 16 columns once.
        float w2r[4][4];
        #pragma unroll
        for (int nt = 0; nt < 4; nt++)
            ld4(w2, (size_t)(col0 + wn + nt * 16 + ln) * 4, isf, w2r[nt]);
        #pragma unroll
        for (int mt = 0; mt < 4; mt++) {
            #pragma unroll
            for (int r = 0; r < 4; r++) {
                int row = row0 + wm + mt * 16 + quad * 4 + r;
                float p0 = 0.f, p1 = 0.f, p2 = 0.f, p3 = 0.f;
                #pragma unroll
                for (int nt = 0; nt < 4; nt++) {
                    int col = col0 + wn + nt * 16 + ln;
                    float v = gelu_f(acc[mt][nt][r] + lmix(bias, col, isf) +
                                     condt[(size_t)((rowbase + row) >> 8) * 2048 + col]);
                    p0 = fmaf(v, w2r[nt][0], p0);
                    p1 = fmaf(v, w2r[nt][1], p1);
                    p2 = fmaf(v, w2r[nt][2], p2);
                    p3 = fmaf(v, w2r[nt][3], p3);
                }
                #pragma unroll
                for (int off = 1; off < 16; off <<= 1) {
                    p0 += __shfl_xor(p0, off, 16);
                    p1 += __shfl_xor(p1, off, 16);
                    p2 += __shfl_xor(p2, off, 16);
                    p3 += __shfl_xor(p3, off, 16);
                }
                if (ln == 0) {
                    float* dst = lg + (size_t)(rowbase + row) * 4;
                    atomicAdd(dst + 0, p0);
                    atomicAdd(dst + 1, p1);
                    atomicAdd(dst + 2, p2);
                    atomicAdd(dst + 3, p3);
                }
            }
        }
    } else {
        #pragma unroll
        for (int mt = 0; mt < 4; mt++) {
            #pragma unroll
            for (int nt = 0; nt < 4; nt++) {
                #pragma unroll
                for (int r = 0; r < 4; r++) {
                    int row = row0 + wm + mt * 16 + quad * 4 + r;
                    int col = col0 + wn + nt * 16 + ln;
                    float v = acc[mt][nt][r];
                    if (mode == SB_PROJ)
                        v += lmix(bias, col, isf) + lmix(resid, (size_t)row * ldc + col, isf);
                    C[(size_t)row * ldc + col] = v;
                }
            }
        }
    }
}

// ---------------------------------------------------------------------------
// top2_kernel: per token, read fused logits + bias, top-2 + weights.
// No atomics (fill2 self-counts). 32 blocks x 256 threads.
// ---------------------------------------------------------------------------
__global__ __launch_bounds__(256) void top2_kernel(
    const float* __restrict__ lg, const void* __restrict__ b2,
    int* __restrict__ t2i, float* __restrict__ t2w,
    const int* __restrict__ flg)
{
    const int isf = flg[12];
    const int t = blockIdx.x * 256 + threadIdx.x;
    float l[4];
    #pragma unroll
    for (int i = 0; i < 4; i++)
        l[i] = lg[(size_t)t * 4 + i] + lmix(b2, i, isf);
    int i0 = 0;
    #pragma unroll
    for (int i = 1; i < 4; i++) if (l[i] > l[i0]) i0 = i;
    int i1 = (i0 == 0) ? 1 : 0;
    #pragma unroll
    for (int i = 0; i < 4; i++) if (i != i0 && l[i] > l[i1]) i1 = i;
    float mx = fmaxf(fmaxf(l[0], l[1]), fmaxf(l[2], l[3]));
    float e0 = __expf(l[0] - mx), e1 = __expf(l[1] - mx);
    float e2 = __expf(l[2] - mx), e3 = __expf(l[3] - mx);
    float inv = 1.0f / (e0 + e1 + e2 + e3);
    float p[4] = { e0 * inv, e1 * inv, e2 * inv, e3 * inv };
    float b0 = fminf(fmaxf(p[i0], 1e-9f), 1.0f - 1e-9f);
    float b1 = fminf(fmaxf(p[i1], 1e-9f), 1.0f - 1e-9f);
    float winv = 1.0f / (b0 + b1);
    t2i[2 * t] = i0; t2i[2 * t + 1] = i1;
    t2w[2 * t] = b0 * winv; t2w[2 * t + 1] = b1 * winv;
}

// ---------------------------------------------------------------------------
// gemm_moe: plain bf16 MFMA GEMM, 128x128 tile (expert FC1).
// ---------------------------------------------------------------------------
#define MOE_FC1 0
#define MOE_FC2 1

__global__ __launch_bounds__(256) void gemm_moe(
    int mode,
    const u16* __restrict__ Ap,
    const u16* __restrict__ Bt,
    int K,
    u16* __restrict__ C, int ldc,
    const void* __restrict__ bias, size_t biasOff,
    const float* __restrict__ rowscale,
    const int* __restrict__ toklist,
    const int* __restrict__ cb, int e, int rowOff,
    const int* __restrict__ flg)
{
    const int isf = flg[12];
    const int Meff = cb[e];
    const int gbase = cb[4 + e];
    const int rg0 = rowOff + blockIdx.y * 128;
    if (rg0 >= Meff) return;
    const int col0 = blockIdx.x * 128;
    __shared__ __align__(16) u16 As[128][40];
    __shared__ __align__(16) u16 Bs[128][40];
    const int tid = threadIdx.x;
    const int wave = tid >> 6, lane = tid & 63;
    const int wm = (wave >> 1) * 64, wn = (wave & 1) * 64;
    const int ln = lane & 15, quad = lane >> 4;
    floatx4 acc[4][4];
    #pragma unroll
    for (int i = 0; i < 4; i++)
        #pragma unroll
        for (int j = 0; j < 4; j++) acc[i][j] = (floatx4){0.f, 0.f, 0.f, 0.f};

    const int ar = tid >> 1, ac = (tid & 1) * 16;
    const int rg = rg0 + ar;
    const bool valid = (rg < Meff);
    const u16* arow;
    if (mode == MOE_FC1) {
        int tokid = valid ? toklist[gbase + rg] : 0;
        arow = Ap + (size_t)tokid * K;
    } else {
        arow = Ap + (size_t)(rg - rowOff) * K;
    }
    const u16* brow = Bt + (size_t)(col0 + ar) * K;
    uint4 pa0 = {0u,0u,0u,0u}, pa1 = {0u,0u,0u,0u}, pb0, pb1;
    if (valid) { pa0 = *(const uint4*)(arow + ac); pa1 = *(const uint4*)(arow + ac + 8); }
    pb0 = *(const uint4*)(brow + ac); pb1 = *(const uint4*)(brow + ac + 8);

    for (int k0 = 0; k0 < K; k0 += 32) {
        __syncthreads();
        *(uint4*)&As[ar][ac] = pa0; *(uint4*)&As[ar][ac + 8] = pa1;
        *(uint4*)&Bs[ar][ac] = pb0; *(uint4*)&Bs[ar][ac + 8] = pb1;
        __syncthreads();
        if (k0 + 32 < K) {
            if (valid) {
                pa0 = *(const uint4*)(arow + k0 + 32 + ac);
                pa1 = *(const uint4*)(arow + k0 + 32 + ac + 8);
            }
            pb0 = *(const uint4*)(brow + k0 + 32 + ac);
            pb1 = *(const uint4*)(brow + k0 + 32 + ac + 8);
        }
        bf16x8 a[4];
        #pragma unroll
        for (int mt = 0; mt < 4; mt++)
            a[mt] = *(const bf16x8*)&As[wm + mt * 16 + ln][quad * 8];
        #pragma unroll
        for (int nt = 0; nt < 4; nt++) {
            bf16x8 b = *(const bf16x8*)&Bs[wn + nt * 16 + ln][quad * 8];
            #pragma unroll
            for (int mt = 0; mt < 4; mt++)
                acc[mt][nt] = __builtin_amdgcn_mfma_f32_16x16x32_bf16(a[mt], b, acc[mt][nt], 0, 0, 0);
        }
    }
    #pragma unroll
    for (int mt = 0; mt < 4; mt++) {
        #pragma unroll
        for (int nt = 0; nt < 4; nt++) {
            #pragma unroll
            for (int r = 0; r < 4; r++) {
                int gw = rg0 + wm + mt * 16 + quad * 4 + r;
                if (gw >= Meff) continue;
                int col = col0 + wn + nt * 16 + ln;
                float v = acc[mt][nt][r] + lmix(bias, biasOff + col, isf);
                if (mode == MOE_FC1) {
                    C[(size_t)(gw - rowOff) * ldc + col] = f2b(gelu_f(v));
                } else {
                    v *= rowscale[gbase + gw];
                    C[(size_t)(gbase + gw) * ldc + col] = f2b(v);
                }
            }
        }
    }
}

// ---------------------------------------------------------------------------
// gemm_moe2: expert FC2 bf16 MFMA GEMM. 128x64 tile, grid 16x16 = 256 blocks.
// ---------------------------------------------------------------------------
__global__ __launch_bounds__(256) void gemm_moe2(
    const u16* __restrict__ Ap,
    const u16* __restrict__ Bt,
    u16* __restrict__ C,
    const void* __restrict__ bias, size_t biasOff,
    const float* __restrict__ rowscale,
    const int* __restrict__ cb, int e, int rowOff,
    const int* __restrict__ flg)
{
    const int isf = flg[12];
    const int Meff = cb[e];
    const int gbase = cb[4 + e];
    const int rg0 = rowOff + blockIdx.y * 128;
    if (rg0 >= Meff) return;
    const int col0 = blockIdx.x * 64;
    const int K = 4096;
    __shared__ __align__(16) u16 As[128][40];
    __shared__ __align__(16) u16 Bs[64][40];
    const int tid = threadIdx.x;
    const int wave = tid >> 6, lane = tid & 63;
    const int ln = lane & 15, quad = lane >> 4;
    floatx4 acc[2][4];
    #pragma unroll
    for (int i = 0; i < 2; i++)
        #pragma unroll
        for (int j = 0; j < 4; j++) acc[i][j] = (floatx4){0.f, 0.f, 0.f, 0.f};

    const int ar = tid >> 1, ac = (tid & 1) * 16;   // A: 128 rows x 32 k
    const int br = tid >> 2, bc = (tid & 3) * 8;    // B: 64 rows x 32 k
    const int rg = rg0 + ar;
    const bool valid = (rg < Meff);
    const u16* arow = Ap + (size_t)(rg - rowOff) * K;
    const u16* brow = Bt + (size_t)(col0 + br) * K;
    uint4 pa0 = {0u,0u,0u,0u}, pa1 = {0u,0u,0u,0u}, pb;
    if (valid) { pa0 = *(const uint4*)(arow + ac); pa1 = *(const uint4*)(arow + ac + 8); }
    pb = *(const uint4*)(brow + bc);

    for (int k0 = 0; k0 < K; k0 += 32) {
        __syncthreads();
        *(uint4*)&As[ar][ac] = pa0; *(uint4*)&As[ar][ac + 8] = pa1;
        *(uint4*)&Bs[br][bc] = pb;
        __syncthreads();
        if (k0 + 32 < K) {
            if (valid) {
                pa0 = *(const uint4*)(arow + k0 + 32 + ac);
                pa1 = *(const uint4*)(arow + k0 + 32 + ac + 8);
            }
            pb = *(const uint4*)(brow + k0 + 32 + bc);
        }
        bf16x8 a0 = *(const bf16x8*)&As[wave * 32 + ln][quad * 8];
        bf16x8 a1 = *(const bf16x8*)&As[wave * 32 + 16 + ln][quad * 8];
        #pragma unroll
        for (int nt = 0; nt < 4; nt++) {
            bf16x8 b = *(const bf16x8*)&Bs[nt * 16 + ln][quad * 8];
            acc[0][nt] = __builtin_amdgcn_mfma_f32_16x16x32_bf16(a0, b, acc[0][nt], 0, 0, 0);
            acc[1][nt] = __builtin_amdgcn_mfma_f32_16x16x32_bf16(a1, b, acc[1][nt], 0, 0, 0);
        }
    }
    #pragma unroll
    for (int mt = 0; mt < 2; mt++) {
        #pragma unroll
        for (int nt = 0; nt < 4; nt++) {
            #pragma unroll
            for (int r = 0; r < 4; r++) {
                int gw = rg0 + wave * 32 + mt * 16 + quad * 4 + r;
                if (gw >= Meff) continue;
                int col = col0 + nt * 16 + ln;
                float v = acc[mt][nt][r] + lmix(bias, biasOff + col, isf);
                v *= rowscale[gbase + gw];
                C[(size_t)(gbase + gw) * 1024 + col] = f2b(v);
            }
        }
    }
}

// ---------------------------------------------------------------------------
__global__ __launch_bounds__(256) void ln_stats_kernel(
    const float* __restrict__ xin, float* __restrict__ mu, float* __restrict__ rs)
{
    const int row = blockIdx.x, tid = threadIdx.x;
    float4 t = *(const float4*)(xin + (size_t)row * 1024 + tid * 4);
    float s = t.x + t.y + t.z + t.w;
    float q = t.x * t.x + t.y * t.y + t.z * t.z + t.w * t.w;
    #pragma unroll
    for (int off = 32; off > 0; off >>= 1) {
        s += __shfl_down(s, off, 64);
        q += __shfl_down(q, off, 64);
    }
    __shared__ float red[8];
    int wid = tid >> 6, lane = tid & 63;
    if (lane == 0) { red[wid] = s; red[4 + wid] = q; }
    __syncthreads();
    if (tid == 0) {
        float ts = red[0] + red[1] + red[2] + red[3];
        float tq = red[4] + red[5] + red[6] + red[7];
        float m = ts * (1.0f / 1024.0f);
        float var = tq * (1.0f / 1024.0f) - m * m;
        float xx = var + 1e-5f;
        float r = rsqrtf(xx);
        r = r * (1.5f - 0.5f * xx * r * r);
        mu[row] = m; rs[row] = r;
    }
}

// ---------------------------------------------------------------------------
// fp32 VALU GEMM (fallback proj).
// ---------------------------------------------------------------------------
#define GM_PLAIN 0
#define GM_PROJ  1

__global__ __launch_bounds__(256) void gemm_f32(
    int mode, int aMode,
    const void* __restrict__ Av, int lda,
    const void* __restrict__ Bv, int ldb, int bRow0,
    int M, int N, int K,
    float* __restrict__ C, int ldc,
    const void* __restrict__ bias,
    const void* __restrict__ resid,
    const int* __restrict__ flg)
{
    const int isf = flg[12];
    __shared__ float As[16][132];
    __shared__ float Bs[16][132];
    const int tid = threadIdx.x;
    const int row0 = blockIdx.y * 128, col0 = blockIdx.x * 128;
    const int tx = tid & 15, ty = tid >> 4;
    float acc[8][8];
    #pragma unroll
    for (int i = 0; i < 8; i++)
        #pragma unroll
        for (int j = 0; j < 8; j++) acc[i][j] = 0.f;

    for (int k0 = 0; k0 < K; k0 += 16) {
        __syncthreads();
        #pragma unroll
        for (int i = 0; i < 2; i++) {
            int lin = tid + i * 256;
            int r = lin >> 2, kc = (lin & 3) * 4;
            float v[4] = {0.f, 0.f, 0.f, 0.f};
            if (row0 + r < M) {
                if (aMode == 1) {
                    ld4(Av, (size_t)(row0 + r) * lda + k0 + kc, isf, v);
                } else {
                    float4 t = *(const float4*)((const float*)Av + (size_t)(row0 + r) * lda + k0 + kc);
                    v[0] = t.x; v[1] = t.y; v[2] = t.z; v[3] = t.w;
                }
            }
            As[kc + 0][r] = v[0]; As[kc + 1][r] = v[1];
            As[kc + 2][r] = v[2]; As[kc + 3][r] = v[3];
        }
        {
            int kc = tid >> 4, c8 = (tid & 15) * 8;
            float w[8];
            ld8(Bv, (size_t)(bRow0 + k0 + kc) * ldb + col0 + c8, isf, w);
            #pragma unroll
            for (int j = 0; j < 8; j++) Bs[kc][c8 + j] = w[j];
        }
        __syncthreads();
        #pragma unroll
        for (int kk = 0; kk < 16; kk++) {
            float a[8], b[8];
            *(float4*)&a[0] = *(const float4*)&As[kk][ty * 8];
            *(float4*)&a[4] = *(const float4*)&As[kk][ty * 8 + 4];
            *(float4*)&b[0] = *(const float4*)&Bs[kk][tx * 8];
            *(float4*)&b[4] = *(const float4*)&Bs[kk][tx * 8 + 4];
            #pragma unroll
            for (int i = 0; i < 8; i++)
                #pragma unroll
                for (int j = 0; j < 8; j++) acc[i][j] = fmaf(a[i], b[j], acc[i][j]);
        }
    }
    #pragma unroll
    for (int i = 0; i < 8; i++) {
        int gr = row0 + ty * 8 + i;
        if (gr >= M) continue;
        #pragma unroll
        for (int j = 0; j < 8; j++) {
            int gc = col0 + tx * 8 + j;
            float v = acc[i][j];
            if (mode == GM_PROJ)
                v += lmix(bias, gc, isf) + lmix(resid, (size_t)gr * ldc + gc, isf);
            C[(size_t)gr * ldc + gc] = v;
        }
    }
}

// ---------------------------------------------------------------------------
// attn_mfma: split-bf16 MFMA flash attention (fat path).
// Block = (b_local, h, qtile of 64); 4 waves, wave owns 16 q rows.
// ---------------------------------------------------------------------------
__global__ __launch_bounds__(256) void attn_mfma_kernel(
    const float* __restrict__ qkv, float* __restrict__ o)
{
    const int bx = blockIdx.x;
    const int b  = bx >> 6;
    const int hh = (bx >> 2) & 15;
    const int qt = bx & 3;
    const int tid = threadIdx.x;
    const int wave = tid >> 6, lane = tid & 63;
    const int ln = lane & 15, quad = lane >> 4;

    __shared__ __align__(16) u16 Sh[64][264];
    __shared__ __align__(16) u16 Sl[64][264];
    __shared__ __align__(16) u16 KVh[64][72];
    __shared__ __align__(16) u16 KVl[64][72];
    __shared__ float mred[64][4];
    __shared__ float lred[64][4];
    __shared__ float lsh[64];

    const size_t tokbase = (size_t)b * 256;

    bf16x8 qh[2], ql[2];
    {
        const float* qp = qkv + (tokbase + qt * 64 + wave * 16 + ln) * 3072 + hh * 64;
        #pragma unroll
        for (int ks = 0; ks < 2; ks++) {
            float4 f0 = *(const float4*)(qp + ks * 32 + quad * 8);
            float4 f1 = *(const float4*)(qp + ks * 32 + quad * 8 + 4);
            float fv[8] = {f0.x, f0.y, f0.z, f0.w, f1.x, f1.y, f1.z, f1.w};
            union { uint4 u; bf16x8 v; } ch, cl;
            u32 hw[4], lw[4];
            #pragma unroll
            for (int j = 0; j < 4; j++) {
                u16 h0 = f2b(fv[2 * j]),      h1 = f2b(fv[2 * j + 1]);
                u16 l0 = f2b(fv[2 * j] - b2f(h0));
                u16 l1 = f2b(fv[2 * j + 1] - b2f(h1));
                hw[j] = (u32)h0 | ((u32)h1 << 16);
                lw[j] = (u32)l0 | ((u32)l1 << 16);
            }
            ch.u.x = hw[0]; ch.u.y = hw[1]; ch.u.z = hw[2]; ch.u.w = hw[3];
            cl.u.x = lw[0]; cl.u.y = lw[1]; cl.u.z = lw[2]; cl.u.w = lw[3];
            qh[ks] = ch.v; ql[ks] = cl.v;
        }
    }

    const int skey = tid >> 2, sds = (tid & 3) * 16;
    float4 kpre[4];
    {
        const float* kp = qkv + (tokbase + skey) * 3072 + 1024 + hh * 64 + sds;
        #pragma unroll
        for (int i = 0; i < 4; i++) kpre[i] = *(const float4*)(kp + i * 4);
    }
    for (int kt = 0; kt < 4; kt++) {
        __syncthreads();
        #pragma unroll
        for (int i = 0; i < 4; i++) {
            float fv[4] = {kpre[i].x, kpre[i].y, kpre[i].z, kpre[i].w};
            u16 hv[4], lv[4];
            #pragma unroll
            for (int j = 0; j < 4; j++) {
                hv[j] = f2b(fv[j]);
                lv[j] = f2b(fv[j] - b2f(hv[j]));
            }
            uint2 uh, ul;
            uh.x = (u32)hv[0] | ((u32)hv[1] << 16);
            uh.y = (u32)hv[2] | ((u32)hv[3] << 16);
            ul.x = (u32)lv[0] | ((u32)lv[1] << 16);
            ul.y = (u32)lv[2] | ((u32)lv[3] << 16);
            *(uint2*)&KVh[skey][sds + i * 4] = uh;
            *(uint2*)&KVl[skey][sds + i * 4] = ul;
        }
        __syncthreads();
        if (kt < 3) {
            const float* kp = qkv + (tokbase + (kt + 1) * 64 + skey) * 3072 + 1024 + hh * 64 + sds;
            #pragma unroll
            for (int i = 0; i < 4; i++) kpre[i] = *(const float4*)(kp + i * 4);
        }
        floatx4 acc[4];
        #pragma unroll
        for (int nt = 0; nt < 4; nt++) acc[nt] = (floatx4){0.f, 0.f, 0.f, 0.f};
        #pragma unroll
        for (int ks = 0; ks < 2; ks++) {
            bf16x8 kh[4], kl[4];
            #pragma unroll
            for (int nt = 0; nt < 4; nt++) {
                kh[nt] = *(const bf16x8*)&KVh[nt * 16 + ln][ks * 32 + quad * 8];
                kl[nt] = *(const bf16x8*)&KVl[nt * 16 + ln][ks * 32 + quad * 8];
            }
            #pragma unroll
            for (int nt = 0; nt < 4; nt++)
                acc[nt] = __builtin_amdgcn_mfma_f32_16x16x32_bf16(qh[ks], kh[nt], acc[nt], 0, 0, 0);
            #pragma unroll
            for (int nt = 0; nt < 4; nt++)
                acc[nt] = __builtin_amdgcn_mfma_f32_16x16x32_bf16(qh[ks], kl[nt], acc[nt], 0, 0, 0);
            #pragma unroll
            for (int nt = 0; nt < 4; nt++)
                acc[nt] = __builtin_amdgcn_mfma_f32_16x16x32_bf16(ql[ks], kh[nt], acc[nt], 0, 0, 0);
        }
        #pragma unroll
        for (int nt = 0; nt < 4; nt++) {
            #pragma unroll
            for (int r = 0; r < 4; r++) {
                float s = acc[nt][r] * 0.125f;
                u16 hi = f2b(s);
                Sh[wave * 16 + quad * 4 + r][kt * 64 + nt * 16 + ln] = hi;
                Sl[wave * 16 + quad * 4 + r][kt * 64 + nt * 16 + ln] = f2b(s - b2f(hi));
            }
        }
    }

    __syncthreads();
    {
        const int q = tid >> 2, seg = tid & 3;
        float mx = -1e30f;
        #pragma unroll
        for (int i = 0; i < 8; i++) {
            uint4 h4 = *(const uint4*)&Sh[q][seg * 64 + i * 8];
            uint4 l4 = *(const uint4*)&Sl[q][seg * 64 + i * 8];
            mx = fmaxf(mx, fmaxf(b2f(h4.x) + b2f(l4.x), b2f(h4.x >> 16) + b2f(l4.x >> 16)));
            mx = fmaxf(mx, fmaxf(b2f(h4.y) + b2f(l4.y), b2f(h4.y >> 16) + b2f(l4.y >> 16)));
            mx = fmaxf(mx, fmaxf(b2f(h4.z) + b2f(l4.z), b2f(h4.z >> 16) + b2f(l4.z >> 16)));
            mx = fmaxf(mx, fmaxf(b2f(h4.w) + b2f(l4.w), b2f(h4.w >> 16) + b2f(l4.w >> 16)));
        }
        mred[q][seg] = mx;
        __syncthreads();
        float m = fmaxf(fmaxf(mred[q][0], mred[q][1]), fmaxf(mred[q][2], mred[q][3]));
        float sum = 0.f;
        #pragma unroll
        for (int i = 0; i < 8; i++) {
            uint4 h4 = *(const uint4*)&Sh[q][seg * 64 + i * 8];
            uint4 l4 = *(const uint4*)&Sl[q][seg * 64 + i * 8];
            u32 hw[4] = {h4.x, h4.y, h4.z, h4.w};
            u32 lw[4] = {l4.x, l4.y, l4.z, l4.w};
            uint4 oh, ol;
            u32* ohp = (u32*)&oh; u32* olp = (u32*)&ol;
            #pragma unroll
            for (int j = 0; j < 4; j++) {
                float p0 = __expf(b2f(hw[j]) + b2f(lw[j]) - m);
                float p1 = __expf(b2f(hw[j] >> 16) + b2f(lw[j] >> 16) - m);
                sum += p0 + p1;
                u16 ph0 = f2b(p0), ph1 = f2b(p1);
                u16 pl0 = f2b(p0 - b2f(ph0)), pl1 = f2b(p1 - b2f(ph1));
                ohp[j] = (u32)ph0 | ((u32)ph1 << 16);
                olp[j] = (u32)pl0 | ((u32)pl1 << 16);
            }
            *(uint4*)&Sh[q][seg * 64 + i * 8] = oh;
            *(uint4*)&Sl[q][seg * 64 + i * 8] = ol;
        }
        lred[q][seg] = sum;
        __syncthreads();
        if (seg == 0)
            lsh[q] = (lred[q][0] + lred[q][1]) + (lred[q][2] + lred[q][3]);
    }

    const int vd = tid & 63, vk0 = (tid >> 6) * 16;
    float vpre[16];
    {
        const float* vp = qkv + (tokbase + vk0) * 3072 + 2048 + hh * 64 + vd;
        #pragma unroll
        for (int j = 0; j < 16; j++) vpre[j] = vp[(size_t)j * 3072];
    }
    floatx4 pacc[4];
    #pragma unroll
    for (int nt = 0; nt < 4; nt++) pacc[nt] = (floatx4){0.f, 0.f, 0.f, 0.f};
    for (int kt = 0; kt < 4; kt++) {
        __syncthreads();
        #pragma unroll
        for (int w = 0; w < 4; w++) {
            u16 hv[4], lv[4];
            #pragma unroll
            for (int j = 0; j < 4; j++) {
                float f = vpre[w * 4 + j];
                hv[j] = f2b(f);
                lv[j] = f2b(f - b2f(hv[j]));
            }
            uint2 uh, ul;
            uh.x = (u32)hv[0] | ((u32)hv[1] << 16);
            uh.y = (u32)hv[2] | ((u32)hv[3] << 16);
            ul.x = (u32)lv[0] | ((u32)lv[1] << 16);
            ul.y = (u32)lv[2] | ((u32)lv[3] << 16);
            *(uint2*)&KVh[vd][vk0 + w * 4] = uh;
            *(uint2*)&KVl[vd][vk0 + w * 4] = ul;
        }
        __syncthreads();
        if (kt < 3) {
            const float* vp = qkv + (tokbase + (kt + 1) * 64 + vk0) * 3072 + 2048 + hh * 64 + vd;
            #pragma unroll
            for (int j = 0; j < 16; j++) vpre[j] = vp[(size_t)j * 3072];
        }
        #pragma unroll
        for (int ks = 0; ks < 2; ks++) {
            const int kc = kt * 64 + ks * 32 + quad * 8;
            bf16x8 ph = *(const bf16x8*)&Sh[wave * 16 + ln][kc];
            bf16x8 pl = *(const bf16x8*)&Sl[wave * 16 + ln][kc];
            bf16x8 vh[4], vl[4];
            #pragma unroll
            for (int nt = 0; nt < 4; nt++) {
                vh[nt] = *(const bf16x8*)&KVh[nt * 16 + ln][ks * 32 + quad * 8];
                vl[nt] = *(const bf16x8*)&KVl[nt * 16 + ln][ks * 32 + quad * 8];
            }
            #pragma unroll
            for (int nt = 0; nt < 4; nt++)
                pacc[nt] = __builtin_amdgcn_mfma_f32_16x16x32_bf16(ph, vh[nt], pacc[nt], 0, 0, 0);
            #pragma unroll
            for (int nt = 0; nt < 4; nt++)
                pacc[nt] = __builtin_amdgcn_mfma_f32_16x16x32_bf16(ph, vl[nt], pacc[nt], 0, 0, 0);
            #pragma unroll
            for (int nt = 0; nt < 4; nt++)
                pacc[nt] = __builtin_amdgcn_mfma_f32_16x16x32_bf16(pl, vh[nt], pacc[nt], 0, 0, 0);
        }
    }
    {
        float linv[4];
        #pragma unroll
        for (int r = 0; r < 4; r++)
            linv[r] = 1.0f / lsh[wave * 16 + quad * 4 + r];
        #pragma unroll
        for (int nt = 0; nt < 4; nt++) {
            #pragma unroll
            for (int r = 0; r < 4; r++) {
                int row = wave * 16 + quad * 4 + r;
                o[(tokbase + qt * 64 + row) * 1024 + hh * 64 + nt * 16 + ln] =
                    pacc[nt][r] * linv[r];
            }
        }
    }
}

// ---------------------------------------------------------------------------
// Fallback attention (fp32 VALU). Block = (b, h, qtile of 64).
// ---------------------------------------------------------------------------
__global__ __launch_bounds__(256) void attn_kernel(
    const float* __restrict__ qkv, float* __restrict__ o)
{
    const int bx = blockIdx.x;
    const int b  = bx >> 6;
    const int hh = (bx >> 2) & 15;
    const int qt = bx & 3;
    const int tid = threadIdx.x;
    const int wave = tid >> 6, lane = tid & 63;

    __shared__ float sh[2 * 64 * 68];
    float* Ks = sh;
    float* Vs = sh + 64 * 68;

    const int q = qt * 64 + lane;
    float qreg[64];
    const float* qp = qkv + (size_t)(b * 256 + q) * 3072 + hh * 64;
    #pragma unroll
    for (int i = 0; i < 16; i++) *(float4*)&qreg[i * 4] = *(const float4*)(qp + i * 4);

    float oa[64];
    #pragma unroll
    for (int d = 0; d < 64; d++) oa[d] = 0.f;
    float m = -1e30f, l = 0.f;

    for (int s = 0; s < 4; s++) {
        __syncthreads();
        {
            int r = tid >> 2;
            int c = (tid & 3) * 16;
            int key = (r >> 4) * 64 + s * 16 + (r & 15);
            const float* kp = qkv + (size_t)(b * 256 + key) * 3072 + 1024 + hh * 64 + c;
            #pragma unroll
            for (int i = 0; i < 4; i++) {
                *(float4*)&Ks[r * 68 + c + i * 4] = *(const float4*)(kp + i * 4);
                *(float4*)&Vs[r * 68 + c + i * 4] = *(const float4*)(kp + 1024 + i * 4);
            }
        }
        __syncthreads();
        const float* Kw = Ks + wave * 16 * 68;
        const float* Vw = Vs + wave * 16 * 68;
        for (int jj = 0; jj < 16; jj++) {
            float s0 = 0.f, s1 = 0.f, s2 = 0.f, s3 = 0.f;
            #pragma unroll
            for (int d = 0; d < 64; d += 4) {
                s0 = fmaf(qreg[d + 0], Kw[jj * 68 + d + 0], s0);
                s1 = fmaf(qreg[d + 1], Kw[jj * 68 + d + 1], s1);
                s2 = fmaf(qreg[d + 2], Kw[jj * 68 + d + 2], s2);
                s3 = fmaf(qreg[d + 3], Kw[jj * 68 + d + 3], s3);
            }
            float sc = ((s0 + s1) + (s2 + s3)) * 0.125f;
            float mn = fmaxf(m, sc);
            float c = __expf(m - mn);
            float p = __expf(sc - mn);
            l = l * c + p;
            #pragma unroll
            for (int d = 0; d < 64; d++)
                oa[d] = fmaf(oa[d], c, p * Vw[jj * 68 + d]);
            m = mn;
        }
    }

    __syncthreads();
    if (wave == 1 || wave == 3) {
        float* dst = sh + (wave >> 1) * (64 * 66) + lane * 66;
        #pragma unroll
        for (int d = 0; d < 64; d++) dst[d] = oa[d];
        dst[64] = m; dst[65] = l;
    }
    __syncthreads();
    if (wave == 0 || wave == 2) {
        const float* src = sh + (wave >> 1) * (64 * 66) + lane * 66;
        float m2 = src[64], l2 = src[65];
        float M = fmaxf(m, m2);
        float c1 = __expf(m - M), c2 = __expf(m2 - M);
        l = l * c1 + l2 * c2;
        #pragma unroll
        for (int d = 0; d < 64; d++) oa[d] = oa[d] * c1 + src[d] * c2;
        m = M;
    }
    __syncthreads();
    if (wave == 2) {
        float* dst = sh + lane * 66;
        #pragma unroll
        for (int d = 0; d < 64; d++) dst[d] = oa[d];
        dst[64] = m; dst[65] = l;
    }
    __syncthreads();
    if (wave == 0) {
        const float* src = sh + lane * 66;
        float m2 = src[64], l2 = src[65];
        float M = fmaxf(m, m2);
        float c1 = __expf(m - M), c2 = __expf(m2 - M);
        l = l * c1 + l2 * c2;
        #pragma unroll
        for (int d = 0; d < 64; d++) oa[d] = oa[d] * c1 + src[d] * c2;
        float inv = 1.0f / l;
        float* op = o + (size_t)(b * 256 + q) * 1024 + hh * 64;
        #pragma unroll
        for (int i = 0; i < 16; i++) {
            float4 v = { oa[i * 4] * inv, oa[i * 4 + 1] * inv,
                         oa[i * 4 + 2] * inv, oa[i * 4 + 3] * inv };
            *(float4*)(op + i * 4) = v;
        }
    }
}

// ---------------------------------------------------------------------------
// Router fc2 + top2 (fallback path only). One wave per token.
// ---------------------------------------------------------------------------
__global__ __launch_bounds__(256) void router_kernel(
    const float* __restrict__ hr, const void* __restrict__ w2,
    const void* __restrict__ b2, int* __restrict__ t2i,
    float* __restrict__ t2w, int* __restrict__ cb, int rowbase,
    const int* __restrict__ flg)
{
    const int isf = flg[12];
    const int lt = blockIdx.x * 4 + (threadIdx.x >> 6);
    const int t = rowbase + lt;
    const int lane = threadIdx.x & 63;
    float a0 = 0.f, a1 = 0.f, a2 = 0.f, a3 = 0.f;
    const float* hp = hr + (size_t)lt * 2048;
    #pragma unroll
    for (int it = 0; it < 8; it++) {
        const int j = it * 256 + lane * 4;
        float4 hv = *(const float4*)(hp + j);
        float w[4];
        ld4(w2, (size_t)(j + 0) * 4, isf, w);
        a0 = fmaf(hv.x, w[0], a0); a1 = fmaf(hv.x, w[1], a1);
        a2 = fmaf(hv.x, w[2], a2); a3 = fmaf(hv.x, w[3], a3);
        ld4(w2, (size_t)(j + 1) * 4, isf, w);
        a0 = fmaf(hv.y, w[0], a0); a1 = fmaf(hv.y, w[1], a1);
        a2 = fmaf(hv.y, w[2], a2); a3 = fmaf(hv.y, w[3], a3);
        ld4(w2, (size_t)(j + 2) * 4, isf, w);
        a0 = fmaf(hv.z, w[0], a0); a1 = fmaf(hv.z, w[1], a1);
        a2 = fmaf(hv.z, w[2], a2); a3 = fmaf(hv.z, w[3], a3);
        ld4(w2, (size_t)(j + 3) * 4, isf, w);
        a0 = fmaf(hv.w, w[0], a0); a1 = fmaf(hv.w, w[1], a1);
        a2 = fmaf(hv.w, w[2], a2); a3 = fmaf(hv.w, w[3], a3);
    }
    #pragma unroll
    for (int off = 32; off > 0; off >>= 1) {
        a0 += __shfl_down(a0, off, 64);
        a1 += __shfl_down(a1, off, 64);
        a2 += __shfl_down(a2, off, 64);
        a3 += __shfl_down(a3, off, 64);
    }
    if (lane == 0) {
        float l[4];
        l[0] = a0 + lmix(b2, 0, isf); l[1] = a1 + lmix(b2, 1, isf);
        l[2] = a2 + lmix(b2, 2, isf); l[3] = a3 + lmix(b2, 3, isf);
        int i0 = 0;
        #pragma unroll
        for (int i = 1; i < 4; i++) if (l[i] > l[i0]) i0 = i;
        int i1 = (i0 == 0) ? 1 : 0;
        #pragma unroll
        for (int i = 0; i < 4; i++) if (i != i0 && l[i] > l[i1]) i1 = i;
        float mx = fmaxf(fmaxf(l[0], l[1]), fmaxf(l[2], l[3]));
        float e0 = __expf(l[0] - mx), e1 = __expf(l[1] - mx);
        float e2 = __expf(l[2] - mx), e3 = __expf(l[3] - mx);
        float inv = 1.0f / (e0 + e1 + e2 + e3);
        float p[4] = { e0 * inv, e1 * inv, e2 * inv, e3 * inv };
        float b0 = fminf(fmaxf(p[i0], 1e-9f), 1.0f - 1e-9f);
        float b1 = fminf(fmaxf(p[i1], 1e-9f), 1.0f - 1e-9f);
        float winv = 1.0f / (b0 + b1);
        t2i[2 * t] = i0; t2i[2 * t + 1] = i1;
        t2w[2 * t] = b0 * winv; t2w[2 * t + 1] = b1 * winv;
    }
}

// ---------------------------------------------------------------------------
// fill2 v2: deterministic token->slot assignment via LDS scan; self-counts
// ALL experts (no external atomic counts); writes cb[e] and cb[4+e].
// ---------------------------------------------------------------------------
__global__ __launch_bounds__(256) void fill2_kernel(
    const int* __restrict__ t2i, const float* __restrict__ t2w,
    int* __restrict__ cb, int* __restrict__ tok,
    float* __restrict__ aw, int* __restrict__ apos)
{
    const int e = blockIdx.x;
    const int tid = threadIdx.x;
    __shared__ int scan4[4][256];
    const int t0 = tid * 32;
    int cnt[4] = {0, 0, 0, 0};
    for (int t = t0; t < t0 + 32; t++) {
        cnt[t2i[2 * t]]++;
        cnt[t2i[2 * t + 1]]++;
    }
    #pragma unroll
    for (int k = 0; k < 4; k++) scan4[k][tid] = cnt[k];
    __syncthreads();
    for (int off = 1; off < 256; off <<= 1) {
        int add[4];
        #pragma unroll
        for (int k = 0; k < 4; k++)
            add[k] = (tid >= off) ? scan4[k][tid - off] : 0;
        __syncthreads();
        #pragma unroll
        for (int k = 0; k < 4; k++) scan4[k][tid] += add[k];
        __syncthreads();
    }
    int base = 0;
    #pragma unroll
    for (int k = 0; k < 4; k++) if (k < e) base += scan4[k][255];
    int pos = base + scan4[e][tid] - cnt[e];   // exclusive prefix within expert
    for (int t = t0; t < t0 + 32; t++) {
        #pragma unroll
        for (int j = 0; j < 2; j++) {
            if (t2i[2 * t + j] == e) {
                tok[pos] = t;
                aw[pos] = t2w[2 * t + j];
                apos[2 * t + j] = pos;
                pos++;
            }
        }
    }
    if (tid == 0) { cb[e] = scan4[e][255]; cb[4 + e] = base; }
}

// ---------------------------------------------------------------------------
// Fallback MoE GEMM (R7): 64x64 tile, in-loop LN + f2b.
// ---------------------------------------------------------------------------
#define EM_FC1 0
#define EM_FC2 1

__global__ __launch_bounds__(256) void gemm_mfma(
    int mode,
    const float* __restrict__ x1,
    const float* __restrict__ mu, const float* __restrict__ rs,
    const void* __restrict__ lng, const void* __restrict__ lnb,
    const u16* __restrict__ Ab,
    const void* __restrict__ B, size_t bOff, int ldb, int K,
    u16* __restrict__ C, int ldc,
    const void* __restrict__ bias, size_t biasOff,
    const float* __restrict__ rowscale,
    const int* __restrict__ toklist,
    const int* __restrict__ cb, int e, int rowOff,
    const int* __restrict__ flg)
{
    const int isf = flg[12];
    const int Meff = cb[e];
    const int gbase = cb[4 + e];
    const int rg0 = rowOff + blockIdx.y * 64;
    if (rg0 >= Meff) return;
    const int col0 = blockIdx.x * 64;
    __shared__ __align__(16) u16 As[64][72];
    __shared__ __align__(16) u16 Bs[64][72];
    const int tid = threadIdx.x;
    const int wave = tid >> 6, lane = tid & 63;
    const int ln = lane & 15, quad = lane >> 4;
    floatx4 acc[4];
    #pragma unroll
    for (int nt = 0; nt < 4; nt++) acc[nt] = (floatx4){0.f, 0.f, 0.f, 0.f};

    const int ar = tid >> 2, ac = (tid & 3) * 8;
    const int bk = tid >> 3, bn = (tid & 7) * 8;
    const int rg = rg0 + ar;
    const bool valid = (rg < Meff);
    int tokid = 0; float lm = 0.f, lr = 0.f;
    if (mode == EM_FC1 && valid) {
        tokid = toklist[gbase + rg];
        lm = mu[tokid]; lr = rs[tokid];
    }

    for (int k0 = 0; k0 < K; k0 += 32) {
        __syncthreads();
        if (mode == EM_FC1) {
            uint4 packed = {0u, 0u, 0u, 0u};
            if (valid) {
                float4 p0 = *(const float4*)(x1 + (size_t)tokid * 1024 + k0 + ac);
                float4 p1 = *(const float4*)(x1 + (size_t)tokid * 1024 + k0 + ac + 4);
                float pv[8] = {p0.x, p0.y, p0.z, p0.w, p1.x, p1.y, p1.z, p1.w};
                float gg[8], bb[8];
                ld8(lng, k0 + ac, isf, gg);
                ld8(lnb, k0 + ac, isf, bb);
                u16 wb[8];
                #pragma unroll
                for (int z = 0; z < 8; z++)
                    wb[z] = f2b((pv[z] - lm) * lr * gg[z] + bb[z]);
                packed.x = (u32)wb[0] | ((u32)wb[1] << 16);
                packed.y = (u32)wb[2] | ((u32)wb[3] << 16);
                packed.z = (u32)wb[4] | ((u32)wb[5] << 16);
                packed.w = (u32)wb[6] | ((u32)wb[7] << 16);
            }
            *(uint4*)&As[ar][ac] = packed;
        } else {
            uint4 av = {0u, 0u, 0u, 0u};
            if (valid) av = *(const uint4*)(Ab + (size_t)(rg - rowOff) * K + k0 + ac);
            *(uint4*)&As[ar][ac] = av;
        }
        u16 u[8];
        {
            float w[8];
            ld8(B, bOff + (size_t)(k0 + bk) * ldb + col0 + bn, isf, w);
            #pragma unroll
            for (int z = 0; z < 8; z++) u[z] = f2b(w[z]);
        }
        #pragma unroll
        for (int jj = 0; jj < 8; jj++) {
            int j = (jj + (tid & 7)) & 7;
            Bs[bn + j][bk] = u[j];
        }
        __syncthreads();
        bf16x8 af = *(const bf16x8*)&As[wave * 16 + ln][quad * 8];
        #pragma unroll
        for (int nt = 0; nt < 4; nt++) {
            bf16x8 bf = *(const bf16x8*)&Bs[nt * 16 + ln][quad * 8];
            acc[nt] = __builtin_amdgcn_mfma_f32_16x16x32_bf16(af, bf, acc[nt], 0, 0, 0);
        }
    }
    #pragma unroll
    for (int nt = 0; nt < 4; nt++) {
        #pragma unroll
        for (int r = 0; r < 4; r++) {
            int gw = rg0 + wave * 16 + quad * 4 + r;
            if (gw >= Meff) continue;
            int gcol = col0 + nt * 16 + ln;
            float v = acc[nt][r] + lmix(bias, biasOff + gcol, isf);
            if (mode == EM_FC1) {
                C[(size_t)(gw - rowOff) * ldc + gcol] = f2b(gelu_f(v));
            } else {
                v *= rowscale[gbase + gw];
                C[(size_t)(gbase + gw) * ldc + gcol] = f2b(v);
            }
        }
    }
}

// ---------------------------------------------------------------------------
__global__ __launch_bounds__(256) void combine_kernel(
    const float* __restrict__ x1, const u16* __restrict__ eo,
    const int* __restrict__ apos, void* __restrict__ outv,
    const int* __restrict__ flg)
{
    const int isf = flg[12];
    int t = blockIdx.x;
    int c = threadIdx.x * 4;
    int p0 = apos[2 * t], p1 = apos[2 * t + 1];
    float4 xv = *(const float4*)(x1 + (size_t)t * 1024 + c);
    uint2 ea = *(const uint2*)(eo + (size_t)p0 * 1024 + c);
    uint2 eb = *(const uint2*)(eo + (size_t)p1 * 1024 + c);
    float r0 = xv.x + b2f(ea.x) + b2f(eb.x);
    float r1 = xv.y + b2f(ea.x >> 16) + b2f(eb.x >> 16);
    float r2 = xv.z + b2f(ea.y) + b2f(eb.y);
    float r3 = xv.w + b2f(ea.y >> 16) + b2f(eb.y >> 16);
    if (isf) {
        float4 res = {r0, r1, r2, r3};
        *(float4*)((float*)outv + (size_t)t * 1024 + c) = res;
    } else {
        uint2 res;
        res.x = (u32)f2b(r0) | ((u32)f2b(r1) << 16);
        res.y = (u32)f2b(r2) | ((u32)f2b(r3) << 16);
        *(uint2*)((u16*)outv + (size_t)t * 1024 + c) = res;
    }
}

// ---------------------------------------------------------------------------
extern "C" void kernel_launch(void* const* d_in, const int* in_sizes, int n_in,
                              void* d_out, int out_size, void* d_ws, size_t ws_size,
                              hipStream_t stream)
{
    const void* x      = d_in[0];
    const void* cond   = d_in[1];
    const void* ln1_g  = d_in[2];
    const void* ln1_b  = d_in[3];
    const void* qkv_w  = d_in[4];
    const void* proj_w = d_in[5];
    const void* proj_b = d_in[6];
    const void* ln2_g  = d_in[7];
    const void* ln2_b  = d_in[8];
    const void* rf1w   = d_in[9];
    const void* rf1b   = d_in[10];
    const void* rf2w   = d_in[11];
    const void* rf2b   = d_in[12];
    const void* ew1    = d_in[13];
    const void* eb1    = d_in[14];
    const void* ew2    = d_in[15];
    const void* eb2    = d_in[16];
    (void)in_sizes; (void)n_in; (void)out_size;

    char* ws = (char*)d_ws;
    const size_t MB = 1024 * 1024;
    const bool fat = ws_size >= (size_t)116 * MB;

    // [0,32M): x1 after proj. Attn phase (fat): qkvt [0,12), hpk [12,28).
    float* x1   = (float*)(ws);
    u16*   qkvt = (u16*)(ws);
    u16*   hpk  = (u16*)(ws + 12 * MB);
    float* qkvcFb = (float*)(ws + 16 * MB);   // fallback: 1024 rows
    // [32,64M): ob (attn out) -> rf1t [32,40) + h2t [40,56) (router) -> eo (MoE).
    char*  B1   = ws + 32 * MB;
    float* ob   = (float*)B1;
    u16*   rf1tF= (u16*)B1;                   // fat router: [32,40)
    u16*   h2tF = (u16*)(ws + 40 * MB);       // fat router: [40,56), 4096 rows
    u16*   eo   = (u16*)B1;
    u16*   rf1tB= (u16*)B1;
    // [64,...): fat attn: qkvc 48M at [64,112). fat proj: obp [64,96).
    // fat MoE: hid [64,80)+ew1t[80,88)+ew2t[88,96).
    char*  R    = ws + 64 * MB;
    float* qkvcF= (float*)R;                  // fat: 4096 rows x 3072 fp32 = 48M
    u16*   h2tB = (u16*)R;
    float* hrcB = (float*)(R + 8 * MB);
    u16*   hid  = (u16*)R;
    u16*   obp  = (u16*)R;
    u16*   ew1t = (u16*)(R + 16 * MB);
    u16*   ew2t = (u16*)(R + 24 * MB);
    u16*   pwt  = (u16*)(ws + 96 * MB);
    u16*   h2b  = (u16*)(ws + 96 * MB);
    char*  ST   = ws + (fat ? 112 : 96) * MB;

    size_t so = 0;
    auto salloc = [&](size_t bytes) { size_t o = so; so += (bytes + 255) & ~(size_t)255; return o; };
    float* mu   = (float*)(ST + salloc(8192 * 4));
    float* rs   = (float*)(ST + salloc(8192 * 4));
    float* ct   = (float*)(ST + salloc((size_t)32 * 2048 * 4));
    int*   t2i  = (int*)  (ST + salloc(16384 * 4));
    float* t2w  = (float*)(ST + salloc(16384 * 4));
    int*   cb   = (int*)  (ST + salloc(16 * 4));
    int*   tok  = (int*)  (ST + salloc(16384 * 4));
    float* aw   = (float*)(ST + salloc(16384 * 4));
    int*   apos = (int*)  (ST + salloc(16384 * 4));
    float* lg   = (float*)(ST + salloc(32768 * 4));   // fused router logits

    init_kernel<<<1, 256, 0, stream>>>(x, cb);

    // ---- Attention pipeline ----
    pack_wt_kernel<<<dim3(16, 48), 256, 0, stream>>>(qkv_w, 3072, 1024, qkvt, cb);
    if (fat) {
        for (int c = 0; c < 2; c++) {
            const size_t r0 = (size_t)c * 4096;
            pack_ln_kernel<<<4096, 256, 0, stream>>>(
                0, x, r0, ln1_g, ln1_b, nullptr, nullptr, hpk, nullptr, cb);
            gemm_sb<<<dim3(24, 32), 256, 0, stream>>>(
                SB_PLAIN, hpk, qkvt, 1024, qkvcF, 3072, nullptr, nullptr, nullptr,
                nullptr, nullptr, 0, cb);
            attn_mfma_kernel<<<1024, 256, 0, stream>>>(qkvcF, ob + r0 * 1024);
        }
    } else {
        for (int c = 0; c < 8; c++) {
            const size_t r0 = (size_t)c * 1024;
            pack_ln_kernel<<<1024, 256, 0, stream>>>(
                0, x, r0, ln1_g, ln1_b, nullptr, nullptr, hpk, nullptr, cb);
            gemm_sb<<<dim3(24, 8), 256, 0, stream>>>(
                SB_PLAIN, hpk, qkvt, 1024, qkvcFb, 3072, nullptr, nullptr, nullptr,
                nullptr, nullptr, 0, cb);
            attn_kernel<<<256, 256, 0, stream>>>(qkvcFb, ob + r0 * 1024);
        }
    }

    // ---- proj + bias + residual(x) -> x1 ----
    if (fat) {
        pack_sb_rows_kernel<<<8192, 256, 0, stream>>>(ob, obp);
        pack_wt_kernel<<<dim3(16, 16), 256, 0, stream>>>(proj_w, 1024, 1024, pwt, cb);
        gemm_sb<<<dim3(8, 64), 256, 0, stream>>>(
            SB_PROJ, obp, pwt, 1024, x1, 1024, proj_b, nullptr, x,
            nullptr, nullptr, 0, cb);
    } else {
        gemm_f32<<<dim3(8, 64), 256, 0, stream>>>(
            GM_PROJ, 0, (const void*)ob, 1024, proj_w, 1024, 0, 8192, 1024, 1024,
            x1, 1024, proj_b, x, cb);
    }

    // LN2 stats
    ln_stats_kernel<<<8192, 256, 0, stream>>>(x1, mu, rs);

    // cond @ r_fc1_w[1024:2048,:] -> ct [32,2048]
    cond_kernel<<<dim3(32, 32), 256, 0, stream>>>(cond, rf1w, ct, cb);

    // ---- Router fc1 (+fused fc2) + top2 ----
    if (fat) {
        zero_lg_kernel<<<128, 256, 0, stream>>>(lg);
        pack_wt_kernel<<<dim3(16, 32), 256, 0, stream>>>(rf1w, 2048, 1024, rf1tF, cb);
        for (int rc = 0; rc < 2; rc++) {
            const int rb = rc * 4096;
            pack_ln_kernel<<<4096, 256, 0, stream>>>(
                1, x1, rb, ln2_g, ln2_b, mu, rs, h2tF, h2b, cb);
            gemm_sb<<<dim3(16, 32), 256, 0, stream>>>(
                SB_FC1, h2tF, rf1tF, 1024, nullptr, 2048, rf1b, ct, nullptr,
                rf2w, lg, rb, cb);
        }
        top2_kernel<<<32, 256, 0, stream>>>(lg, rf2b, t2i, t2w, cb);
    } else {
        pack_wt_kernel<<<dim3(16, 32), 256, 0, stream>>>(rf1w, 2048, 1024, rf1tB, cb);
        zero_lg_kernel<<<128, 256, 0, stream>>>(lg);
        for (int rc = 0; rc < 4; rc++) {
            const int rb = rc * 2048;
            pack_ln_kernel<<<2048, 256, 0, stream>>>(
                1, x1, rb, ln2_g, ln2_b, mu, rs, h2tB, nullptr, cb);
            gemm_sb<<<dim3(16, 16), 256, 0, stream>>>(
                SB_FC1, h2tB, rf1tB, 1024, nullptr, 2048, rf1b, ct, nullptr,
                rf2w, lg, rb, cb);
        }
        top2_kernel<<<32, 256, 0, stream>>>(lg, rf2b, t2i, t2w, cb);
    }
    fill2_kernel<<<4, 256, 0, stream>>>(t2i, t2w, cb, tok, aw, apos);

    // ---- Expert MLPs ----
    if (fat) {
        for (int e = 0; e < 4; e++) {
            pack_wtb_kernel<<<dim3(16, 64), 256, 0, stream>>>(
                ew1, (size_t)e * 1024 * 4096, 4096, 1024, ew1t, cb);
            pack_wtb_kernel<<<dim3(64, 16), 256, 0, stream>>>(
                ew2, (size_t)e * 4096 * 1024, 1024, 4096, ew2t, cb);
            for (int c = 0; c < 4; c++) {
                const int ro = c * 2048;
                gemm_moe<<<dim3(32, 16), 256, 0, stream>>>(
                    MOE_FC1, h2b, ew1t, 1024, hid, 4096,
                    eb1, (size_t)e * 4096, nullptr, tok, cb, e, ro, cb);
                gemm_moe2<<<dim3(16, 16), 256, 0, stream>>>(
                    hid, ew2t, eo, eb2, (size_t)e * 1024, aw, cb, e, ro, cb);
            }
        }
    } else {
        for (int e = 0; e < 4; e++) {
            for (int c = 0; c < 2; c++) {
                const int ro = c * 4096;
                gemm_mfma<<<dim3(64, 64), 256, 0, stream>>>(
                    EM_FC1, x1, mu, rs, ln2_g, ln2_b, nullptr,
                    ew1, (size_t)e * 1024 * 4096, 4096, 1024,
                    hid, 4096, eb1, (size_t)e * 4096, nullptr, tok, cb, e, ro, cb);
                gemm_mfma<<<dim3(16, 64), 256, 0, stream>>>(
                    EM_FC2, nullptr, nullptr, nullptr, nullptr, nullptr, hid,
                    ew2, (size_t)e * 4096 * 1024, 1024, 4096,
                    eo, 1024, eb2, (size_t)e * 1024, aw, tok, cb, e, ro, cb);
            }
        }
    }

    combine_kernel<<<8192, 256, 0, stream>>>(x1, eo, apos, d_out, cb);
}